// Round 10
// baseline (1662.787 us; speedup 1.0000x reference)
//
#include <hip/hip_runtime.h>
#include <math.h>

#define NN 50000
#define NE 800000
#define HID 128
#define NNH ((size_t)NN * HID)
#define NPAD 50176

typedef __attribute__((ext_vector_type(8))) short short8;
typedef __attribute__((ext_vector_type(4))) float f32x4;
typedef __attribute__((ext_vector_type(2))) _Float16 half2v;

__device__ __forceinline__ ushort f2bf(float f) {
  unsigned u = __float_as_uint(f);
  unsigned r = (u + 0x7fffu + ((u >> 16) & 1u)) >> 16;
  return (ushort)r;
}
__device__ __forceinline__ float bf2f(ushort h) {
  return __uint_as_float(((unsigned)h) << 16);
}
__device__ __forceinline__ ushort f2h_bits(float f) {
  _Float16 h = (_Float16)f;
  ushort u;
  __builtin_memcpy(&u, &h, 2);
  return u;
}
__device__ __forceinline__ half2v u2h(uint u) {
  half2v h;
  __builtin_memcpy(&h, &u, 4);
  return h;
}
__device__ __forceinline__ float silu_f(float x) { return x / (1.0f + __expf(-x)); }

// ---------------- utility ----------------
__global__ __launch_bounds__(256) void zero_i(int* __restrict__ p, int n)
{
  int i = blockIdx.x * 256 + threadIdx.x;
  if (i < n) p[i] = 0;
}

// ---------------- counting sort of edges by src ----------------
__global__ __launch_bounds__(256) void count_src(const int* __restrict__ src, int* __restrict__ cnt)
{
  int e = blockIdx.x * 256 + threadIdx.x;
  if (e < NE) atomicAdd(&cnt[src[e]], 1);
}

__global__ __launch_bounds__(1024) void scan_excl(const int* __restrict__ cnt, int* __restrict__ base, int n)
{
  __shared__ int ws[16];
  int t = threadIdx.x;
  const int per = (n + 1023) / 1024;
  int s0 = t * per;
  int sum = 0;
  for (int i = 0; i < per; ++i) { int idx = s0 + i; if (idx < n) sum += cnt[idx]; }
  int lane = t & 63, w = t >> 6;
  int v = sum;
  #pragma unroll
  for (int m = 1; m < 64; m <<= 1) { int o = __shfl_up(v, m, 64); if (lane >= m) v += o; }
  if (lane == 63) ws[w] = v;
  __syncthreads();
  if (t == 0) { int a = 0; for (int i = 0; i < 16; ++i) { int x = ws[i]; ws[i] = a; a += x; } }
  __syncthreads();
  int run = ws[w] + v - sum;
  for (int i = 0; i < per; ++i) {
    int idx = s0 + i;
    if (idx < n) { base[idx] = run; run += cnt[idx]; }
  }
}

__global__ __launch_bounds__(256) void place_edges(const int* __restrict__ src, const int* __restrict__ dst,
    const int* __restrict__ base, int* __restrict__ cur,
    int* __restrict__ dst_s, int* __restrict__ perm)
{
  int e = blockIdx.x * 256 + threadIdx.x;
  if (e >= NE) return;
  int s = src[e];
  int p = base[s] + atomicAdd(&cur[s], 1);
  dst_s[p] = dst[e]; perm[p] = e;
}

// permute edge_attr into sorted order AND convert to f16 ([NE][16] ushort = f16 bits)
__global__ __launch_bounds__(256) void permute_ea_h(const float4* __restrict__ ea,
    const int* __restrict__ perm, ushort* __restrict__ ea_s)
{
  int i = blockIdx.x * 256 + threadIdx.x;
  if (i >= NE * 4) return;
  int e = i >> 2, q = i & 3;
  float4 v = ea[(size_t)perm[e] * 4 + q];
  uint2 p;
  p.x = (uint)f2h_bits(v.x) | ((uint)f2h_bits(v.y) << 16);
  p.y = (uint)f2h_bits(v.z) | ((uint)f2h_bits(v.w) << 16);
  *(uint2*)&ea_s[(size_t)e * 16 + q * 4] = p;
}

// ---------------- weight conversion ----------------
__global__ __launch_bounds__(256) void cvt4(const float* __restrict__ s0, const float* __restrict__ s1,
    const float* __restrict__ s2, const float* __restrict__ s3, ushort* __restrict__ d)
{
  int i = blockIdx.x * 256 + threadIdx.x;
  if (i >= 65536) return;
  const float* s = (i < 16384) ? s0 : (i < 32768) ? s1 : (i < 49152) ? s2 : s3;
  d[i] = f2bf(s[i & 16383]);
}
__global__ __launch_bounds__(256) void cvt_wab(const float* __restrict__ s, ushort* __restrict__ d)
{
  int i = blockIdx.x * 256 + threadIdx.x;
  if (i >= 131072) return;
  int l = i >> 15, rem = i & 32767;
  int r = rem >> 7, c = rem & 127;
  int srow = r & 127, scol = ((r >> 7) << 7) + c;
  d[l * 104448 + r * 128 + c] = f2bf(s[(size_t)l * 34816 + srow * 272 + scol]);
}
__global__ __launch_bounds__(256) void cvt_std(const float* __restrict__ s, ushort* __restrict__ d,
    int rows, int cols, int lss)
{
  int i = blockIdx.x * 256 + threadIdx.x;
  int n = 4 * rows * cols;
  if (i >= n) return;
  int rc = rows * cols;
  int l = i / rc, rem = i - l * rc;
  d[l * 104448 + rem] = f2bf(s[(size_t)l * lss + rem]);
}

// ---------------- fold: W2N = N1b @ W2 (bf16), N1a (bf16), nv = N1b @ b2 (fp32) ----------------
__global__ __launch_bounds__(128) void fold_w(const float* __restrict__ nw1,
    const float* __restrict__ ew2, const float* __restrict__ eb2,
    ushort* __restrict__ wu_base, float* __restrict__ nv)
{
  __shared__ float red[2];
  int bid = blockIdx.x;
  int l = bid >> 7, m = bid & 127;
  int j = threadIdx.x;
  const float* n1row = nw1 + (size_t)l * 32768 + (size_t)m * 256;
  const float* n1b = n1row + 128;
  const float* w2 = ew2 + (size_t)l * 16384;
  float s = 0.f;
  for (int k = 0; k < 128; ++k) s = fmaf(n1b[k], w2[k * 128 + j], s);
  ushort* lb = wu_base + (size_t)l * 104448;
  lb[32768 + m * 128 + j] = f2bf(s);          // W2N
  lb[49152 + m * 128 + j] = f2bf(n1row[j]);   // N1a
  float p = n1b[j] * eb2[l * 128 + j];
  #pragma unroll
  for (int mm = 1; mm < 64; mm <<= 1) p += __shfl_xor(p, mm, 64);
  if ((j & 63) == 0) red[j >> 6] = p;
  __syncthreads();
  if (j == 0) nv[l * 128 + m] = red[0] + red[1];
}

// ---------------- fused 2-layer MLP: C = silu(A@W1^T + b1) @ W2^T + b2 ----------------
__global__ __launch_bounds__(256) void emb2(
    const float* __restrict__ A,
    const ushort* __restrict__ W1, const float* __restrict__ b1,
    const ushort* __restrict__ W2, const float* __restrict__ b2,
    float* __restrict__ C, int n)
{
  __shared__ ushort Al[64][136];
  const int tid = threadIdx.x;
  const int n0 = blockIdx.x * 64;

  #pragma unroll
  for (int i = 0; i < 8; ++i) {
    int s = tid + i * 256;
    int row = s >> 5, c4 = (s & 31) * 4;
    int gr = n0 + row;
    float4 v = make_float4(0.f, 0.f, 0.f, 0.f);
    if (gr < n) v = *(const float4*)(A + (size_t)gr * HID + c4);
    uint2 p;
    p.x = (uint)f2bf(v.x) | ((uint)f2bf(v.y) << 16);
    p.y = (uint)f2bf(v.z) | ((uint)f2bf(v.w) << 16);
    *(uint2*)&Al[row][c4] = p;
  }
  __syncthreads();

  const int w = tid >> 6, l = tid & 63;
  const int lr = l & 15, lh = l >> 4;

  f32x4 zf = {0.f, 0.f, 0.f, 0.f};
  f32x4 acc[8];
  #pragma unroll
  for (int nt = 0; nt < 8; ++nt) acc[nt] = zf;

  #pragma unroll
  for (int q = 0; q < 4; ++q) {
    short8 af = *(const short8*)&Al[w * 16 + lr][q * 32 + lh * 8];
    #pragma unroll
    for (int nt = 0; nt < 8; ++nt) {
      short8 bf = *(const short8*)(W1 + (size_t)(nt * 16 + lr) * HID + q * 32 + lh * 8);
      acc[nt] = __builtin_amdgcn_mfma_f32_16x16x32_bf16(af, bf, acc[nt], 0, 0, 0);
    }
  }

  float vb[8];
  #pragma unroll
  for (int nt = 0; nt < 8; ++nt) vb[nt] = b1[nt * 16 + lr];

  #pragma unroll
  for (int r = 0; r < 4; ++r) {
    int row = w * 16 + lh * 4 + r;
    #pragma unroll
    for (int nt = 0; nt < 8; ++nt)
      Al[row][nt * 16 + lr] = f2bf(silu_f(acc[nt][r] + vb[nt]));
  }

  f32x4 acc2[8];
  #pragma unroll
  for (int nt = 0; nt < 8; ++nt) acc2[nt] = zf;
  #pragma unroll
  for (int q = 0; q < 4; ++q) {
    short8 af = *(const short8*)&Al[w * 16 + lr][q * 32 + lh * 8];
    #pragma unroll
    for (int nt = 0; nt < 8; ++nt) {
      short8 bf = *(const short8*)(W2 + (size_t)(nt * 16 + lr) * HID + q * 32 + lh * 8);
      acc2[nt] = __builtin_amdgcn_mfma_f32_16x16x32_bf16(af, bf, acc2[nt], 0, 0, 0);
    }
  }

  float vb2[8];
  #pragma unroll
  for (int nt = 0; nt < 8; ++nt) vb2[nt] = b2[nt * 16 + lr];
  #pragma unroll
  for (int r = 0; r < 4; ++r) {
    int row = n0 + w * 16 + lh * 4 + r;
    if (row < n) {
      float* cr = C + (size_t)row * HID;
      #pragma unroll
      for (int nt = 0; nt < 8; ++nt)
        cr[nt * 16 + lr] = acc2[nt][r] + vb2[nt];
    }
  }
}

// ---------------- fused LN + dual GEMM (natural-layout Pa/Pb) ----------------
__global__ __launch_bounds__(256) void pab_ln(
    const float* __restrict__ Hraw, const ushort* __restrict__ Wab,
    const float* __restrict__ lg, const float* __restrict__ lbp,
    const float* __restrict__ eb1,
    float* __restrict__ Hn, float* __restrict__ Pa, float* __restrict__ Pb, int n)
{
  __shared__ float Hs[64][132];
  __shared__ ushort Al[64][136];
  const int tid = threadIdx.x;
  const int n0 = blockIdx.x * 64;

  #pragma unroll
  for (int i = 0; i < 8; ++i) {
    int s = tid + i * 256;
    int row = s >> 5, c4 = (s & 31) * 4;
    int gr = n0 + row;
    float4 v = make_float4(0.f, 0.f, 0.f, 0.f);
    if (gr < n) v = *(const float4*)(Hraw + (size_t)gr * HID + c4);
    *(float4*)&Hs[row][c4] = v;
  }
  __syncthreads();

  const int w = tid >> 6, l = tid & 63;
  const int lr = l & 15, lh = l >> 4;

  {
    const int row = w * 16 + lr;
    float s1 = 0.f, s2 = 0.f;
    #pragma unroll
    for (int j = 0; j < 8; ++j) {
      float4 v = *(float4*)&Hs[row][lh * 32 + j * 4];
      s1 += v.x + v.y + v.z + v.w;
      s2 += v.x * v.x + v.y * v.y + v.z * v.z + v.w * v.w;
    }
    s1 += __shfl_xor(s1, 16, 64); s1 += __shfl_xor(s1, 32, 64);
    s2 += __shfl_xor(s2, 16, 64); s2 += __shfl_xor(s2, 32, 64);
    float mu = s1 * (1.0f / 128.0f);
    float var = s2 * (1.0f / 128.0f) - mu * mu;
    float rs = rsqrtf(var + 1e-5f);
    int gr = n0 + row;
    #pragma unroll
    for (int j = 0; j < 8; ++j) {
      int c = lh * 32 + j * 4;
      float4 v = *(float4*)&Hs[row][c];
      float4 o;
      o.x = (v.x - mu) * rs * lg[c + 0] + lbp[c + 0];
      o.y = (v.y - mu) * rs * lg[c + 1] + lbp[c + 1];
      o.z = (v.z - mu) * rs * lg[c + 2] + lbp[c + 2];
      o.w = (v.w - mu) * rs * lg[c + 3] + lbp[c + 3];
      if (gr < n) *(float4*)(Hn + (size_t)gr * HID + c) = o;
      uint2 p;
      p.x = (uint)f2bf(o.x) | ((uint)f2bf(o.y) << 16);
      p.y = (uint)f2bf(o.z) | ((uint)f2bf(o.w) << 16);
      *(uint2*)&Al[row][c] = p;
    }
  }
  __syncthreads();

  f32x4 zf = {0.f, 0.f, 0.f, 0.f};
  f32x4 acc[16];
  #pragma unroll
  for (int nt = 0; nt < 16; ++nt) acc[nt] = zf;

  #pragma unroll
  for (int q = 0; q < 4; ++q) {
    short8 af = *(const short8*)&Al[w * 16 + lr][q * 32 + lh * 8];
    #pragma unroll
    for (int nt = 0; nt < 16; ++nt) {
      short8 bf = *(const short8*)(Wab + (size_t)(nt * 16 + lr) * HID + q * 32 + lh * 8);
      acc[nt] = __builtin_amdgcn_mfma_f32_16x16x32_bf16(af, bf, acc[nt], 0, 0, 0);
    }
  }

  float be[8];
  #pragma unroll
  for (int nt = 0; nt < 8; ++nt) be[nt] = eb1[nt * 16 + lr];

  #pragma unroll
  for (int r = 0; r < 4; ++r) {
    int row = n0 + w * 16 + lh * 4 + r;
    if (row >= n) break;
    float* pa = Pa + (size_t)row * HID;
    float* pb = Pb + (size_t)row * HID;
    #pragma unroll
    for (int nt = 0; nt < 8; ++nt) {
      int col = nt * 16 + lr;
      pa[col] = acc[nt][r] + be[nt];
      pb[col] = acc[nt + 8][r];
    }
  }
}

// ---------------- per-node CSR edge kernel: one wave = one node, 2 edges in 32-lane halves, fdot2 ----------------
// S[n] = sum_e SiLU(LN(Pa[n] + Pb[dst_e] + ea_e @ W1c^T))
__global__ __launch_bounds__(256) void node_edge(
    const float* __restrict__ Pa, const float* __restrict__ Pb,
    const ushort* __restrict__ ea_h,     // f16 bits, [NE][16]
    const int* __restrict__ dst_s,
    const int* __restrict__ ebase, const int* __restrict__ deg,
    const float* __restrict__ w1c,       // ew1 layer base: rows [c][272], cols 256..271 fp32
    const float* __restrict__ elg, const float* __restrict__ elb,
    float* __restrict__ S, int n)
{
  const int tid = threadIdx.x;
  const int wv = __builtin_amdgcn_readfirstlane(tid >> 6);
  const int lane = tid & 63;
  const int node = blockIdx.x * 4 + wv;
  if (node >= n) return;
  const int half = lane >> 5;          // which edge of the pair
  const int l32 = lane & 31;
  const int c0 = l32 * 4;              // 4 cols per lane

  const int beg = __builtin_amdgcn_readfirstlane(ebase[node]);
  const int dg  = __builtin_amdgcn_readfirstlane(deg[node]);

  if (dg == 0) {
    if (half == 0)
      *(float4*)(S + (size_t)node * HID + c0) = make_float4(0.f, 0.f, 0.f, 0.f);
    return;
  }

  // W1c rows c0..c0+3 as packed f16 pairs
  half2v w1h[4][8];
  #pragma unroll
  for (int c = 0; c < 4; ++c) {
    const float* wr = w1c + (size_t)(c0 + c) * 272 + 256;
    #pragma unroll
    for (int k = 0; k < 8; ++k) {
      half2v h;
      h[0] = (_Float16)wr[2 * k];
      h[1] = (_Float16)wr[2 * k + 1];
      w1h[c][k] = h;
    }
  }
  const float4 gv = *(const float4*)(elg + c0);
  const float4 bv = *(const float4*)(elb + c0);
  const float4 pav = *(const float4*)(Pa + (size_t)node * HID + c0);

  float a0 = 0.f, a1 = 0.f, a2 = 0.f, a3 = 0.f;

  uint4 eC0 = make_uint4(0,0,0,0), eC1 = eC0;
  float4 pbc = make_float4(0.f, 0.f, 0.f, 0.f);
  bool vc = false;

  auto LOADE = [&](int pairbase, uint4& e0, uint4& e1, float4& pb, bool& valid) {
    int my = pairbase + half;
    valid = my < dg;
    int eu = beg + (valid ? my : dg - 1);   // clamp to a safe edge
    int d = dst_s[eu];
    const ushort* ep = ea_h + (size_t)eu * 16;
    e0 = *(const uint4*)ep;
    e1 = *(const uint4*)(ep + 8);
    pb = *(const float4*)(Pb + (size_t)d * HID + c0);
  };

  auto PROCESS = [&](const uint4& e0, const uint4& e1, const float4& pb, bool valid) {
    half2v eh[8];
    eh[0] = u2h(e0.x); eh[1] = u2h(e0.y); eh[2] = u2h(e0.z); eh[3] = u2h(e0.w);
    eh[4] = u2h(e1.x); eh[5] = u2h(e1.y); eh[6] = u2h(e1.z); eh[7] = u2h(e1.w);

    float x0 = pav.x + pb.x, x1 = pav.y + pb.y, x2 = pav.z + pb.z, x3 = pav.w + pb.w;
    #pragma unroll
    for (int k = 0; k < 8; ++k) {
      x0 = __builtin_amdgcn_fdot2(eh[k], w1h[0][k], x0, false);
      x1 = __builtin_amdgcn_fdot2(eh[k], w1h[1][k], x1, false);
      x2 = __builtin_amdgcn_fdot2(eh[k], w1h[2][k], x2, false);
      x3 = __builtin_amdgcn_fdot2(eh[k], w1h[3][k], x3, false);
    }

    float s1 = (x0 + x1) + (x2 + x3);
    float s2 = (x0 * x0 + x1 * x1) + (x2 * x2 + x3 * x3);
    #pragma unroll
    for (int m = 1; m < 32; m <<= 1) {        // 5-step butterfly within the 32-lane half
      s1 += __shfl_xor(s1, m, 64);
      s2 += __shfl_xor(s2, m, 64);
    }
    float mu = s1 * (1.0f / 128.0f);
    float var = s2 * (1.0f / 128.0f) - mu * mu;
    float rs = rsqrtf(var + 1e-5f);
    float t0 = silu_f((x0 - mu) * rs * gv.x + bv.x);
    float t1 = silu_f((x1 - mu) * rs * gv.y + bv.y);
    float t2 = silu_f((x2 - mu) * rs * gv.z + bv.z);
    float t3 = silu_f((x3 - mu) * rs * gv.w + bv.w);
    if (valid) { a0 += t0; a1 += t1; a2 += t2; a3 += t3; }
  };

  LOADE(0, eC0, eC1, pbc, vc);

  for (int i = 0; i < dg; i += 2) {
    uint4 nC0 = make_uint4(0,0,0,0), nC1 = nC0;
    float4 npb = make_float4(0.f, 0.f, 0.f, 0.f);
    bool nv = false;
    if (i + 2 < dg) LOADE(i + 2, nC0, nC1, npb, nv);

    PROCESS(eC0, eC1, pbc, vc);

    eC0 = nC0; eC1 = nC1; pbc = npb; vc = nv;
  }

  // combine the two halves (different edge subsets, same columns)
  a0 += __shfl_xor(a0, 32, 64);
  a1 += __shfl_xor(a1, 32, 64);
  a2 += __shfl_xor(a2, 32, 64);
  a3 += __shfl_xor(a3, 32, 64);
  if (half == 0)
    *(float4*)(S + (size_t)node * HID + c0) = make_float4(a0, a1, a2, a3);
}

// ---------------- fused node MLP: h' = hn + (silu(LN(hn@N1a^T + S@W2N^T + deg*nv + nb1)))@N2^T + nb2 ----------------
__global__ __launch_bounds__(256) void node_mlp(
    const float* __restrict__ Hn, const float* __restrict__ S,
    const ushort* __restrict__ N1a, const ushort* __restrict__ W2N, const ushort* __restrict__ N2,
    const float* __restrict__ nb1, const float* __restrict__ nv, const int* __restrict__ deg,
    const float* __restrict__ lng, const float* __restrict__ lnb, const float* __restrict__ nb2,
    float* __restrict__ C, int n)
{
  __shared__ ushort Ahn[64][136];
  __shared__ ushort Ah[64][136];
  __shared__ ushort Alo[64][136];
  const int tid = threadIdx.x;
  const int n0 = blockIdx.x * 64;

  #pragma unroll
  for (int i = 0; i < 8; ++i) {
    int s = tid + i * 256;
    int row = s >> 5, c4 = (s & 31) * 4;
    int gr = n0 + row;
    float4 vh = make_float4(0.f, 0.f, 0.f, 0.f);
    float4 vs = make_float4(0.f, 0.f, 0.f, 0.f);
    if (gr < n) {
      vh = *(const float4*)(Hn + (size_t)gr * HID + c4);
      vs = *(const float4*)(S + (size_t)gr * HID + c4);
    }
    uint2 ph;
    ph.x = (uint)f2bf(vh.x) | ((uint)f2bf(vh.y) << 16);
    ph.y = (uint)f2bf(vh.z) | ((uint)f2bf(vh.w) << 16);
    *(uint2*)&Ahn[row][c4] = ph;
    ushort hx = f2bf(vs.x), hy = f2bf(vs.y), hz = f2bf(vs.z), hw = f2bf(vs.w);
    uint2 ps, pl;
    ps.x = (uint)hx | ((uint)hy << 16);
    ps.y = (uint)hz | ((uint)hw << 16);
    pl.x = (uint)f2bf(vs.x - bf2f(hx)) | ((uint)f2bf(vs.y - bf2f(hy)) << 16);
    pl.y = (uint)f2bf(vs.z - bf2f(hz)) | ((uint)f2bf(vs.w - bf2f(hw)) << 16);
    *(uint2*)&Ah[row][c4]  = ps;
    *(uint2*)&Alo[row][c4] = pl;
  }
  __syncthreads();

  const int w = tid >> 6, l = tid & 63;
  const int lr = l & 15, lh = l >> 4;

  f32x4 zf = {0.f, 0.f, 0.f, 0.f};
  f32x4 acc[8];
  #pragma unroll
  for (int nt = 0; nt < 8; ++nt) acc[nt] = zf;

  #pragma unroll
  for (int q = 0; q < 4; ++q) {
    short8 an = *(const short8*)&Ahn[w * 16 + lr][q * 32 + lh * 8];
    short8 ah = *(const short8*)&Ah[w * 16 + lr][q * 32 + lh * 8];
    short8 al = *(const short8*)&Alo[w * 16 + lr][q * 32 + lh * 8];
    #pragma unroll
    for (int nt = 0; nt < 8; ++nt) {
      short8 b1f = *(const short8*)(N1a + (size_t)(nt * 16 + lr) * HID + q * 32 + lh * 8);
      short8 b2f = *(const short8*)(W2N + (size_t)(nt * 16 + lr) * HID + q * 32 + lh * 8);
      acc[nt] = __builtin_amdgcn_mfma_f32_16x16x32_bf16(an, b1f, acc[nt], 0, 0, 0);
      acc[nt] = __builtin_amdgcn_mfma_f32_16x16x32_bf16(ah, b2f, acc[nt], 0, 0, 0);
      acc[nt] = __builtin_amdgcn_mfma_f32_16x16x32_bf16(al, b2f, acc[nt], 0, 0, 0);
    }
  }

  float vb[8], vn[8], gv[8], bv[8];
  #pragma unroll
  for (int nt = 0; nt < 8; ++nt) {
    int col = nt * 16 + lr;
    vb[nt] = nb1[col]; vn[nt] = nv[col];
    gv[nt] = lng[col]; bv[nt] = lnb[col];
  }

  #pragma unroll
  for (int r = 0; r < 4; ++r) {
    int row = n0 + w * 16 + lh * 4 + r;
    float degf = (row < n) ? (float)deg[row] : 0.f;
    float vals[8];
    #pragma unroll
    for (int nt = 0; nt < 8; ++nt) vals[nt] = acc[nt][r] + vb[nt] + degf * vn[nt];
    float s1 = 0.f, s2 = 0.f;
    #pragma unroll
    for (int nt = 0; nt < 8; ++nt) { s1 += vals[nt]; s2 += vals[nt] * vals[nt]; }
    #pragma unroll
    for (int m = 1; m < 16; m <<= 1) { s1 += __shfl_xor(s1, m, 64); s2 += __shfl_xor(s2, m, 64); }
    float mu = s1 * (1.0f / 128.0f);
    float var = s2 * (1.0f / 128.0f) - mu * mu;
    float rs = rsqrtf(var + 1e-5f);
    int lrow = w * 16 + lh * 4 + r;
    #pragma unroll
    for (int nt = 0; nt < 8; ++nt)
      Ahn[lrow][nt * 16 + lr] = f2bf(silu_f((vals[nt] - mu) * rs * gv[nt] + bv[nt]));
  }

  f32x4 acc2[8];
  #pragma unroll
  for (int nt = 0; nt < 8; ++nt) acc2[nt] = zf;
  #pragma unroll
  for (int q = 0; q < 4; ++q) {
    short8 af = *(const short8*)&Ahn[w * 16 + lr][q * 32 + lh * 8];
    #pragma unroll
    for (int nt = 0; nt < 8; ++nt) {
      short8 bf = *(const short8*)(N2 + (size_t)(nt * 16 + lr) * HID + q * 32 + lh * 8);
      acc2[nt] = __builtin_amdgcn_mfma_f32_16x16x32_bf16(af, bf, acc2[nt], 0, 0, 0);
    }
  }

  float vb2[8];
  #pragma unroll
  for (int nt = 0; nt < 8; ++nt) vb2[nt] = nb2[nt * 16 + lr];
  #pragma unroll
  for (int r = 0; r < 4; ++r) {
    int row = n0 + w * 16 + lh * 4 + r;
    if (row < n) {
      const float* hr = Hn + (size_t)row * HID;
      float* cr = C + (size_t)row * HID;
      #pragma unroll
      for (int nt = 0; nt < 8; ++nt) {
        int col = nt * 16 + lr;
        cr[col] = hr[col] + acc2[nt][r] + vb2[nt];
      }
    }
  }
}

extern "C" void kernel_launch(void* const* d_in, const int* in_sizes, int n_in,
                              void* d_out, int out_size, void* d_ws, size_t ws_size,
                              hipStream_t stream)
{
  const float* in_h  = (const float*)d_in[0];
  const int*   edges = (const int*)d_in[1];
  const float* ea    = (const float*)d_in[2];
  const float* ei_w1 = (const float*)d_in[3];
  const float* ei_b1 = (const float*)d_in[4];
  const float* ei_w2 = (const float*)d_in[5];
  const float* ei_b2 = (const float*)d_in[6];
  const float* ng    = (const float*)d_in[7];
  const float* nbp   = (const float*)d_in[8];
  const float* ew1   = (const float*)d_in[9];
  const float* eb1   = (const float*)d_in[10];
  const float* elg   = (const float*)d_in[11];
  const float* elb   = (const float*)d_in[12];
  const float* ew2   = (const float*)d_in[13];
  const float* eb2   = (const float*)d_in[14];
  const float* nw1   = (const float*)d_in[15];
  const float* nb1   = (const float*)d_in[16];
  const float* nlg   = (const float*)d_in[17];
  const float* nlb   = (const float*)d_in[18];
  const float* nw2   = (const float*)d_in[19];
  const float* nb2   = (const float*)d_in[20];
  const float* eo_w1 = (const float*)d_in[21];
  const float* eo_b1 = (const float*)d_in[22];
  const float* eo_w2 = (const float*)d_in[23];
  const float* eo_b2 = (const float*)d_in[24];

  float* wf    = (float*)d_ws;
  float* B_h   = wf;
  float* B_hn  = wf + NNH;
  float* B_S   = wf + 2 * NNH;   // S (edge-sum); perm alias during setup
  float* B_tmp = wf + 3 * NNH;   // Pa
  float* B_pb  = wf + 4 * NNH;   // Pb

  const size_t WOFF = 5 * NNH;
  ushort* wu = (ushort*)(wf + WOFF);
  // ei1@0, ei2@16384, eo1@32768, eo2@49152; per-layer base 65536 + l*104448:
  //   Wab@0 [256][128] | W2N@32768 | N1a@49152 | N2@81920
  const size_t SOFF = WOFF + 262144;
  int* dst_s = (int*)(wf + SOFF);
  int* cnt   = dst_s + NE;       // = deg
  int* cur   = cnt + NPAD;
  int* base  = cur + NPAD;
  ushort* ea_s = (ushort*)(base + NPAD);
  float* nvb = (float*)(ea_s + (size_t)NE * 16);   // 4*128 fp32
  int* perm  = (int*)B_S;

  const int NB  = (NN + 63) / 64;
  const int NBE = (NN + 3) / 4;
  const int NEB = (NE + 255) / 256;

  const int* erow = edges;
  const int* ecol = edges + NE;

  // ---- counting sort by src (once) ----
  zero_i<<<(2 * NPAD + 255) / 256, 256, 0, stream>>>(cnt, 2 * NPAD);
  count_src<<<NEB, 256, 0, stream>>>(erow, cnt);
  scan_excl<<<1, 1024, 0, stream>>>(cnt, base, NN);
  place_edges<<<NEB, 256, 0, stream>>>(erow, ecol, base, cur, dst_s, perm);
  permute_ea_h<<<(NE * 4 + 255) / 256, 256, 0, stream>>>((const float4*)ea, perm, ea_s);

  // ---- weight conversion / folding ----
  cvt4<<<256, 256, 0, stream>>>(ei_w1, ei_w2, eo_w1, eo_w2, wu);
  cvt_wab<<<512, 256, 0, stream>>>(ew1, wu + 65536);
  cvt_std<<<(4 * 16384 + 255) / 256, 256, 0, stream>>>(nw2, wu + 65536 + 81920, 128, 128, 16384);
  fold_w<<<512, 128, 0, stream>>>(nw1, ew2, eb2, wu + 65536, nvb);

  // ---- embedding_in (fused pair) ----
  emb2<<<NB, 256, 0, stream>>>(in_h, wu, ei_b1, wu + 16384, ei_b2, B_h, NN);

  for (int lyr = 0; lyr < 4; ++lyr) {
    ushort* lb = wu + 65536 + lyr * 104448;
    pab_ln<<<NB, 256, 0, stream>>>(B_h, lb, ng + 128 * lyr, nbp + 128 * lyr,
        eb1 + 128 * lyr, B_hn, B_tmp, B_pb, NN);
    node_edge<<<NBE, 256, 0, stream>>>(B_tmp, B_pb, ea_s, dst_s, base, cnt,
        ew1 + 34816 * lyr, elg + 128 * lyr, elb + 128 * lyr, B_S, NN);
    node_mlp<<<NB, 256, 0, stream>>>(B_hn, B_S, lb + 49152, lb + 32768, lb + 81920,
        nb1 + 128 * lyr, nvb + 128 * lyr, cnt,
        nlg + 128 * lyr, nlb + 128 * lyr, nb2 + 128 * lyr, B_h, NN);
  }

  // ---- embedding_out (fused pair) ----
  emb2<<<NB, 256, 0, stream>>>(B_h, wu + 32768, eo_b1, wu + 49152, eo_b2, (float*)d_out, NN);
}

// Round 11
// 1334.865 us; speedup vs baseline: 1.2457x; 1.2457x over previous
//
#include <hip/hip_runtime.h>
#include <math.h>

#define NN 50000
#define NE 800000
#define HID 128
#define NNH ((size_t)NN * HID)
#define NPAD 50176

typedef __attribute__((ext_vector_type(8))) short short8;
typedef __attribute__((ext_vector_type(4))) float f32x4;

__device__ __forceinline__ ushort f2bf(float f) {
  unsigned u = __float_as_uint(f);
  unsigned r = (u + 0x7fffu + ((u >> 16) & 1u)) >> 16;
  return (ushort)r;
}
__device__ __forceinline__ float bf2f(ushort h) {
  return __uint_as_float(((unsigned)h) << 16);
}
__device__ __forceinline__ float silu_f(float x) { return x / (1.0f + __expf(-x)); }

// ---------------- utility ----------------
__global__ __launch_bounds__(256) void zero_i(int* __restrict__ p, int n)
{
  int i = blockIdx.x * 256 + threadIdx.x;
  if (i < n) p[i] = 0;
}

// ---------------- counting sort of edges by src ----------------
__global__ __launch_bounds__(256) void count_src(const int* __restrict__ src, int* __restrict__ cnt)
{
  int e = blockIdx.x * 256 + threadIdx.x;
  if (e < NE) atomicAdd(&cnt[src[e]], 1);
}

__global__ __launch_bounds__(1024) void scan_excl(const int* __restrict__ cnt, int* __restrict__ base, int n)
{
  __shared__ int ws[16];
  int t = threadIdx.x;
  const int per = (n + 1023) / 1024;
  int s0 = t * per;
  int sum = 0;
  for (int i = 0; i < per; ++i) { int idx = s0 + i; if (idx < n) sum += cnt[idx]; }
  int lane = t & 63, w = t >> 6;
  int v = sum;
  #pragma unroll
  for (int m = 1; m < 64; m <<= 1) { int o = __shfl_up(v, m, 64); if (lane >= m) v += o; }
  if (lane == 63) ws[w] = v;
  __syncthreads();
  if (t == 0) { int a = 0; for (int i = 0; i < 16; ++i) { int x = ws[i]; ws[i] = a; a += x; } }
  __syncthreads();
  int run = ws[w] + v - sum;
  for (int i = 0; i < per; ++i) {
    int idx = s0 + i;
    if (idx < n) { base[idx] = run; run += cnt[idx]; }
  }
}

__global__ __launch_bounds__(256) void place_edges(const int* __restrict__ src, const int* __restrict__ dst,
    const int* __restrict__ base, int* __restrict__ cur,
    int* __restrict__ dst_s, int* __restrict__ perm)
{
  int e = blockIdx.x * 256 + threadIdx.x;
  if (e >= NE) return;
  int s = src[e];
  int p = base[s] + atomicAdd(&cur[s], 1);
  dst_s[p] = dst[e]; perm[p] = e;
}

// permute edge_attr into sorted order AND convert to bf16 ([NE][16] ushort)
__global__ __launch_bounds__(256) void permute_ea_bf(const float4* __restrict__ ea,
    const int* __restrict__ perm, ushort* __restrict__ ea_s)
{
  int i = blockIdx.x * 256 + threadIdx.x;
  if (i >= NE * 4) return;
  int e = i >> 2, q = i & 3;
  float4 v = ea[(size_t)perm[e] * 4 + q];
  uint2 p;
  p.x = (uint)f2bf(v.x) | ((uint)f2bf(v.y) << 16);
  p.y = (uint)f2bf(v.z) | ((uint)f2bf(v.w) << 16);
  *(uint2*)&ea_s[(size_t)e * 16 + q * 4] = p;
}

// ---------------- weight conversion ----------------
__global__ __launch_bounds__(256) void cvt4(const float* __restrict__ s0, const float* __restrict__ s1,
    const float* __restrict__ s2, const float* __restrict__ s3, ushort* __restrict__ d)
{
  int i = blockIdx.x * 256 + threadIdx.x;
  if (i >= 65536) return;
  const float* s = (i < 16384) ? s0 : (i < 32768) ? s1 : (i < 49152) ? s2 : s3;
  d[i] = f2bf(s[i & 16383]);
}
__global__ __launch_bounds__(256) void cvt_wab(const float* __restrict__ s, ushort* __restrict__ d)
{
  int i = blockIdx.x * 256 + threadIdx.x;
  if (i >= 131072) return;
  int l = i >> 15, rem = i & 32767;
  int r = rem >> 7, c = rem & 127;
  int srow = r & 127, scol = ((r >> 7) << 7) + c;
  d[l * 104448 + r * 128 + c] = f2bf(s[(size_t)l * 34816 + srow * 272 + scol]);
}
__global__ __launch_bounds__(256) void cvt_std(const float* __restrict__ s, ushort* __restrict__ d,
    int rows, int cols, int lss)
{
  int i = blockIdx.x * 256 + threadIdx.x;
  int n = 4 * rows * cols;
  if (i >= n) return;
  int rc = rows * cols;
  int l = i / rc, rem = i - l * rc;
  d[l * 104448 + rem] = f2bf(s[(size_t)l * lss + rem]);
}

// ---------------- fold: W2N = N1b @ W2 (bf16), N1a (bf16), nv = N1b @ b2 (fp32) ----------------
__global__ __launch_bounds__(128) void fold_w(const float* __restrict__ nw1,
    const float* __restrict__ ew2, const float* __restrict__ eb2,
    ushort* __restrict__ wu_base, float* __restrict__ nv)
{
  __shared__ float red[2];
  int bid = blockIdx.x;
  int l = bid >> 7, m = bid & 127;
  int j = threadIdx.x;
  const float* n1row = nw1 + (size_t)l * 32768 + (size_t)m * 256;
  const float* n1b = n1row + 128;
  const float* w2 = ew2 + (size_t)l * 16384;
  float s = 0.f;
  for (int k = 0; k < 128; ++k) s = fmaf(n1b[k], w2[k * 128 + j], s);
  ushort* lb = wu_base + (size_t)l * 104448;
  lb[32768 + m * 128 + j] = f2bf(s);          // W2N
  lb[49152 + m * 128 + j] = f2bf(n1row[j]);   // N1a
  float p = n1b[j] * eb2[l * 128 + j];
  #pragma unroll
  for (int mm = 1; mm < 64; mm <<= 1) p += __shfl_xor(p, mm, 64);
  if ((j & 63) == 0) red[j >> 6] = p;
  __syncthreads();
  if (j == 0) nv[l * 128 + m] = red[0] + red[1];
}

// ---------------- fused 2-layer MLP, optional pab tail ----------------
// C2 = silu(A@W1^T + b1) @ W2^T + b2.
// FUSE=0: write C2 to C.  FUSE=1: hn=LN(C2) -> Hn; Pa=hn@Wa^T+eb1, Pb=hn@Wb^T (h never stored).
template<int FUSE>
__global__ __launch_bounds__(256) void emb2(
    const float* __restrict__ A,
    const ushort* __restrict__ W1, const float* __restrict__ b1,
    const ushort* __restrict__ W2, const float* __restrict__ b2,
    const float* __restrict__ lg, const float* __restrict__ lbp,
    const ushort* __restrict__ Wab, const float* __restrict__ eb1,
    float* __restrict__ Hn, float* __restrict__ Pa, float* __restrict__ Pb,
    float* __restrict__ C, int n)
{
  __shared__ ushort Al[64][136];
  const int tid = threadIdx.x;
  const int n0 = blockIdx.x * 64;

  #pragma unroll
  for (int i = 0; i < 8; ++i) {
    int s = tid + i * 256;
    int row = s >> 5, c4 = (s & 31) * 4;
    int gr = n0 + row;
    float4 v = make_float4(0.f, 0.f, 0.f, 0.f);
    if (gr < n) v = *(const float4*)(A + (size_t)gr * HID + c4);
    uint2 p;
    p.x = (uint)f2bf(v.x) | ((uint)f2bf(v.y) << 16);
    p.y = (uint)f2bf(v.z) | ((uint)f2bf(v.w) << 16);
    *(uint2*)&Al[row][c4] = p;
  }
  __syncthreads();

  const int w = tid >> 6, l = tid & 63;
  const int lr = l & 15, lh = l >> 4;

  f32x4 zf = {0.f, 0.f, 0.f, 0.f};
  f32x4 acc[8];
  #pragma unroll
  for (int nt = 0; nt < 8; ++nt) acc[nt] = zf;

  #pragma unroll
  for (int q = 0; q < 4; ++q) {
    short8 af = *(const short8*)&Al[w * 16 + lr][q * 32 + lh * 8];
    #pragma unroll
    for (int nt = 0; nt < 8; ++nt) {
      short8 bf = *(const short8*)(W1 + (size_t)(nt * 16 + lr) * HID + q * 32 + lh * 8);
      acc[nt] = __builtin_amdgcn_mfma_f32_16x16x32_bf16(af, bf, acc[nt], 0, 0, 0);
    }
  }

  float vb[8];
  #pragma unroll
  for (int nt = 0; nt < 8; ++nt) vb[nt] = b1[nt * 16 + lr];

  #pragma unroll
  for (int r = 0; r < 4; ++r) {
    int row = w * 16 + lh * 4 + r;
    #pragma unroll
    for (int nt = 0; nt < 8; ++nt)
      Al[row][nt * 16 + lr] = f2bf(silu_f(acc[nt][r] + vb[nt]));
  }

  f32x4 acc2[8];
  #pragma unroll
  for (int nt = 0; nt < 8; ++nt) acc2[nt] = zf;
  #pragma unroll
  for (int q = 0; q < 4; ++q) {
    short8 af = *(const short8*)&Al[w * 16 + lr][q * 32 + lh * 8];
    #pragma unroll
    for (int nt = 0; nt < 8; ++nt) {
      short8 bf = *(const short8*)(W2 + (size_t)(nt * 16 + lr) * HID + q * 32 + lh * 8);
      acc2[nt] = __builtin_amdgcn_mfma_f32_16x16x32_bf16(af, bf, acc2[nt], 0, 0, 0);
    }
  }

  float vb2[8];
  #pragma unroll
  for (int nt = 0; nt < 8; ++nt) vb2[nt] = b2[nt * 16 + lr];

  if (FUSE == 0) {
    #pragma unroll
    for (int r = 0; r < 4; ++r) {
      int row = n0 + w * 16 + lh * 4 + r;
      if (row < n) {
        float* cr = C + (size_t)row * HID;
        #pragma unroll
        for (int nt = 0; nt < 8; ++nt)
          cr[nt * 16 + lr] = acc2[nt][r] + vb2[nt];
      }
    }
    return;
  }

  // --- FUSE: LN + write Hn + bf16 hn back into Al (wave-private rows) ---
  float gv[8], bv[8];
  #pragma unroll
  for (int nt = 0; nt < 8; ++nt) { gv[nt] = lg[nt * 16 + lr]; bv[nt] = lbp[nt * 16 + lr]; }

  #pragma unroll
  for (int r = 0; r < 4; ++r) {
    int row = n0 + w * 16 + lh * 4 + r;
    bool ok = row < n;
    float vals[8];
    #pragma unroll
    for (int nt = 0; nt < 8; ++nt) vals[nt] = acc2[nt][r] + vb2[nt];
    float s1 = 0.f, s2 = 0.f;
    #pragma unroll
    for (int nt = 0; nt < 8; ++nt) { s1 += vals[nt]; s2 += vals[nt] * vals[nt]; }
    #pragma unroll
    for (int m = 1; m < 16; m <<= 1) { s1 += __shfl_xor(s1, m, 64); s2 += __shfl_xor(s2, m, 64); }
    float mu = s1 * (1.0f / 128.0f);
    float var = s2 * (1.0f / 128.0f) - mu * mu;
    float rs = rsqrtf(var + 1e-5f);
    int lrow = w * 16 + lh * 4 + r;
    float* hnr = Hn + (size_t)row * HID;
    #pragma unroll
    for (int nt = 0; nt < 8; ++nt) {
      float hn = (vals[nt] - mu) * rs * gv[nt] + bv[nt];
      if (ok) hnr[nt * 16 + lr] = hn;
      Al[lrow][nt * 16 + lr] = f2bf(hn);
    }
  }

  // --- pab GEMM: Pa/Pb = hn @ Wab^T ---
  f32x4 aab[16];
  #pragma unroll
  for (int nt = 0; nt < 16; ++nt) aab[nt] = zf;
  #pragma unroll
  for (int q = 0; q < 4; ++q) {
    short8 af = *(const short8*)&Al[w * 16 + lr][q * 32 + lh * 8];
    #pragma unroll
    for (int nt = 0; nt < 16; ++nt) {
      short8 bf = *(const short8*)(Wab + (size_t)(nt * 16 + lr) * HID + q * 32 + lh * 8);
      aab[nt] = __builtin_amdgcn_mfma_f32_16x16x32_bf16(af, bf, aab[nt], 0, 0, 0);
    }
  }
  float be[8];
  #pragma unroll
  for (int nt = 0; nt < 8; ++nt) be[nt] = eb1[nt * 16 + lr];
  #pragma unroll
  for (int r = 0; r < 4; ++r) {
    int row = n0 + w * 16 + lh * 4 + r;
    if (row >= n) break;
    float* pa = Pa + (size_t)row * HID;
    float* pb = Pb + (size_t)row * HID;
    #pragma unroll
    for (int nt = 0; nt < 8; ++nt) {
      int col = nt * 16 + lr;
      pa[col] = aab[nt][r] + be[nt];
      pb[col] = aab[nt + 8][r];
    }
  }
}

// ---------------- per-node CSR edge kernel (R9-proven): one wave = one node, 2 edges/iter pipeline ----------------
__global__ __launch_bounds__(256) void node_edge(
    const float* __restrict__ Pa, const float* __restrict__ Pb,
    const ushort* __restrict__ ea_bf,
    const int* __restrict__ dst_s,
    const int* __restrict__ ebase, const int* __restrict__ deg,
    const float* __restrict__ w1c,
    const float* __restrict__ elg, const float* __restrict__ elb,
    float* __restrict__ S, int n)
{
  const int tid = threadIdx.x;
  const int wv = __builtin_amdgcn_readfirstlane(tid >> 6);
  const int lane = tid & 63;
  const int node = blockIdx.x * 4 + wv;
  if (node >= n) return;
  const int c0 = lane * 2;

  float w10[16], w11[16];
  {
    const float* wr0 = w1c + (size_t)c0 * 272 + 256;
    const float* wr1 = wr0 + 272;
    #pragma unroll
    for (int q = 0; q < 4; ++q) {
      float4 a = *(const float4*)(wr0 + q * 4);
      float4 b = *(const float4*)(wr1 + q * 4);
      w10[q * 4 + 0] = a.x; w10[q * 4 + 1] = a.y; w10[q * 4 + 2] = a.z; w10[q * 4 + 3] = a.w;
      w11[q * 4 + 0] = b.x; w11[q * 4 + 1] = b.y; w11[q * 4 + 2] = b.z; w11[q * 4 + 3] = b.w;
    }
  }
  const float g0 = elg[c0], g1 = elg[c0 + 1];
  const float b0 = elb[c0], b1 = elb[c0 + 1];
  const float pax = Pa[(size_t)node * HID + c0];
  const float pay = Pa[(size_t)node * HID + c0 + 1];

  const int beg = __builtin_amdgcn_readfirstlane(ebase[node]);
  const int dg  = __builtin_amdgcn_readfirstlane(deg[node]);

  float a0 = 0.f, a1 = 0.f;

  uint4 eA0 = make_uint4(0,0,0,0), eB0 = eA0, eA1 = eA0, eB1 = eA0;
  float2 p0 = make_float2(0.f, 0.f), p1 = p0;

  auto LOADE = [&](int idx, uint4& ea, uint4& eb, float2& pb) {
    int eu = __builtin_amdgcn_readfirstlane(beg + idx);
    int d  = dst_s[eu];
    ea = *(const uint4*)(ea_bf + (size_t)eu * 16);
    eb = *(const uint4*)(ea_bf + (size_t)eu * 16 + 8);
    pb = *(const float2*)(Pb + (size_t)d * HID + c0);
  };
  auto PROCESS = [&](const uint4& eaA, const uint4& eaB, const float2& pbc) {
    float ev[16];
    uint u;
    u = eaA.x; ev[0]  = __uint_as_float(u << 16); ev[1]  = __uint_as_float(u & 0xffff0000u);
    u = eaA.y; ev[2]  = __uint_as_float(u << 16); ev[3]  = __uint_as_float(u & 0xffff0000u);
    u = eaA.z; ev[4]  = __uint_as_float(u << 16); ev[5]  = __uint_as_float(u & 0xffff0000u);
    u = eaA.w; ev[6]  = __uint_as_float(u << 16); ev[7]  = __uint_as_float(u & 0xffff0000u);
    u = eaB.x; ev[8]  = __uint_as_float(u << 16); ev[9]  = __uint_as_float(u & 0xffff0000u);
    u = eaB.y; ev[10] = __uint_as_float(u << 16); ev[11] = __uint_as_float(u & 0xffff0000u);
    u = eaB.z; ev[12] = __uint_as_float(u << 16); ev[13] = __uint_as_float(u & 0xffff0000u);
    u = eaB.w; ev[14] = __uint_as_float(u << 16); ev[15] = __uint_as_float(u & 0xffff0000u);

    float x0 = pax + pbc.x;
    float x1 = pay + pbc.y;
    #pragma unroll
    for (int k = 0; k < 16; ++k) {
      x0 = fmaf(ev[k], w10[k], x0);
      x1 = fmaf(ev[k], w11[k], x1);
    }
    float s1 = x0 + x1, s2 = x0 * x0 + x1 * x1;
    #pragma unroll
    for (int m = 1; m < 64; m <<= 1) {
      s1 += __shfl_xor(s1, m, 64);
      s2 += __shfl_xor(s2, m, 64);
    }
    float mu = s1 * (1.0f / 128.0f);
    float var = s2 * (1.0f / 128.0f) - mu * mu;
    float rs = rsqrtf(var + 1e-5f);
    a0 += silu_f((x0 - mu) * rs * g0 + b0);
    a1 += silu_f((x1 - mu) * rs * g1 + b1);
  };

  if (dg > 0) LOADE(0, eA0, eB0, p0);
  if (dg > 1) LOADE(1, eA1, eB1, p1);

  for (int i = 0; i < dg; i += 2) {
    uint4 nA0 = make_uint4(0,0,0,0), nB0 = nA0, nA1 = nA0, nB1 = nA0;
    float2 np0 = make_float2(0.f, 0.f), np1 = np0;
    if (i + 2 < dg) LOADE(i + 2, nA0, nB0, np0);
    if (i + 3 < dg) LOADE(i + 3, nA1, nB1, np1);

    PROCESS(eA0, eB0, p0);
    if (i + 1 < dg) PROCESS(eA1, eB1, p1);

    eA0 = nA0; eB0 = nB0; p0 = np0;
    eA1 = nA1; eB1 = nB1; p1 = np1;
  }

  *(float2*)(S + (size_t)node * HID + c0) = make_float2(a0, a1);
}

// ---------------- fused node MLP (+ optional next-layer pab) ----------------
// h' = hn + (silu(LN(hn@N1a^T + S@W2N^T + deg*nv + nb1)))@N2^T + nb2
// FUSE=0: write h' to C.  FUSE=1: hn' = LN(h') -> Hn (in place); Pa/Pb = hn'@Wab2^T (+eb1_2); h' not stored.
template<int FUSE>
__global__ __launch_bounds__(256) void node_mlp(
    const float* __restrict__ Hn, const float* __restrict__ S,
    const ushort* __restrict__ N1a, const ushort* __restrict__ W2N, const ushort* __restrict__ N2,
    const float* __restrict__ nb1, const float* __restrict__ nv, const int* __restrict__ deg,
    const float* __restrict__ lng, const float* __restrict__ lnb, const float* __restrict__ nb2,
    const float* __restrict__ lg2, const float* __restrict__ lb2p,
    const ushort* __restrict__ Wab2, const float* __restrict__ eb1_2,
    float* __restrict__ HnOut, float* __restrict__ Pa, float* __restrict__ Pb,
    float* __restrict__ C, int n)
{
  __shared__ ushort Ahn[64][136];
  __shared__ ushort Ah[64][136];
  __shared__ ushort Alo[64][136];
  const int tid = threadIdx.x;
  const int n0 = blockIdx.x * 64;

  #pragma unroll
  for (int i = 0; i < 8; ++i) {
    int s = tid + i * 256;
    int row = s >> 5, c4 = (s & 31) * 4;
    int gr = n0 + row;
    float4 vh = make_float4(0.f, 0.f, 0.f, 0.f);
    float4 vs = make_float4(0.f, 0.f, 0.f, 0.f);
    if (gr < n) {
      vh = *(const float4*)(Hn + (size_t)gr * HID + c4);
      vs = *(const float4*)(S + (size_t)gr * HID + c4);
    }
    uint2 ph;
    ph.x = (uint)f2bf(vh.x) | ((uint)f2bf(vh.y) << 16);
    ph.y = (uint)f2bf(vh.z) | ((uint)f2bf(vh.w) << 16);
    *(uint2*)&Ahn[row][c4] = ph;
    ushort hx = f2bf(vs.x), hy = f2bf(vs.y), hz = f2bf(vs.z), hw = f2bf(vs.w);
    uint2 ps, pl;
    ps.x = (uint)hx | ((uint)hy << 16);
    ps.y = (uint)hz | ((uint)hw << 16);
    pl.x = (uint)f2bf(vs.x - bf2f(hx)) | ((uint)f2bf(vs.y - bf2f(hy)) << 16);
    pl.y = (uint)f2bf(vs.z - bf2f(hz)) | ((uint)f2bf(vs.w - bf2f(hw)) << 16);
    *(uint2*)&Ah[row][c4]  = ps;
    *(uint2*)&Alo[row][c4] = pl;
  }
  __syncthreads();

  const int w = tid >> 6, l = tid & 63;
  const int lr = l & 15, lh = l >> 4;

  f32x4 zf = {0.f, 0.f, 0.f, 0.f};
  f32x4 acc[8];
  #pragma unroll
  for (int nt = 0; nt < 8; ++nt) acc[nt] = zf;

  #pragma unroll
  for (int q = 0; q < 4; ++q) {
    short8 an = *(const short8*)&Ahn[w * 16 + lr][q * 32 + lh * 8];
    short8 ah = *(const short8*)&Ah[w * 16 + lr][q * 32 + lh * 8];
    short8 al = *(const short8*)&Alo[w * 16 + lr][q * 32 + lh * 8];
    #pragma unroll
    for (int nt = 0; nt < 8; ++nt) {
      short8 b1f = *(const short8*)(N1a + (size_t)(nt * 16 + lr) * HID + q * 32 + lh * 8);
      short8 b2f = *(const short8*)(W2N + (size_t)(nt * 16 + lr) * HID + q * 32 + lh * 8);
      acc[nt] = __builtin_amdgcn_mfma_f32_16x16x32_bf16(an, b1f, acc[nt], 0, 0, 0);
      acc[nt] = __builtin_amdgcn_mfma_f32_16x16x32_bf16(ah, b2f, acc[nt], 0, 0, 0);
      acc[nt] = __builtin_amdgcn_mfma_f32_16x16x32_bf16(al, b2f, acc[nt], 0, 0, 0);
    }
  }

  float vb[8], vn[8], gv[8], bv[8];
  #pragma unroll
  for (int nt = 0; nt < 8; ++nt) {
    int col = nt * 16 + lr;
    vb[nt] = nb1[col]; vn[nt] = nv[col];
    gv[nt] = lng[col]; bv[nt] = lnb[col];
  }

  #pragma unroll
  for (int r = 0; r < 4; ++r) {
    int row = n0 + w * 16 + lh * 4 + r;
    float degf = (row < n) ? (float)deg[row] : 0.f;
    float vals[8];
    #pragma unroll
    for (int nt = 0; nt < 8; ++nt) vals[nt] = acc[nt][r] + vb[nt] + degf * vn[nt];
    float s1 = 0.f, s2 = 0.f;
    #pragma unroll
    for (int nt = 0; nt < 8; ++nt) { s1 += vals[nt]; s2 += vals[nt] * vals[nt]; }
    #pragma unroll
    for (int m = 1; m < 16; m <<= 1) { s1 += __shfl_xor(s1, m, 64); s2 += __shfl_xor(s2, m, 64); }
    float mu = s1 * (1.0f / 128.0f);
    float var = s2 * (1.0f / 128.0f) - mu * mu;
    float rs = rsqrtf(var + 1e-5f);
    int lrow = w * 16 + lh * 4 + r;
    #pragma unroll
    for (int nt = 0; nt < 8; ++nt)
      Ahn[lrow][nt * 16 + lr] = f2bf(silu_f((vals[nt] - mu) * rs * gv[nt] + bv[nt]));
  }

  f32x4 acc2[8];
  #pragma unroll
  for (int nt = 0; nt < 8; ++nt) acc2[nt] = zf;
  #pragma unroll
  for (int q = 0; q < 4; ++q) {
    short8 af = *(const short8*)&Ahn[w * 16 + lr][q * 32 + lh * 8];
    #pragma unroll
    for (int nt = 0; nt < 8; ++nt) {
      short8 bf = *(const short8*)(N2 + (size_t)(nt * 16 + lr) * HID + q * 32 + lh * 8);
      acc2[nt] = __builtin_amdgcn_mfma_f32_16x16x32_bf16(af, bf, acc2[nt], 0, 0, 0);
    }
  }

  float vb2[8];
  #pragma unroll
  for (int nt = 0; nt < 8; ++nt) vb2[nt] = nb2[nt * 16 + lr];

  if (FUSE == 0) {
    #pragma unroll
    for (int r = 0; r < 4; ++r) {
      int row = n0 + w * 16 + lh * 4 + r;
      if (row < n) {
        const float* hr = Hn + (size_t)row * HID;
        float* cr = C + (size_t)row * HID;
        #pragma unroll
        for (int nt = 0; nt < 8; ++nt) {
          int col = nt * 16 + lr;
          cr[col] = hr[col] + acc2[nt][r] + vb2[nt];
        }
      }
    }
    return;
  }

  // --- FUSE: h' in regs -> LN -> Hn (in place) + bf16 into Ahn (wave-private rows) ---
  float gv2[8], bv2[8];
  #pragma unroll
  for (int nt = 0; nt < 8; ++nt) { gv2[nt] = lg2[nt * 16 + lr]; bv2[nt] = lb2p[nt * 16 + lr]; }

  #pragma unroll
  for (int r = 0; r < 4; ++r) {
    int row = n0 + w * 16 + lh * 4 + r;
    bool ok = row < n;
    const float* hr = Hn + (size_t)row * HID;
    float vals[8];
    #pragma unroll
    for (int nt = 0; nt < 8; ++nt) {
      int col = nt * 16 + lr;
      float base = ok ? hr[col] : 0.f;
      vals[nt] = base + acc2[nt][r] + vb2[nt];
    }
    float s1 = 0.f, s2 = 0.f;
    #pragma unroll
    for (int nt = 0; nt < 8; ++nt) { s1 += vals[nt]; s2 += vals[nt] * vals[nt]; }
    #pragma unroll
    for (int m = 1; m < 16; m <<= 1) { s1 += __shfl_xor(s1, m, 64); s2 += __shfl_xor(s2, m, 64); }
    float mu = s1 * (1.0f / 128.0f);
    float var = s2 * (1.0f / 128.0f) - mu * mu;
    float rs = rsqrtf(var + 1e-5f);
    int lrow = w * 16 + lh * 4 + r;
    float* hnr = HnOut + (size_t)row * HID;
    #pragma unroll
    for (int nt = 0; nt < 8; ++nt) {
      float hn = (vals[nt] - mu) * rs * gv2[nt] + bv2[nt];
      if (ok) hnr[nt * 16 + lr] = hn;
      Ahn[lrow][nt * 16 + lr] = f2bf(hn);
    }
  }

  // --- pab GEMM for next layer ---
  f32x4 aab[16];
  #pragma unroll
  for (int nt = 0; nt < 16; ++nt) aab[nt] = zf;
  #pragma unroll
  for (int q = 0; q < 4; ++q) {
    short8 af = *(const short8*)&Ahn[w * 16 + lr][q * 32 + lh * 8];
    #pragma unroll
    for (int nt = 0; nt < 16; ++nt) {
      short8 bf = *(const short8*)(Wab2 + (size_t)(nt * 16 + lr) * HID + q * 32 + lh * 8);
      aab[nt] = __builtin_amdgcn_mfma_f32_16x16x32_bf16(af, bf, aab[nt], 0, 0, 0);
    }
  }
  float be[8];
  #pragma unroll
  for (int nt = 0; nt < 8; ++nt) be[nt] = eb1_2[nt * 16 + lr];
  #pragma unroll
  for (int r = 0; r < 4; ++r) {
    int row = n0 + w * 16 + lh * 4 + r;
    if (row >= n) break;
    float* pa = Pa + (size_t)row * HID;
    float* pb = Pb + (size_t)row * HID;
    #pragma unroll
    for (int nt = 0; nt < 8; ++nt) {
      int col = nt * 16 + lr;
      pa[col] = aab[nt][r] + be[nt];
      pb[col] = aab[nt + 8][r];
    }
  }
}

extern "C" void kernel_launch(void* const* d_in, const int* in_sizes, int n_in,
                              void* d_out, int out_size, void* d_ws, size_t ws_size,
                              hipStream_t stream)
{
  const float* in_h  = (const float*)d_in[0];
  const int*   edges = (const int*)d_in[1];
  const float* ea    = (const float*)d_in[2];
  const float* ei_w1 = (const float*)d_in[3];
  const float* ei_b1 = (const float*)d_in[4];
  const float* ei_w2 = (const float*)d_in[5];
  const float* ei_b2 = (const float*)d_in[6];
  const float* ng    = (const float*)d_in[7];
  const float* nbp   = (const float*)d_in[8];
  const float* ew1   = (const float*)d_in[9];
  const float* eb1   = (const float*)d_in[10];
  const float* elg   = (const float*)d_in[11];
  const float* elb   = (const float*)d_in[12];
  const float* ew2   = (const float*)d_in[13];
  const float* eb2   = (const float*)d_in[14];
  const float* nw1   = (const float*)d_in[15];
  const float* nb1   = (const float*)d_in[16];
  const float* nlg   = (const float*)d_in[17];
  const float* nlb   = (const float*)d_in[18];
  const float* nw2   = (const float*)d_in[19];
  const float* nb2   = (const float*)d_in[20];
  const float* eo_w1 = (const float*)d_in[21];
  const float* eo_b1 = (const float*)d_in[22];
  const float* eo_w2 = (const float*)d_in[23];
  const float* eo_b2 = (const float*)d_in[24];

  float* wf    = (float*)d_ws;
  float* B_h   = wf;
  float* B_hn  = wf + NNH;
  float* B_S   = wf + 2 * NNH;   // S (edge-sum); perm alias during setup
  float* B_tmp = wf + 3 * NNH;   // Pa
  float* B_pb  = wf + 4 * NNH;   // Pb

  const size_t WOFF = 5 * NNH;
  ushort* wu = (ushort*)(wf + WOFF);
  // ei1@0, ei2@16384, eo1@32768, eo2@49152; per-layer base 65536 + l*104448:
  //   Wab@0 [256][128] | W2N@32768 | N1a@49152 | N2@81920
  const size_t SOFF = WOFF + 262144;
  int* dst_s = (int*)(wf + SOFF);
  int* cnt   = dst_s + NE;       // = deg
  int* cur   = cnt + NPAD;
  int* base  = cur + NPAD;
  ushort* ea_s = (ushort*)(base + NPAD);
  float* nvb = (float*)(ea_s + (size_t)NE * 16);   // 4*128 fp32
  int* perm  = (int*)B_S;

  const int NB  = (NN + 63) / 64;
  const int NBE = (NN + 3) / 4;
  const int NEB = (NE + 255) / 256;

  const int* erow = edges;
  const int* ecol = edges + NE;

  // ---- counting sort by src (once) ----
  zero_i<<<(2 * NPAD + 255) / 256, 256, 0, stream>>>(cnt, 2 * NPAD);
  count_src<<<NEB, 256, 0, stream>>>(erow, cnt);
  scan_excl<<<1, 1024, 0, stream>>>(cnt, base, NN);
  place_edges<<<NEB, 256, 0, stream>>>(erow, ecol, base, cur, dst_s, perm);
  permute_ea_bf<<<(NE * 4 + 255) / 256, 256, 0, stream>>>((const float4*)ea, perm, ea_s);

  // ---- weight conversion / folding ----
  cvt4<<<256, 256, 0, stream>>>(ei_w1, ei_w2, eo_w1, eo_w2, wu);
  cvt_wab<<<512, 256, 0, stream>>>(ew1, wu + 65536);
  cvt_std<<<(4 * 16384 + 255) / 256, 256, 0, stream>>>(nw2, wu + 65536 + 81920, 128, 128, 16384);
  fold_w<<<512, 128, 0, stream>>>(nw1, ew2, eb2, wu + 65536, nvb);

  // ---- embedding_in fused with layer-0 pab_ln (h0 never materialized) ----
  emb2<1><<<NB, 256, 0, stream>>>(in_h, wu, ei_b1, wu + 16384, ei_b2,
      ng, nbp, wu + 65536, eb1, B_hn, B_tmp, B_pb, nullptr, NN);

  for (int lyr = 0; lyr < 4; ++lyr) {
    ushort* lb = wu + 65536 + lyr * 104448;
    node_edge<<<NBE, 256, 0, stream>>>(B_tmp, B_pb, ea_s, dst_s, base, cnt,
        ew1 + 34816 * lyr, elg + 128 * lyr, elb + 128 * lyr, B_S, NN);
    if (lyr < 3) {
      ushort* lb2 = lb + 104448;
      node_mlp<1><<<NB, 256, 0, stream>>>(B_hn, B_S, lb + 49152, lb + 32768, lb + 81920,
          nb1 + 128 * lyr, nvb + 128 * lyr, cnt,
          nlg + 128 * lyr, nlb + 128 * lyr, nb2 + 128 * lyr,
          ng + 128 * (lyr + 1), nbp + 128 * (lyr + 1), lb2, eb1 + 128 * (lyr + 1),
          B_hn, B_tmp, B_pb, nullptr, NN);
    } else {
      node_mlp<0><<<NB, 256, 0, stream>>>(B_hn, B_S, lb + 49152, lb + 32768, lb + 81920,
          nb1 + 128 * lyr, nvb + 128 * lyr, cnt,
          nlg + 128 * lyr, nlb + 128 * lyr, nb2 + 128 * lyr,
          nullptr, nullptr, nullptr, nullptr,
          nullptr, nullptr, nullptr, B_h, NN);
    }
  }

  // ---- embedding_out ----
  emb2<0><<<NB, 256, 0, stream>>>(B_h, wu + 32768, eo_b1, wu + 49152, eo_b2,
      nullptr, nullptr, nullptr, nullptr, nullptr, nullptr, nullptr, (float*)d_out, NN);
}

// Round 12
// 1307.231 us; speedup vs baseline: 1.2720x; 1.0211x over previous
//
#include <hip/hip_runtime.h>
#include <math.h>

#define NN 50000
#define NE 800000
#define HID 128
#define NNH ((size_t)NN * HID)
#define NPAD 50176

typedef __attribute__((ext_vector_type(8))) short short8;
typedef __attribute__((ext_vector_type(4))) float f32x4;
typedef __attribute__((ext_vector_type(2))) _Float16 half2v;

__device__ __forceinline__ ushort f2bf(float f) {
  unsigned u = __float_as_uint(f);
  unsigned r = (u + 0x7fffu + ((u >> 16) & 1u)) >> 16;
  return (ushort)r;
}
__device__ __forceinline__ float bf2f(ushort h) {
  return __uint_as_float(((unsigned)h) << 16);
}
__device__ __forceinline__ ushort f2h_bits(float f) {
  _Float16 h = (_Float16)f;
  ushort u;
  __builtin_memcpy(&u, &h, 2);
  return u;
}
__device__ __forceinline__ half2v u2h(uint u) {
  half2v h;
  __builtin_memcpy(&h, &u, 4);
  return h;
}
__device__ __forceinline__ float silu_f(float x) { return x / (1.0f + __expf(-x)); }

// ---------------- utility ----------------
__global__ __launch_bounds__(256) void zero_i(int* __restrict__ p, int n)
{
  int i = blockIdx.x * 256 + threadIdx.x;
  if (i < n) p[i] = 0;
}

// ---------------- counting sort of edges by src ----------------
__global__ __launch_bounds__(256) void count_src(const int* __restrict__ src, int* __restrict__ cnt)
{
  int e = blockIdx.x * 256 + threadIdx.x;
  if (e < NE) atomicAdd(&cnt[src[e]], 1);
}

__global__ __launch_bounds__(1024) void scan_excl(const int* __restrict__ cnt, int* __restrict__ base, int n)
{
  __shared__ int ws[16];
  int t = threadIdx.x;
  const int per = (n + 1023) / 1024;
  int s0 = t * per;
  int sum = 0;
  for (int i = 0; i < per; ++i) { int idx = s0 + i; if (idx < n) sum += cnt[idx]; }
  int lane = t & 63, w = t >> 6;
  int v = sum;
  #pragma unroll
  for (int m = 1; m < 64; m <<= 1) { int o = __shfl_up(v, m, 64); if (lane >= m) v += o; }
  if (lane == 63) ws[w] = v;
  __syncthreads();
  if (t == 0) { int a = 0; for (int i = 0; i < 16; ++i) { int x = ws[i]; ws[i] = a; a += x; } }
  __syncthreads();
  int run = ws[w] + v - sum;
  for (int i = 0; i < per; ++i) {
    int idx = s0 + i;
    if (idx < n) { base[idx] = run; run += cnt[idx]; }
  }
}

__global__ __launch_bounds__(256) void place_edges(const int* __restrict__ src, const int* __restrict__ dst,
    const int* __restrict__ base, int* __restrict__ cur,
    int* __restrict__ dst_s, int* __restrict__ perm)
{
  int e = blockIdx.x * 256 + threadIdx.x;
  if (e >= NE) return;
  int s = src[e];
  int p = base[s] + atomicAdd(&cur[s], 1);
  dst_s[p] = dst[e]; perm[p] = e;
}

// permute edge_attr into sorted order AND convert to f16 ([NE][16] ushort = f16 bits)
__global__ __launch_bounds__(256) void permute_ea_h(const float4* __restrict__ ea,
    const int* __restrict__ perm, ushort* __restrict__ ea_s)
{
  int i = blockIdx.x * 256 + threadIdx.x;
  if (i >= NE * 4) return;
  int e = i >> 2, q = i & 3;
  float4 v = ea[(size_t)perm[e] * 4 + q];
  uint2 p;
  p.x = (uint)f2h_bits(v.x) | ((uint)f2h_bits(v.y) << 16);
  p.y = (uint)f2h_bits(v.z) | ((uint)f2h_bits(v.w) << 16);
  *(uint2*)&ea_s[(size_t)e * 16 + q * 4] = p;
}

// ---------------- weight conversion ----------------
__global__ __launch_bounds__(256) void cvt4(const float* __restrict__ s0, const float* __restrict__ s1,
    const float* __restrict__ s2, const float* __restrict__ s3, ushort* __restrict__ d)
{
  int i = blockIdx.x * 256 + threadIdx.x;
  if (i >= 65536) return;
  const float* s = (i < 16384) ? s0 : (i < 32768) ? s1 : (i < 49152) ? s2 : s3;
  d[i] = f2bf(s[i & 16383]);
}
__global__ __launch_bounds__(256) void cvt_wab(const float* __restrict__ s, ushort* __restrict__ d)
{
  int i = blockIdx.x * 256 + threadIdx.x;
  if (i >= 131072) return;
  int l = i >> 15, rem = i & 32767;
  int r = rem >> 7, c = rem & 127;
  int srow = r & 127, scol = ((r >> 7) << 7) + c;
  d[l * 104448 + r * 128 + c] = f2bf(s[(size_t)l * 34816 + srow * 272 + scol]);
}
__global__ __launch_bounds__(256) void cvt_std(const float* __restrict__ s, ushort* __restrict__ d,
    int rows, int cols, int lss)
{
  int i = blockIdx.x * 256 + threadIdx.x;
  int n = 4 * rows * cols;
  if (i >= n) return;
  int rc = rows * cols;
  int l = i / rc, rem = i - l * rc;
  d[l * 104448 + rem] = f2bf(s[(size_t)l * lss + rem]);
}

// ---------------- fold: W2N = N1b @ W2 (bf16), N1a (bf16), nv = N1b @ b2 (fp32) ----------------
__global__ __launch_bounds__(128) void fold_w(const float* __restrict__ nw1,
    const float* __restrict__ ew2, const float* __restrict__ eb2,
    ushort* __restrict__ wu_base, float* __restrict__ nv)
{
  __shared__ float red[2];
  int bid = blockIdx.x;
  int l = bid >> 7, m = bid & 127;
  int j = threadIdx.x;
  const float* n1row = nw1 + (size_t)l * 32768 + (size_t)m * 256;
  const float* n1b = n1row + 128;
  const float* w2 = ew2 + (size_t)l * 16384;
  float s = 0.f;
  for (int k = 0; k < 128; ++k) s = fmaf(n1b[k], w2[k * 128 + j], s);
  ushort* lb = wu_base + (size_t)l * 104448;
  lb[32768 + m * 128 + j] = f2bf(s);          // W2N
  lb[49152 + m * 128 + j] = f2bf(n1row[j]);   // N1a
  float p = n1b[j] * eb2[l * 128 + j];
  #pragma unroll
  for (int mm = 1; mm < 64; mm <<= 1) p += __shfl_xor(p, mm, 64);
  if ((j & 63) == 0) red[j >> 6] = p;
  __syncthreads();
  if (j == 0) nv[l * 128 + m] = red[0] + red[1];
}

// ---------------- fused 2-layer MLP, optional pab tail ----------------
template<int FUSE>
__global__ __launch_bounds__(256) void emb2(
    const float* __restrict__ A,
    const ushort* __restrict__ W1, const float* __restrict__ b1,
    const ushort* __restrict__ W2, const float* __restrict__ b2,
    const float* __restrict__ lg, const float* __restrict__ lbp,
    const ushort* __restrict__ Wab, const float* __restrict__ eb1,
    float* __restrict__ Hn, float* __restrict__ Pa, float* __restrict__ Pb,
    float* __restrict__ C, int n)
{
  __shared__ ushort Al[64][136];
  const int tid = threadIdx.x;
  const int n0 = blockIdx.x * 64;

  #pragma unroll
  for (int i = 0; i < 8; ++i) {
    int s = tid + i * 256;
    int row = s >> 5, c4 = (s & 31) * 4;
    int gr = n0 + row;
    float4 v = make_float4(0.f, 0.f, 0.f, 0.f);
    if (gr < n) v = *(const float4*)(A + (size_t)gr * HID + c4);
    uint2 p;
    p.x = (uint)f2bf(v.x) | ((uint)f2bf(v.y) << 16);
    p.y = (uint)f2bf(v.z) | ((uint)f2bf(v.w) << 16);
    *(uint2*)&Al[row][c4] = p;
  }
  __syncthreads();

  const int w = tid >> 6, l = tid & 63;
  const int lr = l & 15, lh = l >> 4;

  f32x4 zf = {0.f, 0.f, 0.f, 0.f};
  f32x4 acc[8];
  #pragma unroll
  for (int nt = 0; nt < 8; ++nt) acc[nt] = zf;

  #pragma unroll
  for (int q = 0; q < 4; ++q) {
    short8 af = *(const short8*)&Al[w * 16 + lr][q * 32 + lh * 8];
    #pragma unroll
    for (int nt = 0; nt < 8; ++nt) {
      short8 bf = *(const short8*)(W1 + (size_t)(nt * 16 + lr) * HID + q * 32 + lh * 8);
      acc[nt] = __builtin_amdgcn_mfma_f32_16x16x32_bf16(af, bf, acc[nt], 0, 0, 0);
    }
  }

  float vb[8];
  #pragma unroll
  for (int nt = 0; nt < 8; ++nt) vb[nt] = b1[nt * 16 + lr];

  #pragma unroll
  for (int r = 0; r < 4; ++r) {
    int row = w * 16 + lh * 4 + r;
    #pragma unroll
    for (int nt = 0; nt < 8; ++nt)
      Al[row][nt * 16 + lr] = f2bf(silu_f(acc[nt][r] + vb[nt]));
  }

  f32x4 acc2[8];
  #pragma unroll
  for (int nt = 0; nt < 8; ++nt) acc2[nt] = zf;
  #pragma unroll
  for (int q = 0; q < 4; ++q) {
    short8 af = *(const short8*)&Al[w * 16 + lr][q * 32 + lh * 8];
    #pragma unroll
    for (int nt = 0; nt < 8; ++nt) {
      short8 bf = *(const short8*)(W2 + (size_t)(nt * 16 + lr) * HID + q * 32 + lh * 8);
      acc2[nt] = __builtin_amdgcn_mfma_f32_16x16x32_bf16(af, bf, acc2[nt], 0, 0, 0);
    }
  }

  float vb2[8];
  #pragma unroll
  for (int nt = 0; nt < 8; ++nt) vb2[nt] = b2[nt * 16 + lr];

  if (FUSE == 0) {
    #pragma unroll
    for (int r = 0; r < 4; ++r) {
      int row = n0 + w * 16 + lh * 4 + r;
      if (row < n) {
        float* cr = C + (size_t)row * HID;
        #pragma unroll
        for (int nt = 0; nt < 8; ++nt)
          cr[nt * 16 + lr] = acc2[nt][r] + vb2[nt];
      }
    }
    return;
  }

  float gv[8], bv[8];
  #pragma unroll
  for (int nt = 0; nt < 8; ++nt) { gv[nt] = lg[nt * 16 + lr]; bv[nt] = lbp[nt * 16 + lr]; }

  #pragma unroll
  for (int r = 0; r < 4; ++r) {
    int row = n0 + w * 16 + lh * 4 + r;
    bool ok = row < n;
    float vals[8];
    #pragma unroll
    for (int nt = 0; nt < 8; ++nt) vals[nt] = acc2[nt][r] + vb2[nt];
    float s1 = 0.f, s2 = 0.f;
    #pragma unroll
    for (int nt = 0; nt < 8; ++nt) { s1 += vals[nt]; s2 += vals[nt] * vals[nt]; }
    #pragma unroll
    for (int m = 1; m < 16; m <<= 1) { s1 += __shfl_xor(s1, m, 64); s2 += __shfl_xor(s2, m, 64); }
    float mu = s1 * (1.0f / 128.0f);
    float var = s2 * (1.0f / 128.0f) - mu * mu;
    float rs = rsqrtf(var + 1e-5f);
    int lrow = w * 16 + lh * 4 + r;
    float* hnr = Hn + (size_t)row * HID;
    #pragma unroll
    for (int nt = 0; nt < 8; ++nt) {
      float hn = (vals[nt] - mu) * rs * gv[nt] + bv[nt];
      if (ok) hnr[nt * 16 + lr] = hn;
      Al[lrow][nt * 16 + lr] = f2bf(hn);
    }
  }

  f32x4 aab[16];
  #pragma unroll
  for (int nt = 0; nt < 16; ++nt) aab[nt] = zf;
  #pragma unroll
  for (int q = 0; q < 4; ++q) {
    short8 af = *(const short8*)&Al[w * 16 + lr][q * 32 + lh * 8];
    #pragma unroll
    for (int nt = 0; nt < 16; ++nt) {
      short8 bf = *(const short8*)(Wab + (size_t)(nt * 16 + lr) * HID + q * 32 + lh * 8);
      aab[nt] = __builtin_amdgcn_mfma_f32_16x16x32_bf16(af, bf, aab[nt], 0, 0, 0);
    }
  }
  float be[8];
  #pragma unroll
  for (int nt = 0; nt < 8; ++nt) be[nt] = eb1[nt * 16 + lr];
  #pragma unroll
  for (int r = 0; r < 4; ++r) {
    int row = n0 + w * 16 + lh * 4 + r;
    if (row >= n) break;
    float* pa = Pa + (size_t)row * HID;
    float* pb = Pb + (size_t)row * HID;
    #pragma unroll
    for (int nt = 0; nt < 8; ++nt) {
      int col = nt * 16 + lr;
      pa[col] = aab[nt][r] + be[nt];
      pb[col] = aab[nt + 8][r];
    }
  }
}

// ---------------- per-node CSR edge kernel: R9 structure + fdot2 inner matvec ----------------
__global__ __launch_bounds__(256) void node_edge(
    const float* __restrict__ Pa, const float* __restrict__ Pb,
    const ushort* __restrict__ ea_h,     // f16 bits, [NE][16]
    const int* __restrict__ dst_s,
    const int* __restrict__ ebase, const int* __restrict__ deg,
    const float* __restrict__ w1c,
    const float* __restrict__ elg, const float* __restrict__ elb,
    float* __restrict__ S, int n)
{
  const int tid = threadIdx.x;
  const int wv = __builtin_amdgcn_readfirstlane(tid >> 6);
  const int lane = tid & 63;
  const int node = blockIdx.x * 4 + wv;
  if (node >= n) return;
  const int c0 = lane * 2;

  // W1c rows c0, c0+1 as packed f16 pairs (16 VGPRs)
  half2v w1h0[8], w1h1[8];
  {
    const float* wr0 = w1c + (size_t)c0 * 272 + 256;
    const float* wr1 = wr0 + 272;
    #pragma unroll
    for (int k = 0; k < 8; ++k) {
      half2v h0; h0[0] = (_Float16)wr0[2 * k]; h0[1] = (_Float16)wr0[2 * k + 1]; w1h0[k] = h0;
      half2v h1; h1[0] = (_Float16)wr1[2 * k]; h1[1] = (_Float16)wr1[2 * k + 1]; w1h1[k] = h1;
    }
  }
  const float g0 = elg[c0], g1 = elg[c0 + 1];
  const float b0 = elb[c0], b1 = elb[c0 + 1];
  const float pax = Pa[(size_t)node * HID + c0];
  const float pay = Pa[(size_t)node * HID + c0 + 1];

  const int beg = __builtin_amdgcn_readfirstlane(ebase[node]);
  const int dg  = __builtin_amdgcn_readfirstlane(deg[node]);

  float a0 = 0.f, a1 = 0.f;

  uint4 eA0 = make_uint4(0,0,0,0), eB0 = eA0, eA1 = eA0, eB1 = eA0;
  float2 p0 = make_float2(0.f, 0.f), p1 = p0;

  auto LOADE = [&](int idx, uint4& ea, uint4& eb, float2& pb) {
    int eu = __builtin_amdgcn_readfirstlane(beg + idx);
    int d  = dst_s[eu];
    ea = *(const uint4*)(ea_h + (size_t)eu * 16);
    eb = *(const uint4*)(ea_h + (size_t)eu * 16 + 8);
    pb = *(const float2*)(Pb + (size_t)d * HID + c0);
  };
  auto PROCESS = [&](const uint4& eaA, const uint4& eaB, const float2& pbc) {
    half2v eh[8];
    eh[0] = u2h(eaA.x); eh[1] = u2h(eaA.y); eh[2] = u2h(eaA.z); eh[3] = u2h(eaA.w);
    eh[4] = u2h(eaB.x); eh[5] = u2h(eaB.y); eh[6] = u2h(eaB.z); eh[7] = u2h(eaB.w);

    float x0 = pax + pbc.x;
    float x1 = pay + pbc.y;
    #pragma unroll
    for (int k = 0; k < 8; ++k) {
      x0 = __builtin_amdgcn_fdot2(eh[k], w1h0[k], x0, false);
      x1 = __builtin_amdgcn_fdot2(eh[k], w1h1[k], x1, false);
    }
    float s1 = x0 + x1, s2 = x0 * x0 + x1 * x1;
    #pragma unroll
    for (int m = 1; m < 64; m <<= 1) {
      s1 += __shfl_xor(s1, m, 64);
      s2 += __shfl_xor(s2, m, 64);
    }
    float mu = s1 * (1.0f / 128.0f);
    float var = s2 * (1.0f / 128.0f) - mu * mu;
    float rs = rsqrtf(var + 1e-5f);
    a0 += silu_f((x0 - mu) * rs * g0 + b0);
    a1 += silu_f((x1 - mu) * rs * g1 + b1);
  };

  if (dg > 0) LOADE(0, eA0, eB0, p0);
  if (dg > 1) LOADE(1, eA1, eB1, p1);

  for (int i = 0; i < dg; i += 2) {
    uint4 nA0 = make_uint4(0,0,0,0), nB0 = nA0, nA1 = nA0, nB1 = nA0;
    float2 np0 = make_float2(0.f, 0.f), np1 = np0;
    if (i + 2 < dg) LOADE(i + 2, nA0, nB0, np0);
    if (i + 3 < dg) LOADE(i + 3, nA1, nB1, np1);

    PROCESS(eA0, eB0, p0);
    if (i + 1 < dg) PROCESS(eA1, eB1, p1);

    eA0 = nA0; eB0 = nB0; p0 = np0;
    eA1 = nA1; eB1 = nB1; p1 = np1;
  }

  *(float2*)(S + (size_t)node * HID + c0) = make_float2(a0, a1);
}

// ---------------- fused node MLP (+ optional next-layer pab) ----------------
template<int FUSE>
__global__ __launch_bounds__(256) void node_mlp(
    const float* __restrict__ Hn, const float* __restrict__ S,
    const ushort* __restrict__ N1a, const ushort* __restrict__ W2N, const ushort* __restrict__ N2,
    const float* __restrict__ nb1, const float* __restrict__ nv, const int* __restrict__ deg,
    const float* __restrict__ lng, const float* __restrict__ lnb, const float* __restrict__ nb2,
    const float* __restrict__ lg2, const float* __restrict__ lb2p,
    const ushort* __restrict__ Wab2, const float* __restrict__ eb1_2,
    float* __restrict__ HnOut, float* __restrict__ Pa, float* __restrict__ Pb,
    float* __restrict__ C, int n)
{
  __shared__ ushort Ahn[64][136];
  __shared__ ushort Ah[64][136];
  __shared__ ushort Alo[64][136];
  const int tid = threadIdx.x;
  const int n0 = blockIdx.x * 64;

  #pragma unroll
  for (int i = 0; i < 8; ++i) {
    int s = tid + i * 256;
    int row = s >> 5, c4 = (s & 31) * 4;
    int gr = n0 + row;
    float4 vh = make_float4(0.f, 0.f, 0.f, 0.f);
    float4 vs = make_float4(0.f, 0.f, 0.f, 0.f);
    if (gr < n) {
      vh = *(const float4*)(Hn + (size_t)gr * HID + c4);
      vs = *(const float4*)(S + (size_t)gr * HID + c4);
    }
    uint2 ph;
    ph.x = (uint)f2bf(vh.x) | ((uint)f2bf(vh.y) << 16);
    ph.y = (uint)f2bf(vh.z) | ((uint)f2bf(vh.w) << 16);
    *(uint2*)&Ahn[row][c4] = ph;
    ushort hx = f2bf(vs.x), hy = f2bf(vs.y), hz = f2bf(vs.z), hw = f2bf(vs.w);
    uint2 ps, pl;
    ps.x = (uint)hx | ((uint)hy << 16);
    ps.y = (uint)hz | ((uint)hw << 16);
    pl.x = (uint)f2bf(vs.x - bf2f(hx)) | ((uint)f2bf(vs.y - bf2f(hy)) << 16);
    pl.y = (uint)f2bf(vs.z - bf2f(hz)) | ((uint)f2bf(vs.w - bf2f(hw)) << 16);
    *(uint2*)&Ah[row][c4]  = ps;
    *(uint2*)&Alo[row][c4] = pl;
  }
  __syncthreads();

  const int w = tid >> 6, l = tid & 63;
  const int lr = l & 15, lh = l >> 4;

  f32x4 zf = {0.f, 0.f, 0.f, 0.f};
  f32x4 acc[8];
  #pragma unroll
  for (int nt = 0; nt < 8; ++nt) acc[nt] = zf;

  #pragma unroll
  for (int q = 0; q < 4; ++q) {
    short8 an = *(const short8*)&Ahn[w * 16 + lr][q * 32 + lh * 8];
    short8 ah = *(const short8*)&Ah[w * 16 + lr][q * 32 + lh * 8];
    short8 al = *(const short8*)&Alo[w * 16 + lr][q * 32 + lh * 8];
    #pragma unroll
    for (int nt = 0; nt < 8; ++nt) {
      short8 b1f = *(const short8*)(N1a + (size_t)(nt * 16 + lr) * HID + q * 32 + lh * 8);
      short8 b2f = *(const short8*)(W2N + (size_t)(nt * 16 + lr) * HID + q * 32 + lh * 8);
      acc[nt] = __builtin_amdgcn_mfma_f32_16x16x32_bf16(an, b1f, acc[nt], 0, 0, 0);
      acc[nt] = __builtin_amdgcn_mfma_f32_16x16x32_bf16(ah, b2f, acc[nt], 0, 0, 0);
      acc[nt] = __builtin_amdgcn_mfma_f32_16x16x32_bf16(al, b2f, acc[nt], 0, 0, 0);
    }
  }

  float vb[8], vn[8], gv[8], bv[8];
  #pragma unroll
  for (int nt = 0; nt < 8; ++nt) {
    int col = nt * 16 + lr;
    vb[nt] = nb1[col]; vn[nt] = nv[col];
    gv[nt] = lng[col]; bv[nt] = lnb[col];
  }

  #pragma unroll
  for (int r = 0; r < 4; ++r) {
    int row = n0 + w * 16 + lh * 4 + r;
    float degf = (row < n) ? (float)deg[row] : 0.f;
    float vals[8];
    #pragma unroll
    for (int nt = 0; nt < 8; ++nt) vals[nt] = acc[nt][r] + vb[nt] + degf * vn[nt];
    float s1 = 0.f, s2 = 0.f;
    #pragma unroll
    for (int nt = 0; nt < 8; ++nt) { s1 += vals[nt]; s2 += vals[nt] * vals[nt]; }
    #pragma unroll
    for (int m = 1; m < 16; m <<= 1) { s1 += __shfl_xor(s1, m, 64); s2 += __shfl_xor(s2, m, 64); }
    float mu = s1 * (1.0f / 128.0f);
    float var = s2 * (1.0f / 128.0f) - mu * mu;
    float rs = rsqrtf(var + 1e-5f);
    int lrow = w * 16 + lh * 4 + r;
    #pragma unroll
    for (int nt = 0; nt < 8; ++nt)
      Ahn[lrow][nt * 16 + lr] = f2bf(silu_f((vals[nt] - mu) * rs * gv[nt] + bv[nt]));
  }

  f32x4 acc2[8];
  #pragma unroll
  for (int nt = 0; nt < 8; ++nt) acc2[nt] = zf;
  #pragma unroll
  for (int q = 0; q < 4; ++q) {
    short8 af = *(const short8*)&Ahn[w * 16 + lr][q * 32 + lh * 8];
    #pragma unroll
    for (int nt = 0; nt < 8; ++nt) {
      short8 bf = *(const short8*)(N2 + (size_t)(nt * 16 + lr) * HID + q * 32 + lh * 8);
      acc2[nt] = __builtin_amdgcn_mfma_f32_16x16x32_bf16(af, bf, acc2[nt], 0, 0, 0);
    }
  }

  float vb2[8];
  #pragma unroll
  for (int nt = 0; nt < 8; ++nt) vb2[nt] = nb2[nt * 16 + lr];

  if (FUSE == 0) {
    #pragma unroll
    for (int r = 0; r < 4; ++r) {
      int row = n0 + w * 16 + lh * 4 + r;
      if (row < n) {
        const float* hr = Hn + (size_t)row * HID;
        float* cr = C + (size_t)row * HID;
        #pragma unroll
        for (int nt = 0; nt < 8; ++nt) {
          int col = nt * 16 + lr;
          cr[col] = hr[col] + acc2[nt][r] + vb2[nt];
        }
      }
    }
    return;
  }

  float gv2[8], bv2[8];
  #pragma unroll
  for (int nt = 0; nt < 8; ++nt) { gv2[nt] = lg2[nt * 16 + lr]; bv2[nt] = lb2p[nt * 16 + lr]; }

  #pragma unroll
  for (int r = 0; r < 4; ++r) {
    int row = n0 + w * 16 + lh * 4 + r;
    bool ok = row < n;
    const float* hr = Hn + (size_t)row * HID;
    float vals[8];
    #pragma unroll
    for (int nt = 0; nt < 8; ++nt) {
      int col = nt * 16 + lr;
      float base = ok ? hr[col] : 0.f;
      vals[nt] = base + acc2[nt][r] + vb2[nt];
    }
    float s1 = 0.f, s2 = 0.f;
    #pragma unroll
    for (int nt = 0; nt < 8; ++nt) { s1 += vals[nt]; s2 += vals[nt] * vals[nt]; }
    #pragma unroll
    for (int m = 1; m < 16; m <<= 1) { s1 += __shfl_xor(s1, m, 64); s2 += __shfl_xor(s2, m, 64); }
    float mu = s1 * (1.0f / 128.0f);
    float var = s2 * (1.0f / 128.0f) - mu * mu;
    float rs = rsqrtf(var + 1e-5f);
    int lrow = w * 16 + lh * 4 + r;
    float* hnr = HnOut + (size_t)row * HID;
    #pragma unroll
    for (int nt = 0; nt < 8; ++nt) {
      float hn = (vals[nt] - mu) * rs * gv2[nt] + bv2[nt];
      if (ok) hnr[nt * 16 + lr] = hn;
      Ahn[lrow][nt * 16 + lr] = f2bf(hn);
    }
  }

  f32x4 aab[16];
  #pragma unroll
  for (int nt = 0; nt < 16; ++nt) aab[nt] = zf;
  #pragma unroll
  for (int q = 0; q < 4; ++q) {
    short8 af = *(const short8*)&Ahn[w * 16 + lr][q * 32 + lh * 8];
    #pragma unroll
    for (int nt = 0; nt < 16; ++nt) {
      short8 bf = *(const short8*)(Wab2 + (size_t)(nt * 16 + lr) * HID + q * 32 + lh * 8);
      aab[nt] = __builtin_amdgcn_mfma_f32_16x16x32_bf16(af, bf, aab[nt], 0, 0, 0);
    }
  }
  float be[8];
  #pragma unroll
  for (int nt = 0; nt < 8; ++nt) be[nt] = eb1_2[nt * 16 + lr];
  #pragma unroll
  for (int r = 0; r < 4; ++r) {
    int row = n0 + w * 16 + lh * 4 + r;
    if (row >= n) break;
    float* pa = Pa + (size_t)row * HID;
    float* pb = Pb + (size_t)row * HID;
    #pragma unroll
    for (int nt = 0; nt < 8; ++nt) {
      int col = nt * 16 + lr;
      pa[col] = aab[nt][r] + be[nt];
      pb[col] = aab[nt + 8][r];
    }
  }
}

extern "C" void kernel_launch(void* const* d_in, const int* in_sizes, int n_in,
                              void* d_out, int out_size, void* d_ws, size_t ws_size,
                              hipStream_t stream)
{
  const float* in_h  = (const float*)d_in[0];
  const int*   edges = (const int*)d_in[1];
  const float* ea    = (const float*)d_in[2];
  const float* ei_w1 = (const float*)d_in[3];
  const float* ei_b1 = (const float*)d_in[4];
  const float* ei_w2 = (const float*)d_in[5];
  const float* ei_b2 = (const float*)d_in[6];
  const float* ng    = (const float*)d_in[7];
  const float* nbp   = (const float*)d_in[8];
  const float* ew1   = (const float*)d_in[9];
  const float* eb1   = (const float*)d_in[10];
  const float* elg   = (const float*)d_in[11];
  const float* elb   = (const float*)d_in[12];
  const float* ew2   = (const float*)d_in[13];
  const float* eb2   = (const float*)d_in[14];
  const float* nw1   = (const float*)d_in[15];
  const float* nb1   = (const float*)d_in[16];
  const float* nlg   = (const float*)d_in[17];
  const float* nlb   = (const float*)d_in[18];
  const float* nw2   = (const float*)d_in[19];
  const float* nb2   = (const float*)d_in[20];
  const float* eo_w1 = (const float*)d_in[21];
  const float* eo_b1 = (const float*)d_in[22];
  const float* eo_w2 = (const float*)d_in[23];
  const float* eo_b2 = (const float*)d_in[24];

  float* wf    = (float*)d_ws;
  float* B_h   = wf;
  float* B_hn  = wf + NNH;
  float* B_S   = wf + 2 * NNH;   // S (edge-sum); perm alias during setup
  float* B_tmp = wf + 3 * NNH;   // Pa
  float* B_pb  = wf + 4 * NNH;   // Pb

  const size_t WOFF = 5 * NNH;
  ushort* wu = (ushort*)(wf + WOFF);
  // ei1@0, ei2@16384, eo1@32768, eo2@49152; per-layer base 65536 + l*104448:
  //   Wab@0 [256][128] | W2N@32768 | N1a@49152 | N2@81920
  const size_t SOFF = WOFF + 262144;
  int* dst_s = (int*)(wf + SOFF);
  int* cnt   = dst_s + NE;       // = deg
  int* cur   = cnt + NPAD;
  int* base  = cur + NPAD;
  ushort* ea_s = (ushort*)(base + NPAD);
  float* nvb = (float*)(ea_s + (size_t)NE * 16);   // 4*128 fp32
  int* perm  = (int*)B_S;

  const int NB  = (NN + 63) / 64;
  const int NBE = (NN + 3) / 4;
  const int NEB = (NE + 255) / 256;

  const int* erow = edges;
  const int* ecol = edges + NE;

  // ---- counting sort by src (once) ----
  zero_i<<<(2 * NPAD + 255) / 256, 256, 0, stream>>>(cnt, 2 * NPAD);
  count_src<<<NEB, 256, 0, stream>>>(erow, cnt);
  scan_excl<<<1, 1024, 0, stream>>>(cnt, base, NN);
  place_edges<<<NEB, 256, 0, stream>>>(erow, ecol, base, cur, dst_s, perm);
  permute_ea_h<<<(NE * 4 + 255) / 256, 256, 0, stream>>>((const float4*)ea, perm, ea_s);

  // ---- weight conversion / folding ----
  cvt4<<<256, 256, 0, stream>>>(ei_w1, ei_w2, eo_w1, eo_w2, wu);
  cvt_wab<<<512, 256, 0, stream>>>(ew1, wu + 65536);
  cvt_std<<<(4 * 16384 + 255) / 256, 256, 0, stream>>>(nw2, wu + 65536 + 81920, 128, 128, 16384);
  fold_w<<<512, 128, 0, stream>>>(nw1, ew2, eb2, wu + 65536, nvb);

  // ---- embedding_in fused with layer-0 pab_ln (h0 never materialized) ----
  emb2<1><<<NB, 256, 0, stream>>>(in_h, wu, ei_b1, wu + 16384, ei_b2,
      ng, nbp, wu + 65536, eb1, B_hn, B_tmp, B_pb, nullptr, NN);

  for (int lyr = 0; lyr < 4; ++lyr) {
    ushort* lb = wu + 65536 + lyr * 104448;
    node_edge<<<NBE, 256, 0, stream>>>(B_tmp, B_pb, ea_s, dst_s, base, cnt,
        ew1 + 34816 * lyr, elg + 128 * lyr, elb + 128 * lyr, B_S, NN);
    if (lyr < 3) {
      ushort* lb2 = lb + 104448;
      node_mlp<1><<<NB, 256, 0, stream>>>(B_hn, B_S, lb + 49152, lb + 32768, lb + 81920,
          nb1 + 128 * lyr, nvb + 128 * lyr, cnt,
          nlg + 128 * lyr, nlb + 128 * lyr, nb2 + 128 * lyr,
          ng + 128 * (lyr + 1), nbp + 128 * (lyr + 1), lb2, eb1 + 128 * (lyr + 1),
          B_hn, B_tmp, B_pb, nullptr, NN);
    } else {
      node_mlp<0><<<NB, 256, 0, stream>>>(B_hn, B_S, lb + 49152, lb + 32768, lb + 81920,
          nb1 + 128 * lyr, nvb + 128 * lyr, cnt,
          nlg + 128 * lyr, nlb + 128 * lyr, nb2 + 128 * lyr,
          nullptr, nullptr, nullptr, nullptr,
          nullptr, nullptr, nullptr, B_h, NN);
    }
  }

  // ---- embedding_out ----
  emb2<0><<<NB, 256, 0, stream>>>(B_h, wu + 32768, eo_b1, wu + 49152, eo_b2,
      nullptr, nullptr, nullptr, nullptr, nullptr, nullptr, nullptr, (float*)d_out, NN);
}

// Round 13
// 1237.315 us; speedup vs baseline: 1.3439x; 1.0565x over previous
//
#include <hip/hip_runtime.h>
#include <math.h>

#define NN 50000
#define NE 800000
#define HID 128
#define NNH ((size_t)NN * HID)
#define NPAD 50176

typedef __attribute__((ext_vector_type(8))) short short8;
typedef __attribute__((ext_vector_type(4))) float f32x4;
typedef __attribute__((ext_vector_type(2))) _Float16 half2v;

__device__ __forceinline__ ushort f2bf(float f) {
  unsigned u = __float_as_uint(f);
  unsigned r = (u + 0x7fffu + ((u >> 16) & 1u)) >> 16;
  return (ushort)r;
}
__device__ __forceinline__ float bf2f(ushort h) {
  return __uint_as_float(((unsigned)h) << 16);
}
__device__ __forceinline__ ushort f2h_bits(float f) {
  _Float16 h = (_Float16)f;
  ushort u;
  __builtin_memcpy(&u, &h, 2);
  return u;
}
__device__ __forceinline__ half2v u2h(uint u) {
  half2v h;
  __builtin_memcpy(&h, &u, 4);
  return h;
}
__device__ __forceinline__ float silu_f(float x) { return x / (1.0f + __expf(-x)); }

// Full-wave (64-lane) sum via DPP adds (no LDS-pipe swizzles); result broadcast via readlane.
// row_shr:1/2/4/8 accumulate within each row of 16; row_bcast:15/31 combine rows; total in lane 63.
__device__ __forceinline__ float wsum64(float x) {
  int t;
  t = __builtin_amdgcn_update_dpp(0, __float_as_int(x), 0x111, 0xf, 0xf, true); x += __int_as_float(t);
  t = __builtin_amdgcn_update_dpp(0, __float_as_int(x), 0x112, 0xf, 0xf, true); x += __int_as_float(t);
  t = __builtin_amdgcn_update_dpp(0, __float_as_int(x), 0x114, 0xf, 0xf, true); x += __int_as_float(t);
  t = __builtin_amdgcn_update_dpp(0, __float_as_int(x), 0x118, 0xf, 0xf, true); x += __int_as_float(t);
  t = __builtin_amdgcn_update_dpp(0, __float_as_int(x), 0x142, 0xf, 0xf, true); x += __int_as_float(t);
  t = __builtin_amdgcn_update_dpp(0, __float_as_int(x), 0x143, 0xf, 0xf, true); x += __int_as_float(t);
  return __uint_as_float(__builtin_amdgcn_readlane(__float_as_int(x), 63));
}

// ---------------- utility ----------------
__global__ __launch_bounds__(256) void zero_i(int* __restrict__ p, int n)
{
  int i = blockIdx.x * 256 + threadIdx.x;
  if (i < n) p[i] = 0;
}

// ---------------- counting sort of edges by src ----------------
__global__ __launch_bounds__(256) void count_src(const int* __restrict__ src, int* __restrict__ cnt)
{
  int e = blockIdx.x * 256 + threadIdx.x;
  if (e < NE) atomicAdd(&cnt[src[e]], 1);
}

__global__ __launch_bounds__(1024) void scan_excl(const int* __restrict__ cnt, int* __restrict__ base, int n)
{
  __shared__ int ws[16];
  int t = threadIdx.x;
  const int per = (n + 1023) / 1024;
  int s0 = t * per;
  int sum = 0;
  for (int i = 0; i < per; ++i) { int idx = s0 + i; if (idx < n) sum += cnt[idx]; }
  int lane = t & 63, w = t >> 6;
  int v = sum;
  #pragma unroll
  for (int m = 1; m < 64; m <<= 1) { int o = __shfl_up(v, m, 64); if (lane >= m) v += o; }
  if (lane == 63) ws[w] = v;
  __syncthreads();
  if (t == 0) { int a = 0; for (int i = 0; i < 16; ++i) { int x = ws[i]; ws[i] = a; a += x; } }
  __syncthreads();
  int run = ws[w] + v - sum;
  for (int i = 0; i < per; ++i) {
    int idx = s0 + i;
    if (idx < n) { base[idx] = run; run += cnt[idx]; }
  }
}

__global__ __launch_bounds__(256) void place_edges(const int* __restrict__ src, const int* __restrict__ dst,
    const int* __restrict__ base, int* __restrict__ cur,
    int* __restrict__ dst_s, int* __restrict__ perm)
{
  int e = blockIdx.x * 256 + threadIdx.x;
  if (e >= NE) return;
  int s = src[e];
  int p = base[s] + atomicAdd(&cur[s], 1);
  dst_s[p] = dst[e]; perm[p] = e;
}

// permute edge_attr into sorted order AND convert to f16 ([NE][16] ushort = f16 bits)
__global__ __launch_bounds__(256) void permute_ea_h(const float4* __restrict__ ea,
    const int* __restrict__ perm, ushort* __restrict__ ea_s)
{
  int i = blockIdx.x * 256 + threadIdx.x;
  if (i >= NE * 4) return;
  int e = i >> 2, q = i & 3;
  float4 v = ea[(size_t)perm[e] * 4 + q];
  uint2 p;
  p.x = (uint)f2h_bits(v.x) | ((uint)f2h_bits(v.y) << 16);
  p.y = (uint)f2h_bits(v.z) | ((uint)f2h_bits(v.w) << 16);
  *(uint2*)&ea_s[(size_t)e * 16 + q * 4] = p;
}

// ---------------- weight conversion ----------------
__global__ __launch_bounds__(256) void cvt4(const float* __restrict__ s0, const float* __restrict__ s1,
    const float* __restrict__ s2, const float* __restrict__ s3, ushort* __restrict__ d)
{
  int i = blockIdx.x * 256 + threadIdx.x;
  if (i >= 65536) return;
  const float* s = (i < 16384) ? s0 : (i < 32768) ? s1 : (i < 49152) ? s2 : s3;
  d[i] = f2bf(s[i & 16383]);
}
__global__ __launch_bounds__(256) void cvt_wab(const float* __restrict__ s, ushort* __restrict__ d)
{
  int i = blockIdx.x * 256 + threadIdx.x;
  if (i >= 131072) return;
  int l = i >> 15, rem = i & 32767;
  int r = rem >> 7, c = rem & 127;
  int srow = r & 127, scol = ((r >> 7) << 7) + c;
  d[l * 104448 + r * 128 + c] = f2bf(s[(size_t)l * 34816 + srow * 272 + scol]);
}
__global__ __launch_bounds__(256) void cvt_std(const float* __restrict__ s, ushort* __restrict__ d,
    int rows, int cols, int lss)
{
  int i = blockIdx.x * 256 + threadIdx.x;
  int n = 4 * rows * cols;
  if (i >= n) return;
  int rc = rows * cols;
  int l = i / rc, rem = i - l * rc;
  d[l * 104448 + rem] = f2bf(s[(size_t)l * lss + rem]);
}

// ---------------- fold: W2N = N1b @ W2 (bf16), N1a (bf16), nv = N1b @ b2 (fp32) ----------------
__global__ __launch_bounds__(128) void fold_w(const float* __restrict__ nw1,
    const float* __restrict__ ew2, const float* __restrict__ eb2,
    ushort* __restrict__ wu_base, float* __restrict__ nv)
{
  __shared__ float red[2];
  int bid = blockIdx.x;
  int l = bid >> 7, m = bid & 127;
  int j = threadIdx.x;
  const float* n1row = nw1 + (size_t)l * 32768 + (size_t)m * 256;
  const float* n1b = n1row + 128;
  const float* w2 = ew2 + (size_t)l * 16384;
  float s = 0.f;
  for (int k = 0; k < 128; ++k) s = fmaf(n1b[k], w2[k * 128 + j], s);
  ushort* lb = wu_base + (size_t)l * 104448;
  lb[32768 + m * 128 + j] = f2bf(s);          // W2N
  lb[49152 + m * 128 + j] = f2bf(n1row[j]);   // N1a
  float p = n1b[j] * eb2[l * 128 + j];
  #pragma unroll
  for (int mm = 1; mm < 64; mm <<= 1) p += __shfl_xor(p, mm, 64);
  if ((j & 63) == 0) red[j >> 6] = p;
  __syncthreads();
  if (j == 0) nv[l * 128 + m] = red[0] + red[1];
}

// ---------------- fused 2-layer MLP, optional pab tail ----------------
template<int FUSE>
__global__ __launch_bounds__(256) void emb2(
    const float* __restrict__ A,
    const ushort* __restrict__ W1, const float* __restrict__ b1,
    const ushort* __restrict__ W2, const float* __restrict__ b2,
    const float* __restrict__ lg, const float* __restrict__ lbp,
    const ushort* __restrict__ Wab, const float* __restrict__ eb1,
    float* __restrict__ Hn, float* __restrict__ Pa, float* __restrict__ Pb,
    float* __restrict__ C, int n)
{
  __shared__ ushort Al[64][136];
  const int tid = threadIdx.x;
  const int n0 = blockIdx.x * 64;

  #pragma unroll
  for (int i = 0; i < 8; ++i) {
    int s = tid + i * 256;
    int row = s >> 5, c4 = (s & 31) * 4;
    int gr = n0 + row;
    float4 v = make_float4(0.f, 0.f, 0.f, 0.f);
    if (gr < n) v = *(const float4*)(A + (size_t)gr * HID + c4);
    uint2 p;
    p.x = (uint)f2bf(v.x) | ((uint)f2bf(v.y) << 16);
    p.y = (uint)f2bf(v.z) | ((uint)f2bf(v.w) << 16);
    *(uint2*)&Al[row][c4] = p;
  }
  __syncthreads();

  const int w = tid >> 6, l = tid & 63;
  const int lr = l & 15, lh = l >> 4;

  f32x4 zf = {0.f, 0.f, 0.f, 0.f};
  f32x4 acc[8];
  #pragma unroll
  for (int nt = 0; nt < 8; ++nt) acc[nt] = zf;

  #pragma unroll
  for (int q = 0; q < 4; ++q) {
    short8 af = *(const short8*)&Al[w * 16 + lr][q * 32 + lh * 8];
    #pragma unroll
    for (int nt = 0; nt < 8; ++nt) {
      short8 bf = *(const short8*)(W1 + (size_t)(nt * 16 + lr) * HID + q * 32 + lh * 8);
      acc[nt] = __builtin_amdgcn_mfma_f32_16x16x32_bf16(af, bf, acc[nt], 0, 0, 0);
    }
  }

  float vb[8];
  #pragma unroll
  for (int nt = 0; nt < 8; ++nt) vb[nt] = b1[nt * 16 + lr];

  #pragma unroll
  for (int r = 0; r < 4; ++r) {
    int row = w * 16 + lh * 4 + r;
    #pragma unroll
    for (int nt = 0; nt < 8; ++nt)
      Al[row][nt * 16 + lr] = f2bf(silu_f(acc[nt][r] + vb[nt]));
  }

  f32x4 acc2[8];
  #pragma unroll
  for (int nt = 0; nt < 8; ++nt) acc2[nt] = zf;
  #pragma unroll
  for (int q = 0; q < 4; ++q) {
    short8 af = *(const short8*)&Al[w * 16 + lr][q * 32 + lh * 8];
    #pragma unroll
    for (int nt = 0; nt < 8; ++nt) {
      short8 bf = *(const short8*)(W2 + (size_t)(nt * 16 + lr) * HID + q * 32 + lh * 8);
      acc2[nt] = __builtin_amdgcn_mfma_f32_16x16x32_bf16(af, bf, acc2[nt], 0, 0, 0);
    }
  }

  float vb2[8];
  #pragma unroll
  for (int nt = 0; nt < 8; ++nt) vb2[nt] = b2[nt * 16 + lr];

  if (FUSE == 0) {
    #pragma unroll
    for (int r = 0; r < 4; ++r) {
      int row = n0 + w * 16 + lh * 4 + r;
      if (row < n) {
        float* cr = C + (size_t)row * HID;
        #pragma unroll
        for (int nt = 0; nt < 8; ++nt)
          cr[nt * 16 + lr] = acc2[nt][r] + vb2[nt];
      }
    }
    return;
  }

  float gv[8], bv[8];
  #pragma unroll
  for (int nt = 0; nt < 8; ++nt) { gv[nt] = lg[nt * 16 + lr]; bv[nt] = lbp[nt * 16 + lr]; }

  #pragma unroll
  for (int r = 0; r < 4; ++r) {
    int row = n0 + w * 16 + lh * 4 + r;
    bool ok = row < n;
    float vals[8];
    #pragma unroll
    for (int nt = 0; nt < 8; ++nt) vals[nt] = acc2[nt][r] + vb2[nt];
    float s1 = 0.f, s2 = 0.f;
    #pragma unroll
    for (int nt = 0; nt < 8; ++nt) { s1 += vals[nt]; s2 += vals[nt] * vals[nt]; }
    #pragma unroll
    for (int m = 1; m < 16; m <<= 1) { s1 += __shfl_xor(s1, m, 64); s2 += __shfl_xor(s2, m, 64); }
    float mu = s1 * (1.0f / 128.0f);
    float var = s2 * (1.0f / 128.0f) - mu * mu;
    float rs = rsqrtf(var + 1e-5f);
    int lrow = w * 16 + lh * 4 + r;
    float* hnr = Hn + (size_t)row * HID;
    #pragma unroll
    for (int nt = 0; nt < 8; ++nt) {
      float hn = (vals[nt] - mu) * rs * gv[nt] + bv[nt];
      if (ok) hnr[nt * 16 + lr] = hn;
      Al[lrow][nt * 16 + lr] = f2bf(hn);
    }
  }

  f32x4 aab[16];
  #pragma unroll
  for (int nt = 0; nt < 16; ++nt) aab[nt] = zf;
  #pragma unroll
  for (int q = 0; q < 4; ++q) {
    short8 af = *(const short8*)&Al[w * 16 + lr][q * 32 + lh * 8];
    #pragma unroll
    for (int nt = 0; nt < 16; ++nt) {
      short8 bf = *(const short8*)(Wab + (size_t)(nt * 16 + lr) * HID + q * 32 + lh * 8);
      aab[nt] = __builtin_amdgcn_mfma_f32_16x16x32_bf16(af, bf, aab[nt], 0, 0, 0);
    }
  }
  float be[8];
  #pragma unroll
  for (int nt = 0; nt < 8; ++nt) be[nt] = eb1[nt * 16 + lr];
  #pragma unroll
  for (int r = 0; r < 4; ++r) {
    int row = n0 + w * 16 + lh * 4 + r;
    if (row >= n) break;
    float* pa = Pa + (size_t)row * HID;
    float* pb = Pb + (size_t)row * HID;
    #pragma unroll
    for (int nt = 0; nt < 8; ++nt) {
      int col = nt * 16 + lr;
      pa[col] = aab[nt][r] + be[nt];
      pb[col] = aab[nt + 8][r];
    }
  }
}

// ---------------- per-node CSR edge kernel: R9 structure + fdot2 + DPP reduce ----------------
__global__ __launch_bounds__(256) void node_edge(
    const float* __restrict__ Pa, const float* __restrict__ Pb,
    const ushort* __restrict__ ea_h,     // f16 bits, [NE][16]
    const int* __restrict__ dst_s,
    const int* __restrict__ ebase, const int* __restrict__ deg,
    const float* __restrict__ w1c,
    const float* __restrict__ elg, const float* __restrict__ elb,
    float* __restrict__ S, int n)
{
  const int tid = threadIdx.x;
  const int wv = __builtin_amdgcn_readfirstlane(tid >> 6);
  const int lane = tid & 63;
  const int node = blockIdx.x * 4 + wv;
  if (node >= n) return;
  const int c0 = lane * 2;

  half2v w1h0[8], w1h1[8];
  {
    const float* wr0 = w1c + (size_t)c0 * 272 + 256;
    const float* wr1 = wr0 + 272;
    #pragma unroll
    for (int k = 0; k < 8; ++k) {
      half2v h0; h0[0] = (_Float16)wr0[2 * k]; h0[1] = (_Float16)wr0[2 * k + 1]; w1h0[k] = h0;
      half2v h1; h1[0] = (_Float16)wr1[2 * k]; h1[1] = (_Float16)wr1[2 * k + 1]; w1h1[k] = h1;
    }
  }
  const float g0 = elg[c0], g1 = elg[c0 + 1];
  const float b0 = elb[c0], b1 = elb[c0 + 1];
  const float pax = Pa[(size_t)node * HID + c0];
  const float pay = Pa[(size_t)node * HID + c0 + 1];

  const int beg = __builtin_amdgcn_readfirstlane(ebase[node]);
  const int dg  = __builtin_amdgcn_readfirstlane(deg[node]);

  float a0 = 0.f, a1 = 0.f;

  uint4 eA0 = make_uint4(0,0,0,0), eB0 = eA0, eA1 = eA0, eB1 = eA0;
  float2 p0 = make_float2(0.f, 0.f), p1 = p0;

  auto LOADE = [&](int idx, uint4& ea, uint4& eb, float2& pb) {
    int eu = __builtin_amdgcn_readfirstlane(beg + idx);
    int d  = dst_s[eu];
    ea = *(const uint4*)(ea_h + (size_t)eu * 16);
    eb = *(const uint4*)(ea_h + (size_t)eu * 16 + 8);
    pb = *(const float2*)(Pb + (size_t)d * HID + c0);
  };
  auto PROCESS = [&](const uint4& eaA, const uint4& eaB, const float2& pbc) {
    half2v eh[8];
    eh[0] = u2h(eaA.x); eh[1] = u2h(eaA.y); eh[2] = u2h(eaA.z); eh[3] = u2h(eaA.w);
    eh[4] = u2h(eaB.x); eh[5] = u2h(eaB.y); eh[6] = u2h(eaB.z); eh[7] = u2h(eaB.w);

    float x0 = pax + pbc.x;
    float x1 = pay + pbc.y;
    #pragma unroll
    for (int k = 0; k < 8; ++k) {
      x0 = __builtin_amdgcn_fdot2(eh[k], w1h0[k], x0, false);
      x1 = __builtin_amdgcn_fdot2(eh[k], w1h1[k], x1, false);
    }
    float s1 = wsum64(x0 + x1);
    float s2 = wsum64(fmaf(x0, x0, x1 * x1));
    float mu = s1 * (1.0f / 128.0f);
    float var = s2 * (1.0f / 128.0f) - mu * mu;
    float rs = rsqrtf(var + 1e-5f);
    a0 += silu_f((x0 - mu) * rs * g0 + b0);
    a1 += silu_f((x1 - mu) * rs * g1 + b1);
  };

  if (dg > 0) LOADE(0, eA0, eB0, p0);
  if (dg > 1) LOADE(1, eA1, eB1, p1);

  for (int i = 0; i < dg; i += 2) {
    uint4 nA0 = make_uint4(0,0,0,0), nB0 = nA0, nA1 = nA0, nB1 = nA0;
    float2 np0 = make_float2(0.f, 0.f), np1 = np0;
    if (i + 2 < dg) LOADE(i + 2, nA0, nB0, np0);
    if (i + 3 < dg) LOADE(i + 3, nA1, nB1, np1);

    PROCESS(eA0, eB0, p0);
    if (i + 1 < dg) PROCESS(eA1, eB1, p1);

    eA0 = nA0; eB0 = nB0; p0 = np0;
    eA1 = nA1; eB1 = nB1; p1 = np1;
  }

  *(float2*)(S + (size_t)node * HID + c0) = make_float2(a0, a1);
}

// ---------------- fused node MLP (+ optional next-layer pab) ----------------
template<int FUSE>
__global__ __launch_bounds__(256) void node_mlp(
    const float* __restrict__ Hn, const float* __restrict__ S,
    const ushort* __restrict__ N1a, const ushort* __restrict__ W2N, const ushort* __restrict__ N2,
    const float* __restrict__ nb1, const float* __restrict__ nv, const int* __restrict__ deg,
    const float* __restrict__ lng, const float* __restrict__ lnb, const float* __restrict__ nb2,
    const float* __restrict__ lg2, const float* __restrict__ lb2p,
    const ushort* __restrict__ Wab2, const float* __restrict__ eb1_2,
    float* __restrict__ HnOut, float* __restrict__ Pa, float* __restrict__ Pb,
    float* __restrict__ C, int n)
{
  __shared__ ushort Ahn[64][136];
  __shared__ ushort Ah[64][136];
  __shared__ ushort Alo[64][136];
  const int tid = threadIdx.x;
  const int n0 = blockIdx.x * 64;

  #pragma unroll
  for (int i = 0; i < 8; ++i) {
    int s = tid + i * 256;
    int row = s >> 5, c4 = (s & 31) * 4;
    int gr = n0 + row;
    float4 vh = make_float4(0.f, 0.f, 0.f, 0.f);
    float4 vs = make_float4(0.f, 0.f, 0.f, 0.f);
    if (gr < n) {
      vh = *(const float4*)(Hn + (size_t)gr * HID + c4);
      vs = *(const float4*)(S + (size_t)gr * HID + c4);
    }
    uint2 ph;
    ph.x = (uint)f2bf(vh.x) | ((uint)f2bf(vh.y) << 16);
    ph.y = (uint)f2bf(vh.z) | ((uint)f2bf(vh.w) << 16);
    *(uint2*)&Ahn[row][c4] = ph;
    ushort hx = f2bf(vs.x), hy = f2bf(vs.y), hz = f2bf(vs.z), hw = f2bf(vs.w);
    uint2 ps, pl;
    ps.x = (uint)hx | ((uint)hy << 16);
    ps.y = (uint)hz | ((uint)hw << 16);
    pl.x = (uint)f2bf(vs.x - bf2f(hx)) | ((uint)f2bf(vs.y - bf2f(hy)) << 16);
    pl.y = (uint)f2bf(vs.z - bf2f(hz)) | ((uint)f2bf(vs.w - bf2f(hw)) << 16);
    *(uint2*)&Ah[row][c4]  = ps;
    *(uint2*)&Alo[row][c4] = pl;
  }
  __syncthreads();

  const int w = tid >> 6, l = tid & 63;
  const int lr = l & 15, lh = l >> 4;

  f32x4 zf = {0.f, 0.f, 0.f, 0.f};
  f32x4 acc[8];
  #pragma unroll
  for (int nt = 0; nt < 8; ++nt) acc[nt] = zf;

  #pragma unroll
  for (int q = 0; q < 4; ++q) {
    short8 an = *(const short8*)&Ahn[w * 16 + lr][q * 32 + lh * 8];
    short8 ah = *(const short8*)&Ah[w * 16 + lr][q * 32 + lh * 8];
    short8 al = *(const short8*)&Alo[w * 16 + lr][q * 32 + lh * 8];
    #pragma unroll
    for (int nt = 0; nt < 8; ++nt) {
      short8 b1f = *(const short8*)(N1a + (size_t)(nt * 16 + lr) * HID + q * 32 + lh * 8);
      short8 b2f = *(const short8*)(W2N + (size_t)(nt * 16 + lr) * HID + q * 32 + lh * 8);
      acc[nt] = __builtin_amdgcn_mfma_f32_16x16x32_bf16(an, b1f, acc[nt], 0, 0, 0);
      acc[nt] = __builtin_amdgcn_mfma_f32_16x16x32_bf16(ah, b2f, acc[nt], 0, 0, 0);
      acc[nt] = __builtin_amdgcn_mfma_f32_16x16x32_bf16(al, b2f, acc[nt], 0, 0, 0);
    }
  }

  float vb[8], vn[8], gv[8], bv[8];
  #pragma unroll
  for (int nt = 0; nt < 8; ++nt) {
    int col = nt * 16 + lr;
    vb[nt] = nb1[col]; vn[nt] = nv[col];
    gv[nt] = lng[col]; bv[nt] = lnb[col];
  }

  #pragma unroll
  for (int r = 0; r < 4; ++r) {
    int row = n0 + w * 16 + lh * 4 + r;
    float degf = (row < n) ? (float)deg[row] : 0.f;
    float vals[8];
    #pragma unroll
    for (int nt = 0; nt < 8; ++nt) vals[nt] = acc[nt][r] + vb[nt] + degf * vn[nt];
    float s1 = 0.f, s2 = 0.f;
    #pragma unroll
    for (int nt = 0; nt < 8; ++nt) { s1 += vals[nt]; s2 += vals[nt] * vals[nt]; }
    #pragma unroll
    for (int m = 1; m < 16; m <<= 1) { s1 += __shfl_xor(s1, m, 64); s2 += __shfl_xor(s2, m, 64); }
    float mu = s1 * (1.0f / 128.0f);
    float var = s2 * (1.0f / 128.0f) - mu * mu;
    float rs = rsqrtf(var + 1e-5f);
    int lrow = w * 16 + lh * 4 + r;
    #pragma unroll
    for (int nt = 0; nt < 8; ++nt)
      Ahn[lrow][nt * 16 + lr] = f2bf(silu_f((vals[nt] - mu) * rs * gv[nt] + bv[nt]));
  }

  f32x4 acc2[8];
  #pragma unroll
  for (int nt = 0; nt < 8; ++nt) acc2[nt] = zf;
  #pragma unroll
  for (int q = 0; q < 4; ++q) {
    short8 af = *(const short8*)&Ahn[w * 16 + lr][q * 32 + lh * 8];
    #pragma unroll
    for (int nt = 0; nt < 8; ++nt) {
      short8 bf = *(const short8*)(N2 + (size_t)(nt * 16 + lr) * HID + q * 32 + lh * 8);
      acc2[nt] = __builtin_amdgcn_mfma_f32_16x16x32_bf16(af, bf, acc2[nt], 0, 0, 0);
    }
  }

  float vb2[8];
  #pragma unroll
  for (int nt = 0; nt < 8; ++nt) vb2[nt] = nb2[nt * 16 + lr];

  if (FUSE == 0) {
    #pragma unroll
    for (int r = 0; r < 4; ++r) {
      int row = n0 + w * 16 + lh * 4 + r;
      if (row < n) {
        const float* hr = Hn + (size_t)row * HID;
        float* cr = C + (size_t)row * HID;
        #pragma unroll
        for (int nt = 0; nt < 8; ++nt) {
          int col = nt * 16 + lr;
          cr[col] = hr[col] + acc2[nt][r] + vb2[nt];
        }
      }
    }
    return;
  }

  float gv2[8], bv2[8];
  #pragma unroll
  for (int nt = 0; nt < 8; ++nt) { gv2[nt] = lg2[nt * 16 + lr]; bv2[nt] = lb2p[nt * 16 + lr]; }

  #pragma unroll
  for (int r = 0; r < 4; ++r) {
    int row = n0 + w * 16 + lh * 4 + r;
    bool ok = row < n;
    const float* hr = Hn + (size_t)row * HID;
    float vals[8];
    #pragma unroll
    for (int nt = 0; nt < 8; ++nt) {
      int col = nt * 16 + lr;
      float base = ok ? hr[col] : 0.f;
      vals[nt] = base + acc2[nt][r] + vb2[nt];
    }
    float s1 = 0.f, s2 = 0.f;
    #pragma unroll
    for (int nt = 0; nt < 8; ++nt) { s1 += vals[nt]; s2 += vals[nt] * vals[nt]; }
    #pragma unroll
    for (int m = 1; m < 16; m <<= 1) { s1 += __shfl_xor(s1, m, 64); s2 += __shfl_xor(s2, m, 64); }
    float mu = s1 * (1.0f / 128.0f);
    float var = s2 * (1.0f / 128.0f) - mu * mu;
    float rs = rsqrtf(var + 1e-5f);
    int lrow = w * 16 + lh * 4 + r;
    float* hnr = HnOut + (size_t)row * HID;
    #pragma unroll
    for (int nt = 0; nt < 8; ++nt) {
      float hn = (vals[nt] - mu) * rs * gv2[nt] + bv2[nt];
      if (ok) hnr[nt * 16 + lr] = hn;
      Ahn[lrow][nt * 16 + lr] = f2bf(hn);
    }
  }

  f32x4 aab[16];
  #pragma unroll
  for (int nt = 0; nt < 16; ++nt) aab[nt] = zf;
  #pragma unroll
  for (int q = 0; q < 4; ++q) {
    short8 af = *(const short8*)&Ahn[w * 16 + lr][q * 32 + lh * 8];
    #pragma unroll
    for (int nt = 0; nt < 16; ++nt) {
      short8 bf = *(const short8*)(Wab2 + (size_t)(nt * 16 + lr) * HID + q * 32 + lh * 8);
      aab[nt] = __builtin_amdgcn_mfma_f32_16x16x32_bf16(af, bf, aab[nt], 0, 0, 0);
    }
  }
  float be[8];
  #pragma unroll
  for (int nt = 0; nt < 8; ++nt) be[nt] = eb1_2[nt * 16 + lr];
  #pragma unroll
  for (int r = 0; r < 4; ++r) {
    int row = n0 + w * 16 + lh * 4 + r;
    if (row >= n) break;
    float* pa = Pa + (size_t)row * HID;
    float* pb = Pb + (size_t)row * HID;
    #pragma unroll
    for (int nt = 0; nt < 8; ++nt) {
      int col = nt * 16 + lr;
      pa[col] = aab[nt][r] + be[nt];
      pb[col] = aab[nt + 8][r];
    }
  }
}

extern "C" void kernel_launch(void* const* d_in, const int* in_sizes, int n_in,
                              void* d_out, int out_size, void* d_ws, size_t ws_size,
                              hipStream_t stream)
{
  const float* in_h  = (const float*)d_in[0];
  const int*   edges = (const int*)d_in[1];
  const float* ea    = (const float*)d_in[2];
  const float* ei_w1 = (const float*)d_in[3];
  const float* ei_b1 = (const float*)d_in[4];
  const float* ei_w2 = (const float*)d_in[5];
  const float* ei_b2 = (const float*)d_in[6];
  const float* ng    = (const float*)d_in[7];
  const float* nbp   = (const float*)d_in[8];
  const float* ew1   = (const float*)d_in[9];
  const float* eb1   = (const float*)d_in[10];
  const float* elg   = (const float*)d_in[11];
  const float* elb   = (const float*)d_in[12];
  const float* ew2   = (const float*)d_in[13];
  const float* eb2   = (const float*)d_in[14];
  const float* nw1   = (const float*)d_in[15];
  const float* nb1   = (const float*)d_in[16];
  const float* nlg   = (const float*)d_in[17];
  const float* nlb   = (const float*)d_in[18];
  const float* nw2   = (const float*)d_in[19];
  const float* nb2   = (const float*)d_in[20];
  const float* eo_w1 = (const float*)d_in[21];
  const float* eo_b1 = (const float*)d_in[22];
  const float* eo_w2 = (const float*)d_in[23];
  const float* eo_b2 = (const float*)d_in[24];

  float* wf    = (float*)d_ws;
  float* B_h   = wf;
  float* B_hn  = wf + NNH;
  float* B_S   = wf + 2 * NNH;   // S (edge-sum); perm alias during setup
  float* B_tmp = wf + 3 * NNH;   // Pa
  float* B_pb  = wf + 4 * NNH;   // Pb

  const size_t WOFF = 5 * NNH;
  ushort* wu = (ushort*)(wf + WOFF);
  // ei1@0, ei2@16384, eo1@32768, eo2@49152; per-layer base 65536 + l*104448:
  //   Wab@0 [256][128] | W2N@32768 | N1a@49152 | N2@81920
  const size_t SOFF = WOFF + 262144;
  int* dst_s = (int*)(wf + SOFF);
  int* cnt   = dst_s + NE;       // = deg
  int* cur   = cnt + NPAD;
  int* base  = cur + NPAD;
  ushort* ea_s = (ushort*)(base + NPAD);
  float* nvb = (float*)(ea_s + (size_t)NE * 16);   // 4*128 fp32
  int* perm  = (int*)B_S;

  const int NB  = (NN + 63) / 64;
  const int NBE = (NN + 3) / 4;
  const int NEB = (NE + 255) / 256;

  const int* erow = edges;
  const int* ecol = edges + NE;

  // ---- counting sort by src (once) ----
  zero_i<<<(2 * NPAD + 255) / 256, 256, 0, stream>>>(cnt, 2 * NPAD);
  count_src<<<NEB, 256, 0, stream>>>(erow, cnt);
  scan_excl<<<1, 1024, 0, stream>>>(cnt, base, NN);
  place_edges<<<NEB, 256, 0, stream>>>(erow, ecol, base, cur, dst_s, perm);
  permute_ea_h<<<(NE * 4 + 255) / 256, 256, 0, stream>>>((const float4*)ea, perm, ea_s);

  // ---- weight conversion / folding ----
  cvt4<<<256, 256, 0, stream>>>(ei_w1, ei_w2, eo_w1, eo_w2, wu);
  cvt_wab<<<512, 256, 0, stream>>>(ew1, wu + 65536);
  cvt_std<<<(4 * 16384 + 255) / 256, 256, 0, stream>>>(nw2, wu + 65536 + 81920, 128, 128, 16384);
  fold_w<<<512, 128, 0, stream>>>(nw1, ew2, eb2, wu + 65536, nvb);

  // ---- embedding_in fused with layer-0 pab_ln (h0 never materialized) ----
  emb2<1><<<NB, 256, 0, stream>>>(in_h, wu, ei_b1, wu + 16384, ei_b2,
      ng, nbp, wu + 65536, eb1, B_hn, B_tmp, B_pb, nullptr, NN);

  for (int lyr = 0; lyr < 4; ++lyr) {
    ushort* lb = wu + 65536 + lyr * 104448;
    node_edge<<<NBE, 256, 0, stream>>>(B_tmp, B_pb, ea_s, dst_s, base, cnt,
        ew1 + 34816 * lyr, elg + 128 * lyr, elb + 128 * lyr, B_S, NN);
    if (lyr < 3) {
      ushort* lb2 = lb + 104448;
      node_mlp<1><<<NB, 256, 0, stream>>>(B_hn, B_S, lb + 49152, lb + 32768, lb + 81920,
          nb1 + 128 * lyr, nvb + 128 * lyr, cnt,
          nlg + 128 * lyr, nlb + 128 * lyr, nb2 + 128 * lyr,
          ng + 128 * (lyr + 1), nbp + 128 * (lyr + 1), lb2, eb1 + 128 * (lyr + 1),
          B_hn, B_tmp, B_pb, nullptr, NN);
    } else {
      node_mlp<0><<<NB, 256, 0, stream>>>(B_hn, B_S, lb + 49152, lb + 32768, lb + 81920,
          nb1 + 128 * lyr, nvb + 128 * lyr, cnt,
          nlg + 128 * lyr, nlb + 128 * lyr, nb2 + 128 * lyr,
          nullptr, nullptr, nullptr, nullptr,
          nullptr, nullptr, nullptr, B_h, NN);
    }
  }

  // ---- embedding_out ----
  emb2<0><<<NB, 256, 0, stream>>>(B_h, wu + 32768, eo_b1, wu + 49152, eo_b2,
      nullptr, nullptr, nullptr, nullptr, nullptr, nullptr, nullptr, (float*)d_out, NN);
}

// Round 14
// 1215.814 us; speedup vs baseline: 1.3676x; 1.0177x over previous
//
#include <hip/hip_runtime.h>
#include <math.h>

#define NN 50000
#define NE 800000
#define HID 128
#define NNH ((size_t)NN * HID)
#define NPAD 50176

typedef __attribute__((ext_vector_type(8))) short short8;
typedef __attribute__((ext_vector_type(4))) float f32x4;
typedef __attribute__((ext_vector_type(2))) _Float16 half2v;
typedef __attribute__((ext_vector_type(8))) _Float16 half8;

__device__ __forceinline__ ushort f2bf(float f) {
  unsigned u = __float_as_uint(f);
  unsigned r = (u + 0x7fffu + ((u >> 16) & 1u)) >> 16;
  return (ushort)r;
}
__device__ __forceinline__ ushort f2h_bits(float f) {
  _Float16 h = (_Float16)f;
  ushort u;
  __builtin_memcpy(&u, &h, 2);
  return u;
}
__device__ __forceinline__ half2v u2h(uint u) {
  half2v h;
  __builtin_memcpy(&h, &u, 4);
  return h;
}
__device__ __forceinline__ float silu_f(float x) { return x / (1.0f + __expf(-x)); }

// Full-wave (64-lane) sum via DPP adds; result broadcast via readlane 63.
__device__ __forceinline__ float wsum64(float x) {
  int t;
  t = __builtin_amdgcn_update_dpp(0, __float_as_int(x), 0x111, 0xf, 0xf, true); x += __int_as_float(t);
  t = __builtin_amdgcn_update_dpp(0, __float_as_int(x), 0x112, 0xf, 0xf, true); x += __int_as_float(t);
  t = __builtin_amdgcn_update_dpp(0, __float_as_int(x), 0x114, 0xf, 0xf, true); x += __int_as_float(t);
  t = __builtin_amdgcn_update_dpp(0, __float_as_int(x), 0x118, 0xf, 0xf, true); x += __int_as_float(t);
  t = __builtin_amdgcn_update_dpp(0, __float_as_int(x), 0x142, 0xf, 0xf, true); x += __int_as_float(t);
  t = __builtin_amdgcn_update_dpp(0, __float_as_int(x), 0x143, 0xf, 0xf, true); x += __int_as_float(t);
  return __uint_as_float(__builtin_amdgcn_readlane(__float_as_int(x), 63));
}

// ---------------- utility ----------------
__global__ __launch_bounds__(256) void zero_i(int* __restrict__ p, int n)
{
  int i = blockIdx.x * 256 + threadIdx.x;
  if (i < n) p[i] = 0;
}

// ---------------- counting sort of edges by src ----------------
__global__ __launch_bounds__(256) void count_src(const int* __restrict__ src, int* __restrict__ cnt)
{
  int e = blockIdx.x * 256 + threadIdx.x;
  if (e < NE) atomicAdd(&cnt[src[e]], 1);
}

__global__ __launch_bounds__(1024) void scan_excl(const int* __restrict__ cnt, int* __restrict__ base, int n)
{
  __shared__ int ws[16];
  int t = threadIdx.x;
  const int per = (n + 1023) / 1024;
  int s0 = t * per;
  int sum = 0;
  for (int i = 0; i < per; ++i) { int idx = s0 + i; if (idx < n) sum += cnt[idx]; }
  int lane = t & 63, w = t >> 6;
  int v = sum;
  #pragma unroll
  for (int m = 1; m < 64; m <<= 1) { int o = __shfl_up(v, m, 64); if (lane >= m) v += o; }
  if (lane == 63) ws[w] = v;
  __syncthreads();
  if (t == 0) { int a = 0; for (int i = 0; i < 16; ++i) { int x = ws[i]; ws[i] = a; a += x; } }
  __syncthreads();
  int run = ws[w] + v - sum;
  for (int i = 0; i < per; ++i) {
    int idx = s0 + i;
    if (idx < n) { base[idx] = run; run += cnt[idx]; }
  }
}

__global__ __launch_bounds__(256) void place_edges(const int* __restrict__ src, const int* __restrict__ dst,
    const int* __restrict__ base, int* __restrict__ cur,
    int* __restrict__ dst_s, int* __restrict__ perm)
{
  int e = blockIdx.x * 256 + threadIdx.x;
  if (e >= NE) return;
  int s = src[e];
  int p = base[s] + atomicAdd(&cur[s], 1);
  dst_s[p] = dst[e]; perm[p] = e;
}

// permute edge_attr into sorted order AND convert to f16 ([NE][16] ushort = f16 bits)
__global__ __launch_bounds__(256) void permute_ea_h(const float4* __restrict__ ea,
    const int* __restrict__ perm, ushort* __restrict__ ea_s)
{
  int i = blockIdx.x * 256 + threadIdx.x;
  if (i >= NE * 4) return;
  int e = i >> 2, q = i & 3;
  float4 v = ea[(size_t)perm[e] * 4 + q];
  uint2 p;
  p.x = (uint)f2h_bits(v.x) | ((uint)f2h_bits(v.y) << 16);
  p.y = (uint)f2h_bits(v.z) | ((uint)f2h_bits(v.w) << 16);
  *(uint2*)&ea_s[(size_t)e * 16 + q * 4] = p;
}

// ---------------- weight conversion ----------------
__global__ __launch_bounds__(256) void cvt4(const float* __restrict__ s0, const float* __restrict__ s1,
    const float* __restrict__ s2, const float* __restrict__ s3, ushort* __restrict__ d)
{
  int i = blockIdx.x * 256 + threadIdx.x;
  if (i >= 65536) return;
  const float* s = (i < 16384) ? s0 : (i < 32768) ? s1 : (i < 49152) ? s2 : s3;
  d[i] = f2bf(s[i & 16383]);
}
__global__ __launch_bounds__(256) void cvt_wab(const float* __restrict__ s, ushort* __restrict__ d)
{
  int i = blockIdx.x * 256 + threadIdx.x;
  if (i >= 131072) return;
  int l = i >> 15, rem = i & 32767;
  int r = rem >> 7, c = rem & 127;
  int srow = r & 127, scol = ((r >> 7) << 7) + c;
  d[l * 104448 + r * 128 + c] = f2bf(s[(size_t)l * 34816 + srow * 272 + scol]);
}
__global__ __launch_bounds__(256) void cvt_std(const float* __restrict__ s, ushort* __restrict__ d,
    int rows, int cols, int lss)
{
  int i = blockIdx.x * 256 + threadIdx.x;
  int n = 4 * rows * cols;
  if (i >= n) return;
  int rc = rows * cols;
  int l = i / rc, rem = i - l * rc;
  d[l * 104448 + rem] = f2bf(s[(size_t)l * lss + rem]);
}

// ---------------- fold: W2N = N1b @ W2 (f16!), N1a (bf16), nv = N1b @ b2 (fp32) ----------------
__global__ __launch_bounds__(128) void fold_w(const float* __restrict__ nw1,
    const float* __restrict__ ew2, const float* __restrict__ eb2,
    ushort* __restrict__ wu_base, float* __restrict__ nv)
{
  __shared__ float red[2];
  int bid = blockIdx.x;
  int l = bid >> 7, m = bid & 127;
  int j = threadIdx.x;
  const float* n1row = nw1 + (size_t)l * 32768 + (size_t)m * 256;
  const float* n1b = n1row + 128;
  const float* w2 = ew2 + (size_t)l * 16384;
  float s = 0.f;
  for (int k = 0; k < 128; ++k) s = fmaf(n1b[k], w2[k * 128 + j], s);
  ushort* lb = wu_base + (size_t)l * 104448;
  lb[32768 + m * 128 + j] = f2h_bits(s);      // W2N as f16
  lb[49152 + m * 128 + j] = f2bf(n1row[j]);   // N1a bf16
  float p = n1b[j] * eb2[l * 128 + j];
  #pragma unroll
  for (int mm = 1; mm < 64; mm <<= 1) p += __shfl_xor(p, mm, 64);
  if ((j & 63) == 0) red[j >> 6] = p;
  __syncthreads();
  if (j == 0) nv[l * 128 + m] = red[0] + red[1];
}

// ---------------- fused 2-layer MLP, optional pab tail ----------------
template<int FUSE>
__global__ __launch_bounds__(256) void emb2(
    const float* __restrict__ A,
    const ushort* __restrict__ W1, const float* __restrict__ b1,
    const ushort* __restrict__ W2, const float* __restrict__ b2,
    const float* __restrict__ lg, const float* __restrict__ lbp,
    const ushort* __restrict__ Wab, const float* __restrict__ eb1,
    float* __restrict__ Hn, float* __restrict__ Pa, float* __restrict__ Pb,
    float* __restrict__ C, int n)
{
  __shared__ ushort Al[64][136];
  const int tid = threadIdx.x;
  const int n0 = blockIdx.x * 64;

  #pragma unroll
  for (int i = 0; i < 8; ++i) {
    int s = tid + i * 256;
    int row = s >> 5, c4 = (s & 31) * 4;
    int gr = n0 + row;
    float4 v = make_float4(0.f, 0.f, 0.f, 0.f);
    if (gr < n) v = *(const float4*)(A + (size_t)gr * HID + c4);
    uint2 p;
    p.x = (uint)f2bf(v.x) | ((uint)f2bf(v.y) << 16);
    p.y = (uint)f2bf(v.z) | ((uint)f2bf(v.w) << 16);
    *(uint2*)&Al[row][c4] = p;
  }
  __syncthreads();

  const int w = tid >> 6, l = tid & 63;
  const int lr = l & 15, lh = l >> 4;

  f32x4 zf = {0.f, 0.f, 0.f, 0.f};
  f32x4 acc[8];
  #pragma unroll
  for (int nt = 0; nt < 8; ++nt) acc[nt] = zf;

  #pragma unroll
  for (int q = 0; q < 4; ++q) {
    short8 af = *(const short8*)&Al[w * 16 + lr][q * 32 + lh * 8];
    #pragma unroll
    for (int nt = 0; nt < 8; ++nt) {
      short8 bf = *(const short8*)(W1 + (size_t)(nt * 16 + lr) * HID + q * 32 + lh * 8);
      acc[nt] = __builtin_amdgcn_mfma_f32_16x16x32_bf16(af, bf, acc[nt], 0, 0, 0);
    }
  }

  float vb[8];
  #pragma unroll
  for (int nt = 0; nt < 8; ++nt) vb[nt] = b1[nt * 16 + lr];

  #pragma unroll
  for (int r = 0; r < 4; ++r) {
    int row = w * 16 + lh * 4 + r;
    #pragma unroll
    for (int nt = 0; nt < 8; ++nt)
      Al[row][nt * 16 + lr] = f2bf(silu_f(acc[nt][r] + vb[nt]));
  }

  f32x4 acc2[8];
  #pragma unroll
  for (int nt = 0; nt < 8; ++nt) acc2[nt] = zf;
  #pragma unroll
  for (int q = 0; q < 4; ++q) {
    short8 af = *(const short8*)&Al[w * 16 + lr][q * 32 + lh * 8];
    #pragma unroll
    for (int nt = 0; nt < 8; ++nt) {
      short8 bf = *(const short8*)(W2 + (size_t)(nt * 16 + lr) * HID + q * 32 + lh * 8);
      acc2[nt] = __builtin_amdgcn_mfma_f32_16x16x32_bf16(af, bf, acc2[nt], 0, 0, 0);
    }
  }

  float vb2[8];
  #pragma unroll
  for (int nt = 0; nt < 8; ++nt) vb2[nt] = b2[nt * 16 + lr];

  if (FUSE == 0) {
    #pragma unroll
    for (int r = 0; r < 4; ++r) {
      int row = n0 + w * 16 + lh * 4 + r;
      if (row < n) {
        float* cr = C + (size_t)row * HID;
        #pragma unroll
        for (int nt = 0; nt < 8; ++nt)
          cr[nt * 16 + lr] = acc2[nt][r] + vb2[nt];
      }
    }
    return;
  }

  float gv[8], bv[8];
  #pragma unroll
  for (int nt = 0; nt < 8; ++nt) { gv[nt] = lg[nt * 16 + lr]; bv[nt] = lbp[nt * 16 + lr]; }

  #pragma unroll
  for (int r = 0; r < 4; ++r) {
    int row = n0 + w * 16 + lh * 4 + r;
    bool ok = row < n;
    float vals[8];
    #pragma unroll
    for (int nt = 0; nt < 8; ++nt) vals[nt] = acc2[nt][r] + vb2[nt];
    float s1 = 0.f, s2 = 0.f;
    #pragma unroll
    for (int nt = 0; nt < 8; ++nt) { s1 += vals[nt]; s2 += vals[nt] * vals[nt]; }
    #pragma unroll
    for (int m = 1; m < 16; m <<= 1) { s1 += __shfl_xor(s1, m, 64); s2 += __shfl_xor(s2, m, 64); }
    float mu = s1 * (1.0f / 128.0f);
    float var = s2 * (1.0f / 128.0f) - mu * mu;
    float rs = rsqrtf(var + 1e-5f);
    int lrow = w * 16 + lh * 4 + r;
    float* hnr = Hn + (size_t)row * HID;
    #pragma unroll
    for (int nt = 0; nt < 8; ++nt) {
      float hn = (vals[nt] - mu) * rs * gv[nt] + bv[nt];
      if (ok) hnr[nt * 16 + lr] = hn;
      Al[lrow][nt * 16 + lr] = f2bf(hn);
    }
  }

  f32x4 aab[16];
  #pragma unroll
  for (int nt = 0; nt < 16; ++nt) aab[nt] = zf;
  #pragma unroll
  for (int q = 0; q < 4; ++q) {
    short8 af = *(const short8*)&Al[w * 16 + lr][q * 32 + lh * 8];
    #pragma unroll
    for (int nt = 0; nt < 16; ++nt) {
      short8 bf = *(const short8*)(Wab + (size_t)(nt * 16 + lr) * HID + q * 32 + lh * 8);
      aab[nt] = __builtin_amdgcn_mfma_f32_16x16x32_bf16(af, bf, aab[nt], 0, 0, 0);
    }
  }
  float be[8];
  #pragma unroll
  for (int nt = 0; nt < 8; ++nt) be[nt] = eb1[nt * 16 + lr];
  #pragma unroll
  for (int r = 0; r < 4; ++r) {
    int row = n0 + w * 16 + lh * 4 + r;
    if (row >= n) break;
    float* pa = Pa + (size_t)row * HID;
    float* pb = Pb + (size_t)row * HID;
    #pragma unroll
    for (int nt = 0; nt < 8; ++nt) {
      int col = nt * 16 + lr;
      pa[col] = aab[nt][r] + be[nt];
      pb[col] = aab[nt + 8][r];
    }
  }
}

// ---------------- per-node CSR edge kernel: R13 structure, S written as f16 ----------------
__global__ __launch_bounds__(256) void node_edge(
    const float* __restrict__ Pa, const float* __restrict__ Pb,
    const ushort* __restrict__ ea_h,     // f16 bits, [NE][16]
    const int* __restrict__ dst_s,
    const int* __restrict__ ebase, const int* __restrict__ deg,
    const float* __restrict__ w1c,
    const float* __restrict__ elg, const float* __restrict__ elb,
    ushort* __restrict__ Sh, int n)      // f16 out [NN][128]
{
  const int tid = threadIdx.x;
  const int wv = __builtin_amdgcn_readfirstlane(tid >> 6);
  const int lane = tid & 63;
  const int node = blockIdx.x * 4 + wv;
  if (node >= n) return;
  const int c0 = lane * 2;

  half2v w1h0[8], w1h1[8];
  {
    const float* wr0 = w1c + (size_t)c0 * 272 + 256;
    const float* wr1 = wr0 + 272;
    #pragma unroll
    for (int k = 0; k < 8; ++k) {
      half2v h0; h0[0] = (_Float16)wr0[2 * k]; h0[1] = (_Float16)wr0[2 * k + 1]; w1h0[k] = h0;
      half2v h1; h1[0] = (_Float16)wr1[2 * k]; h1[1] = (_Float16)wr1[2 * k + 1]; w1h1[k] = h1;
    }
  }
  const float g0 = elg[c0], g1 = elg[c0 + 1];
  const float b0 = elb[c0], b1 = elb[c0 + 1];
  const float pax = Pa[(size_t)node * HID + c0];
  const float pay = Pa[(size_t)node * HID + c0 + 1];

  const int beg = __builtin_amdgcn_readfirstlane(ebase[node]);
  const int dg  = __builtin_amdgcn_readfirstlane(deg[node]);

  float a0 = 0.f, a1 = 0.f;

  uint4 eA0 = make_uint4(0,0,0,0), eB0 = eA0, eA1 = eA0, eB1 = eA0;
  float2 p0 = make_float2(0.f, 0.f), p1 = p0;

  auto LOADE = [&](int idx, uint4& ea, uint4& eb, float2& pb) {
    int eu = __builtin_amdgcn_readfirstlane(beg + idx);
    int d  = dst_s[eu];
    ea = *(const uint4*)(ea_h + (size_t)eu * 16);
    eb = *(const uint4*)(ea_h + (size_t)eu * 16 + 8);
    pb = *(const float2*)(Pb + (size_t)d * HID + c0);
  };
  auto PROCESS = [&](const uint4& eaA, const uint4& eaB, const float2& pbc) {
    half2v eh[8];
    eh[0] = u2h(eaA.x); eh[1] = u2h(eaA.y); eh[2] = u2h(eaA.z); eh[3] = u2h(eaA.w);
    eh[4] = u2h(eaB.x); eh[5] = u2h(eaB.y); eh[6] = u2h(eaB.z); eh[7] = u2h(eaB.w);

    float x0 = pax + pbc.x;
    float x1 = pay + pbc.y;
    #pragma unroll
    for (int k = 0; k < 8; ++k) {
      x0 = __builtin_amdgcn_fdot2(eh[k], w1h0[k], x0, false);
      x1 = __builtin_amdgcn_fdot2(eh[k], w1h1[k], x1, false);
    }
    float s1 = wsum64(x0 + x1);
    float s2 = wsum64(fmaf(x0, x0, x1 * x1));
    float mu = s1 * (1.0f / 128.0f);
    float var = s2 * (1.0f / 128.0f) - mu * mu;
    float rs = rsqrtf(var + 1e-5f);
    a0 += silu_f((x0 - mu) * rs * g0 + b0);
    a1 += silu_f((x1 - mu) * rs * g1 + b1);
  };

  if (dg > 0) LOADE(0, eA0, eB0, p0);
  if (dg > 1) LOADE(1, eA1, eB1, p1);

  for (int i = 0; i < dg; i += 2) {
    uint4 nA0 = make_uint4(0,0,0,0), nB0 = nA0, nA1 = nA0, nB1 = nA0;
    float2 np0 = make_float2(0.f, 0.f), np1 = np0;
    if (i + 2 < dg) LOADE(i + 2, nA0, nB0, np0);
    if (i + 3 < dg) LOADE(i + 3, nA1, nB1, np1);

    PROCESS(eA0, eB0, p0);
    if (i + 1 < dg) PROCESS(eA1, eB1, p1);

    eA0 = nA0; eB0 = nB0; p0 = np0;
    eA1 = nA1; eB1 = nB1; p1 = np1;
  }

  uint pk = (uint)f2h_bits(a0) | ((uint)f2h_bits(a1) << 16);
  *(uint*)(Sh + (size_t)node * HID + c0) = pk;
}

// ---------------- fused node MLP (+ optional next-layer pab), S consumed as f16 single tile ----------------
template<int FUSE>
__global__ __launch_bounds__(256) void node_mlp(
    const float* __restrict__ Hn, const ushort* __restrict__ Sh,
    const ushort* __restrict__ N1a, const ushort* __restrict__ W2Nh, const ushort* __restrict__ N2,
    const float* __restrict__ nb1, const float* __restrict__ nv, const int* __restrict__ deg,
    const float* __restrict__ lng, const float* __restrict__ lnb, const float* __restrict__ nb2,
    const float* __restrict__ lg2, const float* __restrict__ lb2p,
    const ushort* __restrict__ Wab2, const float* __restrict__ eb1_2,
    float* __restrict__ HnOut, float* __restrict__ Pa, float* __restrict__ Pb,
    float* __restrict__ C, int n)
{
  __shared__ ushort Ahn[64][136];
  __shared__ ushort Ash[64][136];
  const int tid = threadIdx.x;
  const int n0 = blockIdx.x * 64;

  #pragma unroll
  for (int i = 0; i < 8; ++i) {
    int s = tid + i * 256;
    int row = s >> 5, c4 = (s & 31) * 4;
    int gr = n0 + row;
    float4 vh = make_float4(0.f, 0.f, 0.f, 0.f);
    uint2 sv = make_uint2(0, 0);
    if (gr < n) {
      vh = *(const float4*)(Hn + (size_t)gr * HID + c4);
      sv = *(const uint2*)(Sh + (size_t)gr * HID + c4);
    }
    uint2 ph;
    ph.x = (uint)f2bf(vh.x) | ((uint)f2bf(vh.y) << 16);
    ph.y = (uint)f2bf(vh.z) | ((uint)f2bf(vh.w) << 16);
    *(uint2*)&Ahn[row][c4] = ph;
    *(uint2*)&Ash[row][c4] = sv;
  }
  __syncthreads();

  const int w = tid >> 6, l = tid & 63;
  const int lr = l & 15, lh = l >> 4;

  f32x4 zf = {0.f, 0.f, 0.f, 0.f};
  f32x4 acc[8];
  #pragma unroll
  for (int nt = 0; nt < 8; ++nt) acc[nt] = zf;

  #pragma unroll
  for (int q = 0; q < 4; ++q) {
    short8 an = *(const short8*)&Ahn[w * 16 + lr][q * 32 + lh * 8];
    half8  as = *(const half8*)&Ash[w * 16 + lr][q * 32 + lh * 8];
    #pragma unroll
    for (int nt = 0; nt < 8; ++nt) {
      short8 b1f = *(const short8*)(N1a + (size_t)(nt * 16 + lr) * HID + q * 32 + lh * 8);
      half8  b2h = *(const half8*)(W2Nh + (size_t)(nt * 16 + lr) * HID + q * 32 + lh * 8);
      acc[nt] = __builtin_amdgcn_mfma_f32_16x16x32_bf16(an, b1f, acc[nt], 0, 0, 0);
      acc[nt] = __builtin_amdgcn_mfma_f32_16x16x32_f16(as, b2h, acc[nt], 0, 0, 0);
    }
  }

  float vb[8], vn[8], gv[8], bv[8];
  #pragma unroll
  for (int nt = 0; nt < 8; ++nt) {
    int col = nt * 16 + lr;
    vb[nt] = nb1[col]; vn[nt] = nv[col];
    gv[nt] = lng[col]; bv[nt] = lnb[col];
  }

  #pragma unroll
  for (int r = 0; r < 4; ++r) {
    int row = n0 + w * 16 + lh * 4 + r;
    float degf = (row < n) ? (float)deg[row] : 0.f;
    float vals[8];
    #pragma unroll
    for (int nt = 0; nt < 8; ++nt) vals[nt] = acc[nt][r] + vb[nt] + degf * vn[nt];
    float s1 = 0.f, s2 = 0.f;
    #pragma unroll
    for (int nt = 0; nt < 8; ++nt) { s1 += vals[nt]; s2 += vals[nt] * vals[nt]; }
    #pragma unroll
    for (int m = 1; m < 16; m <<= 1) { s1 += __shfl_xor(s1, m, 64); s2 += __shfl_xor(s2, m, 64); }
    float mu = s1 * (1.0f / 128.0f);
    float var = s2 * (1.0f / 128.0f) - mu * mu;
    float rs = rsqrtf(var + 1e-5f);
    int lrow = w * 16 + lh * 4 + r;
    #pragma unroll
    for (int nt = 0; nt < 8; ++nt)
      Ahn[lrow][nt * 16 + lr] = f2bf(silu_f((vals[nt] - mu) * rs * gv[nt] + bv[nt]));
  }

  f32x4 acc2[8];
  #pragma unroll
  for (int nt = 0; nt < 8; ++nt) acc2[nt] = zf;
  #pragma unroll
  for (int q = 0; q < 4; ++q) {
    short8 af = *(const short8*)&Ahn[w * 16 + lr][q * 32 + lh * 8];
    #pragma unroll
    for (int nt = 0; nt < 8; ++nt) {
      short8 bf = *(const short8*)(N2 + (size_t)(nt * 16 + lr) * HID + q * 32 + lh * 8);
      acc2[nt] = __builtin_amdgcn_mfma_f32_16x16x32_bf16(af, bf, acc2[nt], 0, 0, 0);
    }
  }

  float vb2[8];
  #pragma unroll
  for (int nt = 0; nt < 8; ++nt) vb2[nt] = nb2[nt * 16 + lr];

  if (FUSE == 0) {
    #pragma unroll
    for (int r = 0; r < 4; ++r) {
      int row = n0 + w * 16 + lh * 4 + r;
      if (row < n) {
        const float* hr = Hn + (size_t)row * HID;
        float* cr = C + (size_t)row * HID;
        #pragma unroll
        for (int nt = 0; nt < 8; ++nt) {
          int col = nt * 16 + lr;
          cr[col] = hr[col] + acc2[nt][r] + vb2[nt];
        }
      }
    }
    return;
  }

  float gv2[8], bv2[8];
  #pragma unroll
  for (int nt = 0; nt < 8; ++nt) { gv2[nt] = lg2[nt * 16 + lr]; bv2[nt] = lb2p[nt * 16 + lr]; }

  #pragma unroll
  for (int r = 0; r < 4; ++r) {
    int row = n0 + w * 16 + lh * 4 + r;
    bool ok = row < n;
    const float* hr = Hn + (size_t)row * HID;
    float vals[8];
    #pragma unroll
    for (int nt = 0; nt < 8; ++nt) {
      int col = nt * 16 + lr;
      float base = ok ? hr[col] : 0.f;
      vals[nt] = base + acc2[nt][r] + vb2[nt];
    }
    float s1 = 0.f, s2 = 0.f;
    #pragma unroll
    for (int nt = 0; nt < 8; ++nt) { s1 += vals[nt]; s2 += vals[nt] * vals[nt]; }
    #pragma unroll
    for (int m = 1; m < 16; m <<= 1) { s1 += __shfl_xor(s1, m, 64); s2 += __shfl_xor(s2, m, 64); }
    float mu = s1 * (1.0f / 128.0f);
    float var = s2 * (1.0f / 128.0f) - mu * mu;
    float rs = rsqrtf(var + 1e-5f);
    int lrow = w * 16 + lh * 4 + r;
    float* hnr = HnOut + (size_t)row * HID;
    #pragma unroll
    for (int nt = 0; nt < 8; ++nt) {
      float hn = (vals[nt] - mu) * rs * gv2[nt] + bv2[nt];
      if (ok) hnr[nt * 16 + lr] = hn;
      Ahn[lrow][nt * 16 + lr] = f2bf(hn);
    }
  }

  f32x4 aab[16];
  #pragma unroll
  for (int nt = 0; nt < 16; ++nt) aab[nt] = zf;
  #pragma unroll
  for (int q = 0; q < 4; ++q) {
    short8 af = *(const short8*)&Ahn[w * 16 + lr][q * 32 + lh * 8];
    #pragma unroll
    for (int nt = 0; nt < 16; ++nt) {
      short8 bf = *(const short8*)(Wab2 + (size_t)(nt * 16 + lr) * HID + q * 32 + lh * 8);
      aab[nt] = __builtin_amdgcn_mfma_f32_16x16x32_bf16(af, bf, aab[nt], 0, 0, 0);
    }
  }
  float be[8];
  #pragma unroll
  for (int nt = 0; nt < 8; ++nt) be[nt] = eb1_2[nt * 16 + lr];
  #pragma unroll
  for (int r = 0; r < 4; ++r) {
    int row = n0 + w * 16 + lh * 4 + r;
    if (row >= n) break;
    float* pa = Pa + (size_t)row * HID;
    float* pb = Pb + (size_t)row * HID;
    #pragma unroll
    for (int nt = 0; nt < 8; ++nt) {
      int col = nt * 16 + lr;
      pa[col] = aab[nt][r] + be[nt];
      pb[col] = aab[nt + 8][r];
    }
  }
}

extern "C" void kernel_launch(void* const* d_in, const int* in_sizes, int n_in,
                              void* d_out, int out_size, void* d_ws, size_t ws_size,
                              hipStream_t stream)
{
  const float* in_h  = (const float*)d_in[0];
  const int*   edges = (const int*)d_in[1];
  const float* ea    = (const float*)d_in[2];
  const float* ei_w1 = (const float*)d_in[3];
  const float* ei_b1 = (const float*)d_in[4];
  const float* ei_w2 = (const float*)d_in[5];
  const float* ei_b2 = (const float*)d_in[6];
  const float* ng    = (const float*)d_in[7];
  const float* nbp   = (const float*)d_in[8];
  const float* ew1   = (const float*)d_in[9];
  const float* eb1   = (const float*)d_in[10];
  const float* elg   = (const float*)d_in[11];
  const float* elb   = (const float*)d_in[12];
  const float* ew2   = (const float*)d_in[13];
  const float* eb2   = (const float*)d_in[14];
  const float* nw1   = (const float*)d_in[15];
  const float* nb1   = (const float*)d_in[16];
  const float* nlg   = (const float*)d_in[17];
  const float* nlb   = (const float*)d_in[18];
  const float* nw2   = (const float*)d_in[19];
  const float* nb2   = (const float*)d_in[20];
  const float* eo_w1 = (const float*)d_in[21];
  const float* eo_b1 = (const float*)d_in[22];
  const float* eo_w2 = (const float*)d_in[23];
  const float* eo_b2 = (const float*)d_in[24];

  float* wf    = (float*)d_ws;
  float* B_h   = wf;
  float* B_hn  = wf + NNH;
  float* B_S   = wf + 2 * NNH;   // S f16 buffer (uses half the slot); perm alias during setup
  float* B_tmp = wf + 3 * NNH;   // Pa
  float* B_pb  = wf + 4 * NNH;   // Pb
  ushort* Sh   = (ushort*)B_S;

  const size_t WOFF = 5 * NNH;
  ushort* wu = (ushort*)(wf + WOFF);
  // ei1@0, ei2@16384, eo1@32768, eo2@49152; per-layer base 65536 + l*104448:
  //   Wab@0 [256][128] | W2N(f16)@32768 | N1a@49152 | N2@81920
  const size_t SOFF = WOFF + 262144;
  int* dst_s = (int*)(wf + SOFF);
  int* cnt   = dst_s + NE;       // = deg
  int* cur   = cnt + NPAD;
  int* base  = cur + NPAD;
  ushort* ea_s = (ushort*)(base + NPAD);
  float* nvb = (float*)(ea_s + (size_t)NE * 16);   // 4*128 fp32
  int* perm  = (int*)B_S;

  const int NB  = (NN + 63) / 64;
  const int NBE = (NN + 3) / 4;
  const int NEB = (NE + 255) / 256;

  const int* erow = edges;
  const int* ecol = edges + NE;

  // ---- counting sort by src (once) ----
  zero_i<<<(2 * NPAD + 255) / 256, 256, 0, stream>>>(cnt, 2 * NPAD);
  count_src<<<NEB, 256, 0, stream>>>(erow, cnt);
  scan_excl<<<1, 1024, 0, stream>>>(cnt, base, NN);
  place_edges<<<NEB, 256, 0, stream>>>(erow, ecol, base, cur, dst_s, perm);
  permute_ea_h<<<(NE * 4 + 255) / 256, 256, 0, stream>>>((const float4*)ea, perm, ea_s);

  // ---- weight conversion / folding ----
  cvt4<<<256, 256, 0, stream>>>(ei_w1, ei_w2, eo_w1, eo_w2, wu);
  cvt_wab<<<512, 256, 0, stream>>>(ew1, wu + 65536);
  cvt_std<<<(4 * 16384 + 255) / 256, 256, 0, stream>>>(nw2, wu + 65536 + 81920, 128, 128, 16384);
  fold_w<<<512, 128, 0, stream>>>(nw1, ew2, eb2, wu + 65536, nvb);

  // ---- embedding_in fused with layer-0 pab_ln (h0 never materialized) ----
  emb2<1><<<NB, 256, 0, stream>>>(in_h, wu, ei_b1, wu + 16384, ei_b2,
      ng, nbp, wu + 65536, eb1, B_hn, B_tmp, B_pb, nullptr, NN);

  for (int lyr = 0; lyr < 4; ++lyr) {
    ushort* lb = wu + 65536 + lyr * 104448;
    node_edge<<<NBE, 256, 0, stream>>>(B_tmp, B_pb, ea_s, dst_s, base, cnt,
        ew1 + 34816 * lyr, elg + 128 * lyr, elb + 128 * lyr, Sh, NN);
    if (lyr < 3) {
      ushort* lb2 = lb + 104448;
      node_mlp<1><<<NB, 256, 0, stream>>>(B_hn, Sh, lb + 49152, lb + 32768, lb + 81920,
          nb1 + 128 * lyr, nvb + 128 * lyr, cnt,
          nlg + 128 * lyr, nlb + 128 * lyr, nb2 + 128 * lyr,
          ng + 128 * (lyr + 1), nbp + 128 * (lyr + 1), lb2, eb1 + 128 * (lyr + 1),
          B_hn, B_tmp, B_pb, nullptr, NN);
    } else {
      node_mlp<0><<<NB, 256, 0, stream>>>(B_hn, Sh, lb + 49152, lb + 32768, lb + 81920,
          nb1 + 128 * lyr, nvb + 128 * lyr, cnt,
          nlg + 128 * lyr, nlb + 128 * lyr, nb2 + 128 * lyr,
          nullptr, nullptr, nullptr, nullptr,
          nullptr, nullptr, nullptr, B_h, NN);
    }
  }

  // ---- embedding_out ----
  emb2<0><<<NB, 256, 0, stream>>>(B_h, wu + 32768, eo_b1, wu + 49152, eo_b2,
      nullptr, nullptr, nullptr, nullptr, nullptr, nullptr, nullptr, (float*)d_out, NN);
}

// Round 15
// 1164.538 us; speedup vs baseline: 1.4279x; 1.0440x over previous
//
#include <hip/hip_runtime.h>
#include <math.h>

#define NN 50000
#define NE 800000
#define HID 128
#define NNH ((size_t)NN * HID)
#define NPAD 50176

typedef __attribute__((ext_vector_type(8))) short short8;
typedef __attribute__((ext_vector_type(4))) float f32x4;
typedef __attribute__((ext_vector_type(2))) _Float16 half2v;
typedef __attribute__((ext_vector_type(8))) _Float16 half8;

__device__ __forceinline__ ushort f2bf(float f) {
  unsigned u = __float_as_uint(f);
  unsigned r = (u + 0x7fffu + ((u >> 16) & 1u)) >> 16;
  return (ushort)r;
}
__device__ __forceinline__ ushort f2h_bits(float f) {
  _Float16 h = (_Float16)f;
  ushort u;
  __builtin_memcpy(&u, &h, 2);
  return u;
}
__device__ __forceinline__ half2v u2h(uint u) {
  half2v h;
  __builtin_memcpy(&h, &u, 4);
  return h;
}
__device__ __forceinline__ float silu_f(float x) { return x / (1.0f + __expf(-x)); }

// Full-wave (64-lane) sum via DPP adds; result broadcast via readlane 63.
__device__ __forceinline__ float wsum64(float x) {
  int t;
  t = __builtin_amdgcn_update_dpp(0, __float_as_int(x), 0x111, 0xf, 0xf, true); x += __int_as_float(t);
  t = __builtin_amdgcn_update_dpp(0, __float_as_int(x), 0x112, 0xf, 0xf, true); x += __int_as_float(t);
  t = __builtin_amdgcn_update_dpp(0, __float_as_int(x), 0x114, 0xf, 0xf, true); x += __int_as_float(t);
  t = __builtin_amdgcn_update_dpp(0, __float_as_int(x), 0x118, 0xf, 0xf, true); x += __int_as_float(t);
  t = __builtin_amdgcn_update_dpp(0, __float_as_int(x), 0x142, 0xf, 0xf, true); x += __int_as_float(t);
  t = __builtin_amdgcn_update_dpp(0, __float_as_int(x), 0x143, 0xf, 0xf, true); x += __int_as_float(t);
  return __uint_as_float(__builtin_amdgcn_readlane(__float_as_int(x), 63));
}

// ---------------- utility ----------------
__global__ __launch_bounds__(256) void zero_i(int* __restrict__ p, int n)
{
  int i = blockIdx.x * 256 + threadIdx.x;
  if (i < n) p[i] = 0;
}

// ---------------- counting sort of edges by src ----------------
__global__ __launch_bounds__(256) void count_src(const int* __restrict__ src, int* __restrict__ cnt)
{
  int e = blockIdx.x * 256 + threadIdx.x;
  if (e < NE) atomicAdd(&cnt[src[e]], 1);
}

__global__ __launch_bounds__(1024) void scan_excl(const int* __restrict__ cnt, int* __restrict__ base, int n)
{
  __shared__ int ws[16];
  int t = threadIdx.x;
  const int per = (n + 1023) / 1024;
  int s0 = t * per;
  int sum = 0;
  for (int i = 0; i < per; ++i) { int idx = s0 + i; if (idx < n) sum += cnt[idx]; }
  int lane = t & 63, w = t >> 6;
  int v = sum;
  #pragma unroll
  for (int m = 1; m < 64; m <<= 1) { int o = __shfl_up(v, m, 64); if (lane >= m) v += o; }
  if (lane == 63) ws[w] = v;
  __syncthreads();
  if (t == 0) { int a = 0; for (int i = 0; i < 16; ++i) { int x = ws[i]; ws[i] = a; a += x; } }
  __syncthreads();
  int run = ws[w] + v - sum;
  for (int i = 0; i < per; ++i) {
    int idx = s0 + i;
    if (idx < n) { base[idx] = run; run += cnt[idx]; }
  }
}

// place edges into CSR order AND permute+convert ea to f16 in the same pass
__global__ __launch_bounds__(256) void place_edges(const int* __restrict__ src, const int* __restrict__ dst,
    const float4* __restrict__ ea,
    const int* __restrict__ base, int* __restrict__ cur,
    int* __restrict__ dst_s, ushort* __restrict__ ea_s)
{
  int e = blockIdx.x * 256 + threadIdx.x;
  if (e >= NE) return;
  int s = src[e];
  int p = base[s] + atomicAdd(&cur[s], 1);
  dst_s[p] = dst[e];
  const float4* ef = ea + (size_t)e * 4;
  float4 v0 = ef[0], v1 = ef[1], v2 = ef[2], v3 = ef[3];
  uint4 o0, o1;
  o0.x = (uint)f2h_bits(v0.x) | ((uint)f2h_bits(v0.y) << 16);
  o0.y = (uint)f2h_bits(v0.z) | ((uint)f2h_bits(v0.w) << 16);
  o0.z = (uint)f2h_bits(v1.x) | ((uint)f2h_bits(v1.y) << 16);
  o0.w = (uint)f2h_bits(v1.z) | ((uint)f2h_bits(v1.w) << 16);
  o1.x = (uint)f2h_bits(v2.x) | ((uint)f2h_bits(v2.y) << 16);
  o1.y = (uint)f2h_bits(v2.z) | ((uint)f2h_bits(v2.w) << 16);
  o1.z = (uint)f2h_bits(v3.x) | ((uint)f2h_bits(v3.y) << 16);
  o1.w = (uint)f2h_bits(v3.z) | ((uint)f2h_bits(v3.w) << 16);
  ushort* dp = ea_s + (size_t)p * 16;
  *(uint4*)dp = o0;
  *(uint4*)(dp + 8) = o1;
}

// ---------------- weight conversion ----------------
__global__ __launch_bounds__(256) void cvt4(const float* __restrict__ s0, const float* __restrict__ s1,
    const float* __restrict__ s2, const float* __restrict__ s3, ushort* __restrict__ d)
{
  int i = blockIdx.x * 256 + threadIdx.x;
  if (i >= 65536) return;
  const float* s = (i < 16384) ? s0 : (i < 32768) ? s1 : (i < 49152) ? s2 : s3;
  d[i] = f2bf(s[i & 16383]);
}
__global__ __launch_bounds__(256) void cvt_wab(const float* __restrict__ s, ushort* __restrict__ d)
{
  int i = blockIdx.x * 256 + threadIdx.x;
  if (i >= 131072) return;
  int l = i >> 15, rem = i & 32767;
  int r = rem >> 7, c = rem & 127;
  int srow = r & 127, scol = ((r >> 7) << 7) + c;
  d[l * 104448 + r * 128 + c] = f2bf(s[(size_t)l * 34816 + srow * 272 + scol]);
}
__global__ __launch_bounds__(256) void cvt_std(const float* __restrict__ s, ushort* __restrict__ d,
    int rows, int cols, int lss)
{
  int i = blockIdx.x * 256 + threadIdx.x;
  int n = 4 * rows * cols;
  if (i >= n) return;
  int rc = rows * cols;
  int l = i / rc, rem = i - l * rc;
  d[l * 104448 + rem] = f2bf(s[(size_t)l * lss + rem]);
}

// ---------------- fold: W2N = N1b @ W2 (f16), N1a (bf16), nv = N1b @ b2 (fp32) ----------------
__global__ __launch_bounds__(128) void fold_w(const float* __restrict__ nw1,
    const float* __restrict__ ew2, const float* __restrict__ eb2,
    ushort* __restrict__ wu_base, float* __restrict__ nv)
{
  __shared__ float red[2];
  int bid = blockIdx.x;
  int l = bid >> 7, m = bid & 127;
  int j = threadIdx.x;
  const float* n1row = nw1 + (size_t)l * 32768 + (size_t)m * 256;
  const float* n1b = n1row + 128;
  const float* w2 = ew2 + (size_t)l * 16384;
  float s = 0.f;
  for (int k = 0; k < 128; ++k) s = fmaf(n1b[k], w2[k * 128 + j], s);
  ushort* lb = wu_base + (size_t)l * 104448;
  lb[32768 + m * 128 + j] = f2h_bits(s);      // W2N as f16
  lb[49152 + m * 128 + j] = f2bf(n1row[j]);   // N1a bf16
  float p = n1b[j] * eb2[l * 128 + j];
  #pragma unroll
  for (int mm = 1; mm < 64; mm <<= 1) p += __shfl_xor(p, mm, 64);
  if ((j & 63) == 0) red[j >> 6] = p;
  __syncthreads();
  if (j == 0) nv[l * 128 + m] = red[0] + red[1];
}

// ---------------- fused 2-layer MLP, optional pab tail (Pa/Pb f16) ----------------
template<int FUSE>
__global__ __launch_bounds__(256) void emb2(
    const float* __restrict__ A,
    const ushort* __restrict__ W1, const float* __restrict__ b1,
    const ushort* __restrict__ W2, const float* __restrict__ b2,
    const float* __restrict__ lg, const float* __restrict__ lbp,
    const ushort* __restrict__ Wab, const float* __restrict__ eb1,
    float* __restrict__ Hn, ushort* __restrict__ Pa, ushort* __restrict__ Pb,
    float* __restrict__ C, int n)
{
  __shared__ ushort Al[64][136];
  const int tid = threadIdx.x;
  const int n0 = blockIdx.x * 64;

  #pragma unroll
  for (int i = 0; i < 8; ++i) {
    int s = tid + i * 256;
    int row = s >> 5, c4 = (s & 31) * 4;
    int gr = n0 + row;
    float4 v = make_float4(0.f, 0.f, 0.f, 0.f);
    if (gr < n) v = *(const float4*)(A + (size_t)gr * HID + c4);
    uint2 p;
    p.x = (uint)f2bf(v.x) | ((uint)f2bf(v.y) << 16);
    p.y = (uint)f2bf(v.z) | ((uint)f2bf(v.w) << 16);
    *(uint2*)&Al[row][c4] = p;
  }
  __syncthreads();

  const int w = tid >> 6, l = tid & 63;
  const int lr = l & 15, lh = l >> 4;

  f32x4 zf = {0.f, 0.f, 0.f, 0.f};
  f32x4 acc[8];
  #pragma unroll
  for (int nt = 0; nt < 8; ++nt) acc[nt] = zf;

  #pragma unroll
  for (int q = 0; q < 4; ++q) {
    short8 af = *(const short8*)&Al[w * 16 + lr][q * 32 + lh * 8];
    #pragma unroll
    for (int nt = 0; nt < 8; ++nt) {
      short8 bf = *(const short8*)(W1 + (size_t)(nt * 16 + lr) * HID + q * 32 + lh * 8);
      acc[nt] = __builtin_amdgcn_mfma_f32_16x16x32_bf16(af, bf, acc[nt], 0, 0, 0);
    }
  }

  float vb[8];
  #pragma unroll
  for (int nt = 0; nt < 8; ++nt) vb[nt] = b1[nt * 16 + lr];

  #pragma unroll
  for (int r = 0; r < 4; ++r) {
    int row = w * 16 + lh * 4 + r;
    #pragma unroll
    for (int nt = 0; nt < 8; ++nt)
      Al[row][nt * 16 + lr] = f2bf(silu_f(acc[nt][r] + vb[nt]));
  }

  f32x4 acc2[8];
  #pragma unroll
  for (int nt = 0; nt < 8; ++nt) acc2[nt] = zf;
  #pragma unroll
  for (int q = 0; q < 4; ++q) {
    short8 af = *(const short8*)&Al[w * 16 + lr][q * 32 + lh * 8];
    #pragma unroll
    for (int nt = 0; nt < 8; ++nt) {
      short8 bf = *(const short8*)(W2 + (size_t)(nt * 16 + lr) * HID + q * 32 + lh * 8);
      acc2[nt] = __builtin_amdgcn_mfma_f32_16x16x32_bf16(af, bf, acc2[nt], 0, 0, 0);
    }
  }

  float vb2[8];
  #pragma unroll
  for (int nt = 0; nt < 8; ++nt) vb2[nt] = b2[nt * 16 + lr];

  if (FUSE == 0) {
    #pragma unroll
    for (int r = 0; r < 4; ++r) {
      int row = n0 + w * 16 + lh * 4 + r;
      if (row < n) {
        float* cr = C + (size_t)row * HID;
        #pragma unroll
        for (int nt = 0; nt < 8; ++nt)
          cr[nt * 16 + lr] = acc2[nt][r] + vb2[nt];
      }
    }
    return;
  }

  float gv[8], bv[8];
  #pragma unroll
  for (int nt = 0; nt < 8; ++nt) { gv[nt] = lg[nt * 16 + lr]; bv[nt] = lbp[nt * 16 + lr]; }

  #pragma unroll
  for (int r = 0; r < 4; ++r) {
    int row = n0 + w * 16 + lh * 4 + r;
    bool ok = row < n;
    float vals[8];
    #pragma unroll
    for (int nt = 0; nt < 8; ++nt) vals[nt] = acc2[nt][r] + vb2[nt];
    float s1 = 0.f, s2 = 0.f;
    #pragma unroll
    for (int nt = 0; nt < 8; ++nt) { s1 += vals[nt]; s2 += vals[nt] * vals[nt]; }
    #pragma unroll
    for (int m = 1; m < 16; m <<= 1) { s1 += __shfl_xor(s1, m, 64); s2 += __shfl_xor(s2, m, 64); }
    float mu = s1 * (1.0f / 128.0f);
    float var = s2 * (1.0f / 128.0f) - mu * mu;
    float rs = rsqrtf(var + 1e-5f);
    int lrow = w * 16 + lh * 4 + r;
    float* hnr = Hn + (size_t)row * HID;
    #pragma unroll
    for (int nt = 0; nt < 8; ++nt) {
      float hn = (vals[nt] - mu) * rs * gv[nt] + bv[nt];
      if (ok) hnr[nt * 16 + lr] = hn;
      Al[lrow][nt * 16 + lr] = f2bf(hn);
    }
  }

  f32x4 aab[16];
  #pragma unroll
  for (int nt = 0; nt < 16; ++nt) aab[nt] = zf;
  #pragma unroll
  for (int q = 0; q < 4; ++q) {
    short8 af = *(const short8*)&Al[w * 16 + lr][q * 32 + lh * 8];
    #pragma unroll
    for (int nt = 0; nt < 16; ++nt) {
      short8 bf = *(const short8*)(Wab + (size_t)(nt * 16 + lr) * HID + q * 32 + lh * 8);
      aab[nt] = __builtin_amdgcn_mfma_f32_16x16x32_bf16(af, bf, aab[nt], 0, 0, 0);
    }
  }
  float be[8];
  #pragma unroll
  for (int nt = 0; nt < 8; ++nt) be[nt] = eb1[nt * 16 + lr];
  #pragma unroll
  for (int r = 0; r < 4; ++r) {
    int row = n0 + w * 16 + lh * 4 + r;
    if (row >= n) break;
    ushort* pa = Pa + (size_t)row * HID;
    ushort* pb = Pb + (size_t)row * HID;
    #pragma unroll
    for (int nt = 0; nt < 8; ++nt) {
      int col = nt * 16 + lr;
      pa[col] = f2h_bits(aab[nt][r] + be[nt]);
      pb[col] = f2h_bits(aab[nt + 8][r]);
    }
  }
}

// ---------------- per-node CSR edge kernel: f16 Pa/Pb/ea, fdot2 + DPP reduce ----------------
__global__ __launch_bounds__(256) void node_edge(
    const ushort* __restrict__ Pah, const ushort* __restrict__ Pbh,
    const ushort* __restrict__ ea_h,
    const int* __restrict__ dst_s,
    const int* __restrict__ ebase, const int* __restrict__ deg,
    const float* __restrict__ w1c,
    const float* __restrict__ elg, const float* __restrict__ elb,
    ushort* __restrict__ Sh, int n)
{
  const int tid = threadIdx.x;
  const int wv = __builtin_amdgcn_readfirstlane(tid >> 6);
  const int lane = tid & 63;
  const int node = blockIdx.x * 4 + wv;
  if (node >= n) return;
  const int c0 = lane * 2;

  half2v w1h0[8], w1h1[8];
  {
    const float* wr0 = w1c + (size_t)c0 * 272 + 256;
    const float* wr1 = wr0 + 272;
    #pragma unroll
    for (int k = 0; k < 8; ++k) {
      half2v h0; h0[0] = (_Float16)wr0[2 * k]; h0[1] = (_Float16)wr0[2 * k + 1]; w1h0[k] = h0;
      half2v h1; h1[0] = (_Float16)wr1[2 * k]; h1[1] = (_Float16)wr1[2 * k + 1]; w1h1[k] = h1;
    }
  }
  const float g0 = elg[c0], g1 = elg[c0 + 1];
  const float b0 = elb[c0], b1 = elb[c0 + 1];
  half2v pav = u2h(*(const uint*)(Pah + (size_t)node * HID + c0));
  const float pax = (float)pav[0];
  const float pay = (float)pav[1];

  const int beg = __builtin_amdgcn_readfirstlane(ebase[node]);
  const int dg  = __builtin_amdgcn_readfirstlane(deg[node]);

  float a0 = 0.f, a1 = 0.f;

  uint4 eA0 = make_uint4(0,0,0,0), eB0 = eA0, eA1 = eA0, eB1 = eA0;
  uint p0 = 0, p1 = 0;

  auto LOADE = [&](int idx, uint4& ea, uint4& eb, uint& pb) {
    int eu = __builtin_amdgcn_readfirstlane(beg + idx);
    int d  = dst_s[eu];
    ea = *(const uint4*)(ea_h + (size_t)eu * 16);
    eb = *(const uint4*)(ea_h + (size_t)eu * 16 + 8);
    pb = *(const uint*)(Pbh + (size_t)d * HID + c0);
  };
  auto PROCESS = [&](const uint4& eaA, const uint4& eaB, uint pbu) {
    half2v eh[8];
    eh[0] = u2h(eaA.x); eh[1] = u2h(eaA.y); eh[2] = u2h(eaA.z); eh[3] = u2h(eaA.w);
    eh[4] = u2h(eaB.x); eh[5] = u2h(eaB.y); eh[6] = u2h(eaB.z); eh[7] = u2h(eaB.w);
    half2v pb2 = u2h(pbu);

    float x0 = pax + (float)pb2[0];
    float x1 = pay + (float)pb2[1];
    #pragma unroll
    for (int k = 0; k < 8; ++k) {
      x0 = __builtin_amdgcn_fdot2(eh[k], w1h0[k], x0, false);
      x1 = __builtin_amdgcn_fdot2(eh[k], w1h1[k], x1, false);
    }
    float s1 = wsum64(x0 + x1);
    float s2 = wsum64(fmaf(x0, x0, x1 * x1));
    float mu = s1 * (1.0f / 128.0f);
    float var = s2 * (1.0f / 128.0f) - mu * mu;
    float rs = rsqrtf(var + 1e-5f);
    a0 += silu_f((x0 - mu) * rs * g0 + b0);
    a1 += silu_f((x1 - mu) * rs * g1 + b1);
  };

  if (dg > 0) LOADE(0, eA0, eB0, p0);
  if (dg > 1) LOADE(1, eA1, eB1, p1);

  for (int i = 0; i < dg; i += 2) {
    uint4 nA0 = make_uint4(0,0,0,0), nB0 = nA0, nA1 = nA0, nB1 = nA0;
    uint np0 = 0, np1 = 0;
    if (i + 2 < dg) LOADE(i + 2, nA0, nB0, np0);
    if (i + 3 < dg) LOADE(i + 3, nA1, nB1, np1);

    PROCESS(eA0, eB0, p0);
    if (i + 1 < dg) PROCESS(eA1, eB1, p1);

    eA0 = nA0; eB0 = nB0; p0 = np0;
    eA1 = nA1; eB1 = nB1; p1 = np1;
  }

  uint pk = (uint)f2h_bits(a0) | ((uint)f2h_bits(a1) << 16);
  *(uint*)(Sh + (size_t)node * HID + c0) = pk;
}

// ---------------- fused node MLP (+ optional next-layer pab), S f16, Pa/Pb f16 out ----------------
template<int FUSE>
__global__ __launch_bounds__(256) void node_mlp(
    const float* __restrict__ Hn, const ushort* __restrict__ Sh,
    const ushort* __restrict__ N1a, const ushort* __restrict__ W2Nh, const ushort* __restrict__ N2,
    const float* __restrict__ nb1, const float* __restrict__ nv, const int* __restrict__ deg,
    const float* __restrict__ lng, const float* __restrict__ lnb, const float* __restrict__ nb2,
    const float* __restrict__ lg2, const float* __restrict__ lb2p,
    const ushort* __restrict__ Wab2, const float* __restrict__ eb1_2,
    float* __restrict__ HnOut, ushort* __restrict__ Pa, ushort* __restrict__ Pb,
    float* __restrict__ C, int n)
{
  __shared__ ushort Ahn[64][136];
  __shared__ ushort Ash[64][136];
  const int tid = threadIdx.x;
  const int n0 = blockIdx.x * 64;

  #pragma unroll
  for (int i = 0; i < 8; ++i) {
    int s = tid + i * 256;
    int row = s >> 5, c4 = (s & 31) * 4;
    int gr = n0 + row;
    float4 vh = make_float4(0.f, 0.f, 0.f, 0.f);
    uint2 sv = make_uint2(0, 0);
    if (gr < n) {
      vh = *(const float4*)(Hn + (size_t)gr * HID + c4);
      sv = *(const uint2*)(Sh + (size_t)gr * HID + c4);
    }
    uint2 ph;
    ph.x = (uint)f2bf(vh.x) | ((uint)f2bf(vh.y) << 16);
    ph.y = (uint)f2bf(vh.z) | ((uint)f2bf(vh.w) << 16);
    *(uint2*)&Ahn[row][c4] = ph;
    *(uint2*)&Ash[row][c4] = sv;
  }
  __syncthreads();

  const int w = tid >> 6, l = tid & 63;
  const int lr = l & 15, lh = l >> 4;

  f32x4 zf = {0.f, 0.f, 0.f, 0.f};
  f32x4 acc[8];
  #pragma unroll
  for (int nt = 0; nt < 8; ++nt) acc[nt] = zf;

  #pragma unroll
  for (int q = 0; q < 4; ++q) {
    short8 an = *(const short8*)&Ahn[w * 16 + lr][q * 32 + lh * 8];
    half8  as = *(const half8*)&Ash[w * 16 + lr][q * 32 + lh * 8];
    #pragma unroll
    for (int nt = 0; nt < 8; ++nt) {
      short8 b1f = *(const short8*)(N1a + (size_t)(nt * 16 + lr) * HID + q * 32 + lh * 8);
      half8  b2h = *(const half8*)(W2Nh + (size_t)(nt * 16 + lr) * HID + q * 32 + lh * 8);
      acc[nt] = __builtin_amdgcn_mfma_f32_16x16x32_bf16(an, b1f, acc[nt], 0, 0, 0);
      acc[nt] = __builtin_amdgcn_mfma_f32_16x16x32_f16(as, b2h, acc[nt], 0, 0, 0);
    }
  }

  float vb[8], vn[8], gv[8], bv[8];
  #pragma unroll
  for (int nt = 0; nt < 8; ++nt) {
    int col = nt * 16 + lr;
    vb[nt] = nb1[col]; vn[nt] = nv[col];
    gv[nt] = lng[col]; bv[nt] = lnb[col];
  }

  #pragma unroll
  for (int r = 0; r < 4; ++r) {
    int row = n0 + w * 16 + lh * 4 + r;
    float degf = (row < n) ? (float)deg[row] : 0.f;
    float vals[8];
    #pragma unroll
    for (int nt = 0; nt < 8; ++nt) vals[nt] = acc[nt][r] + vb[nt] + degf * vn[nt];
    float s1 = 0.f, s2 = 0.f;
    #pragma unroll
    for (int nt = 0; nt < 8; ++nt) { s1 += vals[nt]; s2 += vals[nt] * vals[nt]; }
    #pragma unroll
    for (int m = 1; m < 16; m <<= 1) { s1 += __shfl_xor(s1, m, 64); s2 += __shfl_xor(s2, m, 64); }
    float mu = s1 * (1.0f / 128.0f);
    float var = s2 * (1.0f / 128.0f) - mu * mu;
    float rs = rsqrtf(var + 1e-5f);
    int lrow = w * 16 + lh * 4 + r;
    #pragma unroll
    for (int nt = 0; nt < 8; ++nt)
      Ahn[lrow][nt * 16 + lr] = f2bf(silu_f((vals[nt] - mu) * rs * gv[nt] + bv[nt]));
  }

  f32x4 acc2[8];
  #pragma unroll
  for (int nt = 0; nt < 8; ++nt) acc2[nt] = zf;
  #pragma unroll
  for (int q = 0; q < 4; ++q) {
    short8 af = *(const short8*)&Ahn[w * 16 + lr][q * 32 + lh * 8];
    #pragma unroll
    for (int nt = 0; nt < 8; ++nt) {
      short8 bf = *(const short8*)(N2 + (size_t)(nt * 16 + lr) * HID + q * 32 + lh * 8);
      acc2[nt] = __builtin_amdgcn_mfma_f32_16x16x32_bf16(af, bf, acc2[nt], 0, 0, 0);
    }
  }

  float vb2[8];
  #pragma unroll
  for (int nt = 0; nt < 8; ++nt) vb2[nt] = nb2[nt * 16 + lr];

  if (FUSE == 0) {
    #pragma unroll
    for (int r = 0; r < 4; ++r) {
      int row = n0 + w * 16 + lh * 4 + r;
      if (row < n) {
        const float* hr = Hn + (size_t)row * HID;
        float* cr = C + (size_t)row * HID;
        #pragma unroll
        for (int nt = 0; nt < 8; ++nt) {
          int col = nt * 16 + lr;
          cr[col] = hr[col] + acc2[nt][r] + vb2[nt];
        }
      }
    }
    return;
  }

  float gv2[8], bv2[8];
  #pragma unroll
  for (int nt = 0; nt < 8; ++nt) { gv2[nt] = lg2[nt * 16 + lr]; bv2[nt] = lb2p[nt * 16 + lr]; }

  #pragma unroll
  for (int r = 0; r < 4; ++r) {
    int row = n0 + w * 16 + lh * 4 + r;
    bool ok = row < n;
    const float* hr = Hn + (size_t)row * HID;
    float vals[8];
    #pragma unroll
    for (int nt = 0; nt < 8; ++nt) {
      int col = nt * 16 + lr;
      float base = ok ? hr[col] : 0.f;
      vals[nt] = base + acc2[nt][r] + vb2[nt];
    }
    float s1 = 0.f, s2 = 0.f;
    #pragma unroll
    for (int nt = 0; nt < 8; ++nt) { s1 += vals[nt]; s2 += vals[nt] * vals[nt]; }
    #pragma unroll
    for (int m = 1; m < 16; m <<= 1) { s1 += __shfl_xor(s1, m, 64); s2 += __shfl_xor(s2, m, 64); }
    float mu = s1 * (1.0f / 128.0f);
    float var = s2 * (1.0f / 128.0f) - mu * mu;
    float rs = rsqrtf(var + 1e-5f);
    int lrow = w * 16 + lh * 4 + r;
    float* hnr = HnOut + (size_t)row * HID;
    #pragma unroll
    for (int nt = 0; nt < 8; ++nt) {
      float hn = (vals[nt] - mu) * rs * gv2[nt] + bv2[nt];
      if (ok) hnr[nt * 16 + lr] = hn;
      Ahn[lrow][nt * 16 + lr] = f2bf(hn);
    }
  }

  f32x4 aab[16];
  #pragma unroll
  for (int nt = 0; nt < 16; ++nt) aab[nt] = zf;
  #pragma unroll
  for (int q = 0; q < 4; ++q) {
    short8 af = *(const short8*)&Ahn[w * 16 + lr][q * 32 + lh * 8];
    #pragma unroll
    for (int nt = 0; nt < 16; ++nt) {
      short8 bf = *(const short8*)(Wab2 + (size_t)(nt * 16 + lr) * HID + q * 32 + lh * 8);
      aab[nt] = __builtin_amdgcn_mfma_f32_16x16x32_bf16(af, bf, aab[nt], 0, 0, 0);
    }
  }
  float be[8];
  #pragma unroll
  for (int nt = 0; nt < 8; ++nt) be[nt] = eb1_2[nt * 16 + lr];
  #pragma unroll
  for (int r = 0; r < 4; ++r) {
    int row = n0 + w * 16 + lh * 4 + r;
    if (row >= n) break;
    ushort* pa = Pa + (size_t)row * HID;
    ushort* pb = Pb + (size_t)row * HID;
    #pragma unroll
    for (int nt = 0; nt < 8; ++nt) {
      int col = nt * 16 + lr;
      pa[col] = f2h_bits(aab[nt][r] + be[nt]);
      pb[col] = f2h_bits(aab[nt + 8][r]);
    }
  }
}

extern "C" void kernel_launch(void* const* d_in, const int* in_sizes, int n_in,
                              void* d_out, int out_size, void* d_ws, size_t ws_size,
                              hipStream_t stream)
{
  const float* in_h  = (const float*)d_in[0];
  const int*   edges = (const int*)d_in[1];
  const float* ea    = (const float*)d_in[2];
  const float* ei_w1 = (const float*)d_in[3];
  const float* ei_b1 = (const float*)d_in[4];
  const float* ei_w2 = (const float*)d_in[5];
  const float* ei_b2 = (const float*)d_in[6];
  const float* ng    = (const float*)d_in[7];
  const float* nbp   = (const float*)d_in[8];
  const float* ew1   = (const float*)d_in[9];
  const float* eb1   = (const float*)d_in[10];
  const float* elg   = (const float*)d_in[11];
  const float* elb   = (const float*)d_in[12];
  const float* ew2   = (const float*)d_in[13];
  const float* eb2   = (const float*)d_in[14];
  const float* nw1   = (const float*)d_in[15];
  const float* nb1   = (const float*)d_in[16];
  const float* nlg   = (const float*)d_in[17];
  const float* nlb   = (const float*)d_in[18];
  const float* nw2   = (const float*)d_in[19];
  const float* nb2   = (const float*)d_in[20];
  const float* eo_w1 = (const float*)d_in[21];
  const float* eo_b1 = (const float*)d_in[22];
  const float* eo_w2 = (const float*)d_in[23];
  const float* eo_b2 = (const float*)d_in[24];

  float* wf    = (float*)d_ws;
  float* B_h   = wf;
  float* B_hn  = wf + NNH;
  float* B_S   = wf + 2 * NNH;
  float* B_tmp = wf + 3 * NNH;   // Pa (f16, half used)
  float* B_pb  = wf + 4 * NNH;   // Pb (f16, half used)
  ushort* Sh   = (ushort*)B_S;
  ushort* Pah  = (ushort*)B_tmp;
  ushort* Pbh  = (ushort*)B_pb;

  const size_t WOFF = 5 * NNH;
  ushort* wu = (ushort*)(wf + WOFF);
  // ei1@0, ei2@16384, eo1@32768, eo2@49152; per-layer base 65536 + l*104448:
  //   Wab@0 [256][128] | W2N(f16)@32768 | N1a@49152 | N2@81920
  const size_t SOFF = WOFF + 262144;
  int* dst_s = (int*)(wf + SOFF);
  int* cnt   = dst_s + NE;       // = deg
  int* cur   = cnt + NPAD;
  int* base  = cur + NPAD;
  ushort* ea_s = (ushort*)(base + NPAD);
  float* nvb = (float*)(ea_s + (size_t)NE * 16);   // 4*128 fp32

  const int NB  = (NN + 63) / 64;
  const int NBE = (NN + 3) / 4;
  const int NEB = (NE + 255) / 256;

  const int* erow = edges;
  const int* ecol = edges + NE;

  // ---- counting sort by src (once; ea permute+cvt fused into placement) ----
  zero_i<<<(2 * NPAD + 255) / 256, 256, 0, stream>>>(cnt, 2 * NPAD);
  count_src<<<NEB, 256, 0, stream>>>(erow, cnt);
  scan_excl<<<1, 1024, 0, stream>>>(cnt, base, NN);
  place_edges<<<NEB, 256, 0, stream>>>(erow, ecol, (const float4*)ea, base, cur, dst_s, ea_s);

  // ---- weight conversion / folding ----
  cvt4<<<256, 256, 0, stream>>>(ei_w1, ei_w2, eo_w1, eo_w2, wu);
  cvt_wab<<<512, 256, 0, stream>>>(ew1, wu + 65536);
  cvt_std<<<(4 * 16384 + 255) / 256, 256, 0, stream>>>(nw2, wu + 65536 + 81920, 128, 128, 16384);
  fold_w<<<512, 128, 0, stream>>>(nw1, ew2, eb2, wu + 65536, nvb);

  // ---- embedding_in fused with layer-0 pab_ln ----
  emb2<1><<<NB, 256, 0, stream>>>(in_h, wu, ei_b1, wu + 16384, ei_b2,
      ng, nbp, wu + 65536, eb1, B_hn, Pah, Pbh, nullptr, NN);

  for (int lyr = 0; lyr < 4; ++lyr) {
    ushort* lb = wu + 65536 + lyr * 104448;
    node_edge<<<NBE, 256, 0, stream>>>(Pah, Pbh, ea_s, dst_s, base, cnt,
        ew1 + 34816 * lyr, elg + 128 * lyr, elb + 128 * lyr, Sh, NN);
    if (lyr < 3) {
      ushort* lb2 = lb + 104448;
      node_mlp<1><<<NB, 256, 0, stream>>>(B_hn, Sh, lb + 49152, lb + 32768, lb + 81920,
          nb1 + 128 * lyr, nvb + 128 * lyr, cnt,
          nlg + 128 * lyr, nlb + 128 * lyr, nb2 + 128 * lyr,
          ng + 128 * (lyr + 1), nbp + 128 * (lyr + 1), lb2, eb1 + 128 * (lyr + 1),
          B_hn, Pah, Pbh, nullptr, NN);
    } else {
      node_mlp<0><<<NB, 256, 0, stream>>>(B_hn, Sh, lb + 49152, lb + 32768, lb + 81920,
          nb1 + 128 * lyr, nvb + 128 * lyr, cnt,
          nlg + 128 * lyr, nlb + 128 * lyr, nb2 + 128 * lyr,
          nullptr, nullptr, nullptr, nullptr,
          nullptr, nullptr, nullptr, B_h, NN);
    }
  }

  // ---- embedding_out ----
  emb2<0><<<NB, 256, 0, stream>>>(B_h, wu + 32768, eo_b1, wu + 49152, eo_b2,
      nullptr, nullptr, nullptr, nullptr, nullptr, nullptr, nullptr, (float*)d_out, NN);
}

// Round 16
// 1150.972 us; speedup vs baseline: 1.4447x; 1.0118x over previous
//
#include <hip/hip_runtime.h>
#include <math.h>

#define NN 50000
#define NE 800000
#define HID 128
#define NNH ((size_t)NN * HID)
#define NPAD 50176

typedef __attribute__((ext_vector_type(8))) short short8;
typedef __attribute__((ext_vector_type(4))) float f32x4;
typedef __attribute__((ext_vector_type(2))) _Float16 half2v;
typedef __attribute__((ext_vector_type(8))) _Float16 half8;

__device__ __forceinline__ ushort f2bf(float f) {
  unsigned u = __float_as_uint(f);
  unsigned r = (u + 0x7fffu + ((u >> 16) & 1u)) >> 16;
  return (ushort)r;
}
__device__ __forceinline__ ushort f2h_bits(float f) {
  _Float16 h = (_Float16)f;
  ushort u;
  __builtin_memcpy(&u, &h, 2);
  return u;
}
__device__ __forceinline__ half2v u2h(uint u) {
  half2v h;
  __builtin_memcpy(&h, &u, 4);
  return h;
}
__device__ __forceinline__ float silu_f(float x) { return x / (1.0f + __expf(-x)); }

// Full-wave (64-lane) sum via DPP adds; result broadcast via readlane 63.
__device__ __forceinline__ float wsum64(float x) {
  int t;
  t = __builtin_amdgcn_update_dpp(0, __float_as_int(x), 0x111, 0xf, 0xf, true); x += __int_as_float(t);
  t = __builtin_amdgcn_update_dpp(0, __float_as_int(x), 0x112, 0xf, 0xf, true); x += __int_as_float(t);
  t = __builtin_amdgcn_update_dpp(0, __float_as_int(x), 0x114, 0xf, 0xf, true); x += __int_as_float(t);
  t = __builtin_amdgcn_update_dpp(0, __float_as_int(x), 0x118, 0xf, 0xf, true); x += __int_as_float(t);
  t = __builtin_amdgcn_update_dpp(0, __float_as_int(x), 0x142, 0xf, 0xf, true); x += __int_as_float(t);
  t = __builtin_amdgcn_update_dpp(0, __float_as_int(x), 0x143, 0xf, 0xf, true); x += __int_as_float(t);
  return __uint_as_float(__builtin_amdgcn_readlane(__float_as_int(x), 63));
}

// ---------------- utility ----------------
__global__ __launch_bounds__(256) void zero_i(int* __restrict__ p, int n)
{
  int i = blockIdx.x * 256 + threadIdx.x;
  if (i < n) p[i] = 0;
}

// ---------------- counting sort of edges by src ----------------
__global__ __launch_bounds__(256) void count_src(const int* __restrict__ src, int* __restrict__ cnt)
{
  int e = blockIdx.x * 256 + threadIdx.x;
  if (e < NE) atomicAdd(&cnt[src[e]], 1);
}

__global__ __launch_bounds__(1024) void scan_excl(const int* __restrict__ cnt, int* __restrict__ base, int n)
{
  __shared__ int ws[16];
  int t = threadIdx.x;
  const int per = (n + 1023) / 1024;
  int s0 = t * per;
  int sum = 0;
  for (int i = 0; i < per; ++i) { int idx = s0 + i; if (idx < n) sum += cnt[idx]; }
  int lane = t & 63, w = t >> 6;
  int v = sum;
  #pragma unroll
  for (int m = 1; m < 64; m <<= 1) { int o = __shfl_up(v, m, 64); if (lane >= m) v += o; }
  if (lane == 63) ws[w] = v;
  __syncthreads();
  if (t == 0) { int a = 0; for (int i = 0; i < 16; ++i) { int x = ws[i]; ws[i] = a; a += x; } }
  __syncthreads();
  int run = ws[w] + v - sum;
  for (int i = 0; i < per; ++i) {
    int idx = s0 + i;
    if (idx < n) { base[idx] = run; run += cnt[idx]; }
  }
}

// place edges into CSR order AND permute+convert ea to f16 in the same pass
__global__ __launch_bounds__(256) void place_edges(const int* __restrict__ src, const int* __restrict__ dst,
    const float4* __restrict__ ea,
    const int* __restrict__ base, int* __restrict__ cur,
    int* __restrict__ dst_s, ushort* __restrict__ ea_s)
{
  int e = blockIdx.x * 256 + threadIdx.x;
  if (e >= NE) return;
  int s = src[e];
  int p = base[s] + atomicAdd(&cur[s], 1);
  dst_s[p] = dst[e];
  const float4* ef = ea + (size_t)e * 4;
  float4 v0 = ef[0], v1 = ef[1], v2 = ef[2], v3 = ef[3];
  uint4 o0, o1;
  o0.x = (uint)f2h_bits(v0.x) | ((uint)f2h_bits(v0.y) << 16);
  o0.y = (uint)f2h_bits(v0.z) | ((uint)f2h_bits(v0.w) << 16);
  o0.z = (uint)f2h_bits(v1.x) | ((uint)f2h_bits(v1.y) << 16);
  o0.w = (uint)f2h_bits(v1.z) | ((uint)f2h_bits(v1.w) << 16);
  o1.x = (uint)f2h_bits(v2.x) | ((uint)f2h_bits(v2.y) << 16);
  o1.y = (uint)f2h_bits(v2.z) | ((uint)f2h_bits(v2.w) << 16);
  o1.z = (uint)f2h_bits(v3.x) | ((uint)f2h_bits(v3.y) << 16);
  o1.w = (uint)f2h_bits(v3.z) | ((uint)f2h_bits(v3.w) << 16);
  ushort* dp = ea_s + (size_t)p * 16;
  *(uint4*)dp = o0;
  *(uint4*)(dp + 8) = o1;
}

// ---------------- weight conversion ----------------
__global__ __launch_bounds__(256) void cvt4(const float* __restrict__ s0, const float* __restrict__ s1,
    const float* __restrict__ s2, const float* __restrict__ s3, ushort* __restrict__ d)
{
  int i = blockIdx.x * 256 + threadIdx.x;
  if (i >= 65536) return;
  const float* s = (i < 16384) ? s0 : (i < 32768) ? s1 : (i < 49152) ? s2 : s3;
  d[i] = f2bf(s[i & 16383]);
}
__global__ __launch_bounds__(256) void cvt_wab(const float* __restrict__ s, ushort* __restrict__ d)
{
  int i = blockIdx.x * 256 + threadIdx.x;
  if (i >= 131072) return;
  int l = i >> 15, rem = i & 32767;
  int r = rem >> 7, c = rem & 127;
  int srow = r & 127, scol = ((r >> 7) << 7) + c;
  d[l * 104448 + r * 128 + c] = f2bf(s[(size_t)l * 34816 + srow * 272 + scol]);
}
__global__ __launch_bounds__(256) void cvt_std(const float* __restrict__ s, ushort* __restrict__ d,
    int rows, int cols, int lss)
{
  int i = blockIdx.x * 256 + threadIdx.x;
  int n = 4 * rows * cols;
  if (i >= n) return;
  int rc = rows * cols;
  int l = i / rc, rem = i - l * rc;
  d[l * 104448 + rem] = f2bf(s[(size_t)l * lss + rem]);
}

// ---------------- fold: W2N = N1b @ W2 (f16), N1a (bf16), nv = N1b @ b2 (fp32) ----------------
__global__ __launch_bounds__(128) void fold_w(const float* __restrict__ nw1,
    const float* __restrict__ ew2, const float* __restrict__ eb2,
    ushort* __restrict__ wu_base, float* __restrict__ nv)
{
  __shared__ float red[2];
  int bid = blockIdx.x;
  int l = bid >> 7, m = bid & 127;
  int j = threadIdx.x;
  const float* n1row = nw1 + (size_t)l * 32768 + (size_t)m * 256;
  const float* n1b = n1row + 128;
  const float* w2 = ew2 + (size_t)l * 16384;
  float s = 0.f;
  for (int k = 0; k < 128; ++k) s = fmaf(n1b[k], w2[k * 128 + j], s);
  ushort* lb = wu_base + (size_t)l * 104448;
  lb[32768 + m * 128 + j] = f2h_bits(s);      // W2N as f16
  lb[49152 + m * 128 + j] = f2bf(n1row[j]);   // N1a bf16
  float p = n1b[j] * eb2[l * 128 + j];
  #pragma unroll
  for (int mm = 1; mm < 64; mm <<= 1) p += __shfl_xor(p, mm, 64);
  if ((j & 63) == 0) red[j >> 6] = p;
  __syncthreads();
  if (j == 0) nv[l * 128 + m] = red[0] + red[1];
}

// ---------------- fused 2-layer MLP, optional pab tail (Pa/Pb f16) ----------------
template<int FUSE>
__global__ __launch_bounds__(256) void emb2(
    const float* __restrict__ A,
    const ushort* __restrict__ W1, const float* __restrict__ b1,
    const ushort* __restrict__ W2, const float* __restrict__ b2,
    const float* __restrict__ lg, const float* __restrict__ lbp,
    const ushort* __restrict__ Wab, const float* __restrict__ eb1,
    float* __restrict__ Hn, ushort* __restrict__ Pa, ushort* __restrict__ Pb,
    float* __restrict__ C, int n)
{
  __shared__ ushort Al[64][136];
  const int tid = threadIdx.x;
  const int n0 = blockIdx.x * 64;

  #pragma unroll
  for (int i = 0; i < 8; ++i) {
    int s = tid + i * 256;
    int row = s >> 5, c4 = (s & 31) * 4;
    int gr = n0 + row;
    float4 v = make_float4(0.f, 0.f, 0.f, 0.f);
    if (gr < n) v = *(const float4*)(A + (size_t)gr * HID + c4);
    uint2 p;
    p.x = (uint)f2bf(v.x) | ((uint)f2bf(v.y) << 16);
    p.y = (uint)f2bf(v.z) | ((uint)f2bf(v.w) << 16);
    *(uint2*)&Al[row][c4] = p;
  }
  __syncthreads();

  const int w = tid >> 6, l = tid & 63;
  const int lr = l & 15, lh = l >> 4;

  f32x4 zf = {0.f, 0.f, 0.f, 0.f};
  f32x4 acc[8];
  #pragma unroll
  for (int nt = 0; nt < 8; ++nt) acc[nt] = zf;

  #pragma unroll
  for (int q = 0; q < 4; ++q) {
    short8 af = *(const short8*)&Al[w * 16 + lr][q * 32 + lh * 8];
    #pragma unroll
    for (int nt = 0; nt < 8; ++nt) {
      short8 bf = *(const short8*)(W1 + (size_t)(nt * 16 + lr) * HID + q * 32 + lh * 8);
      acc[nt] = __builtin_amdgcn_mfma_f32_16x16x32_bf16(af, bf, acc[nt], 0, 0, 0);
    }
  }

  float vb[8];
  #pragma unroll
  for (int nt = 0; nt < 8; ++nt) vb[nt] = b1[nt * 16 + lr];

  #pragma unroll
  for (int r = 0; r < 4; ++r) {
    int row = w * 16 + lh * 4 + r;
    #pragma unroll
    for (int nt = 0; nt < 8; ++nt)
      Al[row][nt * 16 + lr] = f2bf(silu_f(acc[nt][r] + vb[nt]));
  }

  f32x4 acc2[8];
  #pragma unroll
  for (int nt = 0; nt < 8; ++nt) acc2[nt] = zf;
  #pragma unroll
  for (int q = 0; q < 4; ++q) {
    short8 af = *(const short8*)&Al[w * 16 + lr][q * 32 + lh * 8];
    #pragma unroll
    for (int nt = 0; nt < 8; ++nt) {
      short8 bf = *(const short8*)(W2 + (size_t)(nt * 16 + lr) * HID + q * 32 + lh * 8);
      acc2[nt] = __builtin_amdgcn_mfma_f32_16x16x32_bf16(af, bf, acc2[nt], 0, 0, 0);
    }
  }

  float vb2[8];
  #pragma unroll
  for (int nt = 0; nt < 8; ++nt) vb2[nt] = b2[nt * 16 + lr];

  if (FUSE == 0) {
    #pragma unroll
    for (int r = 0; r < 4; ++r) {
      int row = n0 + w * 16 + lh * 4 + r;
      if (row < n) {
        float* cr = C + (size_t)row * HID;
        #pragma unroll
        for (int nt = 0; nt < 8; ++nt)
          cr[nt * 16 + lr] = acc2[nt][r] + vb2[nt];
      }
    }
    return;
  }

  float gv[8], bv[8];
  #pragma unroll
  for (int nt = 0; nt < 8; ++nt) { gv[nt] = lg[nt * 16 + lr]; bv[nt] = lbp[nt * 16 + lr]; }

  #pragma unroll
  for (int r = 0; r < 4; ++r) {
    int row = n0 + w * 16 + lh * 4 + r;
    bool ok = row < n;
    float vals[8];
    #pragma unroll
    for (int nt = 0; nt < 8; ++nt) vals[nt] = acc2[nt][r] + vb2[nt];
    float s1 = 0.f, s2 = 0.f;
    #pragma unroll
    for (int nt = 0; nt < 8; ++nt) { s1 += vals[nt]; s2 += vals[nt] * vals[nt]; }
    #pragma unroll
    for (int m = 1; m < 16; m <<= 1) { s1 += __shfl_xor(s1, m, 64); s2 += __shfl_xor(s2, m, 64); }
    float mu = s1 * (1.0f / 128.0f);
    float var = s2 * (1.0f / 128.0f) - mu * mu;
    float rs = rsqrtf(var + 1e-5f);
    int lrow = w * 16 + lh * 4 + r;
    float* hnr = Hn + (size_t)row * HID;
    #pragma unroll
    for (int nt = 0; nt < 8; ++nt) {
      float hn = (vals[nt] - mu) * rs * gv[nt] + bv[nt];
      if (ok) hnr[nt * 16 + lr] = hn;
      Al[lrow][nt * 16 + lr] = f2bf(hn);
    }
  }

  f32x4 aab[16];
  #pragma unroll
  for (int nt = 0; nt < 16; ++nt) aab[nt] = zf;
  #pragma unroll
  for (int q = 0; q < 4; ++q) {
    short8 af = *(const short8*)&Al[w * 16 + lr][q * 32 + lh * 8];
    #pragma unroll
    for (int nt = 0; nt < 16; ++nt) {
      short8 bf = *(const short8*)(Wab + (size_t)(nt * 16 + lr) * HID + q * 32 + lh * 8);
      aab[nt] = __builtin_amdgcn_mfma_f32_16x16x32_bf16(af, bf, aab[nt], 0, 0, 0);
    }
  }
  float be[8];
  #pragma unroll
  for (int nt = 0; nt < 8; ++nt) be[nt] = eb1[nt * 16 + lr];
  #pragma unroll
  for (int r = 0; r < 4; ++r) {
    int row = n0 + w * 16 + lh * 4 + r;
    if (row >= n) break;
    ushort* pa = Pa + (size_t)row * HID;
    ushort* pb = Pb + (size_t)row * HID;
    #pragma unroll
    for (int nt = 0; nt < 8; ++nt) {
      int col = nt * 16 + lr;
      pa[col] = f2h_bits(aab[nt][r] + be[nt]);
      pb[col] = f2h_bits(aab[nt + 8][r]);
    }
  }
}

// ---------------- per-node CSR edge kernel: f16 Pa/Pb/ea, fdot2 + DPP reduce ----------------
__global__ __launch_bounds__(256) void node_edge(
    const ushort* __restrict__ Pah, const ushort* __restrict__ Pbh,
    const ushort* __restrict__ ea_h,
    const int* __restrict__ dst_s,
    const int* __restrict__ ebase, const int* __restrict__ deg,
    const float* __restrict__ w1c,
    const float* __restrict__ elg, const float* __restrict__ elb,
    ushort* __restrict__ Sh, int n)
{
  const int tid = threadIdx.x;
  const int wv = __builtin_amdgcn_readfirstlane(tid >> 6);
  const int lane = tid & 63;
  const int node = blockIdx.x * 4 + wv;
  if (node >= n) return;
  const int c0 = lane * 2;

  half2v w1h0[8], w1h1[8];
  {
    const float* wr0 = w1c + (size_t)c0 * 272 + 256;
    const float* wr1 = wr0 + 272;
    #pragma unroll
    for (int k = 0; k < 8; ++k) {
      half2v h0; h0[0] = (_Float16)wr0[2 * k]; h0[1] = (_Float16)wr0[2 * k + 1]; w1h0[k] = h0;
      half2v h1; h1[0] = (_Float16)wr1[2 * k]; h1[1] = (_Float16)wr1[2 * k + 1]; w1h1[k] = h1;
    }
  }
  const float g0 = elg[c0], g1 = elg[c0 + 1];
  const float b0 = elb[c0], b1 = elb[c0 + 1];
  half2v pav = u2h(*(const uint*)(Pah + (size_t)node * HID + c0));
  const float pax = (float)pav[0];
  const float pay = (float)pav[1];

  const int beg = __builtin_amdgcn_readfirstlane(ebase[node]);
  const int dg  = __builtin_amdgcn_readfirstlane(deg[node]);

  float a0 = 0.f, a1 = 0.f;

  uint4 eA0 = make_uint4(0,0,0,0), eB0 = eA0, eA1 = eA0, eB1 = eA0;
  uint p0 = 0, p1 = 0;

  auto LOADE = [&](int idx, uint4& ea, uint4& eb, uint& pb) {
    int eu = __builtin_amdgcn_readfirstlane(beg + idx);
    int d  = dst_s[eu];
    ea = *(const uint4*)(ea_h + (size_t)eu * 16);
    eb = *(const uint4*)(ea_h + (size_t)eu * 16 + 8);
    pb = *(const uint*)(Pbh + (size_t)d * HID + c0);
  };
  auto PROCESS = [&](const uint4& eaA, const uint4& eaB, uint pbu) {
    half2v eh[8];
    eh[0] = u2h(eaA.x); eh[1] = u2h(eaA.y); eh[2] = u2h(eaA.z); eh[3] = u2h(eaA.w);
    eh[4] = u2h(eaB.x); eh[5] = u2h(eaB.y); eh[6] = u2h(eaB.z); eh[7] = u2h(eaB.w);
    half2v pb2 = u2h(pbu);

    float x0 = pax + (float)pb2[0];
    float x1 = pay + (float)pb2[1];
    #pragma unroll
    for (int k = 0; k < 8; ++k) {
      x0 = __builtin_amdgcn_fdot2(eh[k], w1h0[k], x0, false);
      x1 = __builtin_amdgcn_fdot2(eh[k], w1h1[k], x1, false);
    }
    float s1 = wsum64(x0 + x1);
    float s2 = wsum64(fmaf(x0, x0, x1 * x1));
    float mu = s1 * (1.0f / 128.0f);
    float var = s2 * (1.0f / 128.0f) - mu * mu;
    float rs = rsqrtf(var + 1e-5f);
    a0 += silu_f((x0 - mu) * rs * g0 + b0);
    a1 += silu_f((x1 - mu) * rs * g1 + b1);
  };

  if (dg > 0) LOADE(0, eA0, eB0, p0);
  if (dg > 1) LOADE(1, eA1, eB1, p1);

  for (int i = 0; i < dg; i += 2) {
    uint4 nA0 = make_uint4(0,0,0,0), nB0 = nA0, nA1 = nA0, nB1 = nA0;
    uint np0 = 0, np1 = 0;
    if (i + 2 < dg) LOADE(i + 2, nA0, nB0, np0);
    if (i + 3 < dg) LOADE(i + 3, nA1, nB1, np1);

    PROCESS(eA0, eB0, p0);
    if (i + 1 < dg) PROCESS(eA1, eB1, p1);

    eA0 = nA0; eB0 = nB0; p0 = np0;
    eA1 = nA1; eB1 = nB1; p1 = np1;
  }

  uint pk = (uint)f2h_bits(a0) | ((uint)f2h_bits(a1) << 16);
  *(uint*)(Sh + (size_t)node * HID + c0) = pk;
}

// ---------------- fused node MLP with next-layer pab tail (FUSE=1 of R15) ----------------
__global__ __launch_bounds__(256) void node_mlp_pab(
    const float* __restrict__ Hn, const ushort* __restrict__ Sh,
    const ushort* __restrict__ N1a, const ushort* __restrict__ W2Nh, const ushort* __restrict__ N2,
    const float* __restrict__ nb1, const float* __restrict__ nv, const int* __restrict__ deg,
    const float* __restrict__ lng, const float* __restrict__ lnb, const float* __restrict__ nb2,
    const float* __restrict__ lg2, const float* __restrict__ lb2p,
    const ushort* __restrict__ Wab2, const float* __restrict__ eb1_2,
    float* __restrict__ HnOut, ushort* __restrict__ Pa, ushort* __restrict__ Pb, int n)
{
  __shared__ ushort Ahn[64][136];
  __shared__ ushort Ash[64][136];
  const int tid = threadIdx.x;
  const int n0 = blockIdx.x * 64;

  #pragma unroll
  for (int i = 0; i < 8; ++i) {
    int s = tid + i * 256;
    int row = s >> 5, c4 = (s & 31) * 4;
    int gr = n0 + row;
    float4 vh = make_float4(0.f, 0.f, 0.f, 0.f);
    uint2 sv = make_uint2(0, 0);
    if (gr < n) {
      vh = *(const float4*)(Hn + (size_t)gr * HID + c4);
      sv = *(const uint2*)(Sh + (size_t)gr * HID + c4);
    }
    uint2 ph;
    ph.x = (uint)f2bf(vh.x) | ((uint)f2bf(vh.y) << 16);
    ph.y = (uint)f2bf(vh.z) | ((uint)f2bf(vh.w) << 16);
    *(uint2*)&Ahn[row][c4] = ph;
    *(uint2*)&Ash[row][c4] = sv;
  }
  __syncthreads();

  const int w = tid >> 6, l = tid & 63;
  const int lr = l & 15, lh = l >> 4;

  f32x4 zf = {0.f, 0.f, 0.f, 0.f};
  f32x4 acc[8];
  #pragma unroll
  for (int nt = 0; nt < 8; ++nt) acc[nt] = zf;

  #pragma unroll
  for (int q = 0; q < 4; ++q) {
    short8 an = *(const short8*)&Ahn[w * 16 + lr][q * 32 + lh * 8];
    half8  as = *(const half8*)&Ash[w * 16 + lr][q * 32 + lh * 8];
    #pragma unroll
    for (int nt = 0; nt < 8; ++nt) {
      short8 b1f = *(const short8*)(N1a + (size_t)(nt * 16 + lr) * HID + q * 32 + lh * 8);
      half8  b2h = *(const half8*)(W2Nh + (size_t)(nt * 16 + lr) * HID + q * 32 + lh * 8);
      acc[nt] = __builtin_amdgcn_mfma_f32_16x16x32_bf16(an, b1f, acc[nt], 0, 0, 0);
      acc[nt] = __builtin_amdgcn_mfma_f32_16x16x32_f16(as, b2h, acc[nt], 0, 0, 0);
    }
  }

  float vb[8], vn[8], gv[8], bv[8];
  #pragma unroll
  for (int nt = 0; nt < 8; ++nt) {
    int col = nt * 16 + lr;
    vb[nt] = nb1[col]; vn[nt] = nv[col];
    gv[nt] = lng[col]; bv[nt] = lnb[col];
  }

  #pragma unroll
  for (int r = 0; r < 4; ++r) {
    int row = n0 + w * 16 + lh * 4 + r;
    float degf = (row < n) ? (float)deg[row] : 0.f;
    float vals[8];
    #pragma unroll
    for (int nt = 0; nt < 8; ++nt) vals[nt] = acc[nt][r] + vb[nt] + degf * vn[nt];
    float s1 = 0.f, s2 = 0.f;
    #pragma unroll
    for (int nt = 0; nt < 8; ++nt) { s1 += vals[nt]; s2 += vals[nt] * vals[nt]; }
    #pragma unroll
    for (int m = 1; m < 16; m <<= 1) { s1 += __shfl_xor(s1, m, 64); s2 += __shfl_xor(s2, m, 64); }
    float mu = s1 * (1.0f / 128.0f);
    float var = s2 * (1.0f / 128.0f) - mu * mu;
    float rs = rsqrtf(var + 1e-5f);
    int lrow = w * 16 + lh * 4 + r;
    #pragma unroll
    for (int nt = 0; nt < 8; ++nt)
      Ahn[lrow][nt * 16 + lr] = f2bf(silu_f((vals[nt] - mu) * rs * gv[nt] + bv[nt]));
  }

  f32x4 acc2[8];
  #pragma unroll
  for (int nt = 0; nt < 8; ++nt) acc2[nt] = zf;
  #pragma unroll
  for (int q = 0; q < 4; ++q) {
    short8 af = *(const short8*)&Ahn[w * 16 + lr][q * 32 + lh * 8];
    #pragma unroll
    for (int nt = 0; nt < 8; ++nt) {
      short8 bf = *(const short8*)(N2 + (size_t)(nt * 16 + lr) * HID + q * 32 + lh * 8);
      acc2[nt] = __builtin_amdgcn_mfma_f32_16x16x32_bf16(af, bf, acc2[nt], 0, 0, 0);
    }
  }

  float vb2[8];
  #pragma unroll
  for (int nt = 0; nt < 8; ++nt) vb2[nt] = nb2[nt * 16 + lr];

  float gv2[8], bv2[8];
  #pragma unroll
  for (int nt = 0; nt < 8; ++nt) { gv2[nt] = lg2[nt * 16 + lr]; bv2[nt] = lb2p[nt * 16 + lr]; }

  #pragma unroll
  for (int r = 0; r < 4; ++r) {
    int row = n0 + w * 16 + lh * 4 + r;
    bool ok = row < n;
    const float* hr = Hn + (size_t)row * HID;
    float vals[8];
    #pragma unroll
    for (int nt = 0; nt < 8; ++nt) {
      int col = nt * 16 + lr;
      float base = ok ? hr[col] : 0.f;
      vals[nt] = base + acc2[nt][r] + vb2[nt];
    }
    float s1 = 0.f, s2 = 0.f;
    #pragma unroll
    for (int nt = 0; nt < 8; ++nt) { s1 += vals[nt]; s2 += vals[nt] * vals[nt]; }
    #pragma unroll
    for (int m = 1; m < 16; m <<= 1) { s1 += __shfl_xor(s1, m, 64); s2 += __shfl_xor(s2, m, 64); }
    float mu = s1 * (1.0f / 128.0f);
    float var = s2 * (1.0f / 128.0f) - mu * mu;
    float rs = rsqrtf(var + 1e-5f);
    int lrow = w * 16 + lh * 4 + r;
    float* hnr = HnOut + (size_t)row * HID;
    #pragma unroll
    for (int nt = 0; nt < 8; ++nt) {
      float hn = (vals[nt] - mu) * rs * gv2[nt] + bv2[nt];
      if (ok) hnr[nt * 16 + lr] = hn;
      Ahn[lrow][nt * 16 + lr] = f2bf(hn);
    }
  }

  f32x4 aab[16];
  #pragma unroll
  for (int nt = 0; nt < 16; ++nt) aab[nt] = zf;
  #pragma unroll
  for (int q = 0; q < 4; ++q) {
    short8 af = *(const short8*)&Ahn[w * 16 + lr][q * 32 + lh * 8];
    #pragma unroll
    for (int nt = 0; nt < 16; ++nt) {
      short8 bf = *(const short8*)(Wab2 + (size_t)(nt * 16 + lr) * HID + q * 32 + lh * 8);
      aab[nt] = __builtin_amdgcn_mfma_f32_16x16x32_bf16(af, bf, aab[nt], 0, 0, 0);
    }
  }
  float be[8];
  #pragma unroll
  for (int nt = 0; nt < 8; ++nt) be[nt] = eb1_2[nt * 16 + lr];
  #pragma unroll
  for (int r = 0; r < 4; ++r) {
    int row = n0 + w * 16 + lh * 4 + r;
    if (row >= n) break;
    ushort* pa = Pa + (size_t)row * HID;
    ushort* pb = Pb + (size_t)row * HID;
    #pragma unroll
    for (int nt = 0; nt < 8; ++nt) {
      int col = nt * 16 + lr;
      pa[col] = f2h_bits(aab[nt][r] + be[nt]);
      pb[col] = f2h_bits(aab[nt + 8][r]);
    }
  }
}

// ---------------- fused LAST node MLP + embedding_out (B_h never materialized) ----------------
__global__ __launch_bounds__(256) void node_mlp_out(
    const float* __restrict__ Hn, const ushort* __restrict__ Sh,
    const ushort* __restrict__ N1a, const ushort* __restrict__ W2Nh, const ushort* __restrict__ N2,
    const float* __restrict__ nb1, const float* __restrict__ nv, const int* __restrict__ deg,
    const float* __restrict__ lng, const float* __restrict__ lnb, const float* __restrict__ nb2,
    const ushort* __restrict__ Wo1, const float* __restrict__ bo1,
    const ushort* __restrict__ Wo2, const float* __restrict__ bo2,
    float* __restrict__ Out, int n)
{
  __shared__ ushort Ahn[64][136];
  __shared__ ushort Ash[64][136];
  const int tid = threadIdx.x;
  const int n0 = blockIdx.x * 64;

  #pragma unroll
  for (int i = 0; i < 8; ++i) {
    int s = tid + i * 256;
    int row = s >> 5, c4 = (s & 31) * 4;
    int gr = n0 + row;
    float4 vh = make_float4(0.f, 0.f, 0.f, 0.f);
    uint2 sv = make_uint2(0, 0);
    if (gr < n) {
      vh = *(const float4*)(Hn + (size_t)gr * HID + c4);
      sv = *(const uint2*)(Sh + (size_t)gr * HID + c4);
    }
    uint2 ph;
    ph.x = (uint)f2bf(vh.x) | ((uint)f2bf(vh.y) << 16);
    ph.y = (uint)f2bf(vh.z) | ((uint)f2bf(vh.w) << 16);
    *(uint2*)&Ahn[row][c4] = ph;
    *(uint2*)&Ash[row][c4] = sv;
  }
  __syncthreads();

  const int w = tid >> 6, l = tid & 63;
  const int lr = l & 15, lh = l >> 4;

  f32x4 zf = {0.f, 0.f, 0.f, 0.f};
  f32x4 acc[8];
  #pragma unroll
  for (int nt = 0; nt < 8; ++nt) acc[nt] = zf;

  #pragma unroll
  for (int q = 0; q < 4; ++q) {
    short8 an = *(const short8*)&Ahn[w * 16 + lr][q * 32 + lh * 8];
    half8  as = *(const half8*)&Ash[w * 16 + lr][q * 32 + lh * 8];
    #pragma unroll
    for (int nt = 0; nt < 8; ++nt) {
      short8 b1f = *(const short8*)(N1a + (size_t)(nt * 16 + lr) * HID + q * 32 + lh * 8);
      half8  b2h = *(const half8*)(W2Nh + (size_t)(nt * 16 + lr) * HID + q * 32 + lh * 8);
      acc[nt] = __builtin_amdgcn_mfma_f32_16x16x32_bf16(an, b1f, acc[nt], 0, 0, 0);
      acc[nt] = __builtin_amdgcn_mfma_f32_16x16x32_f16(as, b2h, acc[nt], 0, 0, 0);
    }
  }

  float vb[8], vn[8], gv[8], bv[8];
  #pragma unroll
  for (int nt = 0; nt < 8; ++nt) {
    int col = nt * 16 + lr;
    vb[nt] = nb1[col]; vn[nt] = nv[col];
    gv[nt] = lng[col]; bv[nt] = lnb[col];
  }

  #pragma unroll
  for (int r = 0; r < 4; ++r) {
    int row = n0 + w * 16 + lh * 4 + r;
    float degf = (row < n) ? (float)deg[row] : 0.f;
    float vals[8];
    #pragma unroll
    for (int nt = 0; nt < 8; ++nt) vals[nt] = acc[nt][r] + vb[nt] + degf * vn[nt];
    float s1 = 0.f, s2 = 0.f;
    #pragma unroll
    for (int nt = 0; nt < 8; ++nt) { s1 += vals[nt]; s2 += vals[nt] * vals[nt]; }
    #pragma unroll
    for (int m = 1; m < 16; m <<= 1) { s1 += __shfl_xor(s1, m, 64); s2 += __shfl_xor(s2, m, 64); }
    float mu = s1 * (1.0f / 128.0f);
    float var = s2 * (1.0f / 128.0f) - mu * mu;
    float rs = rsqrtf(var + 1e-5f);
    int lrow = w * 16 + lh * 4 + r;
    #pragma unroll
    for (int nt = 0; nt < 8; ++nt)
      Ahn[lrow][nt * 16 + lr] = f2bf(silu_f((vals[nt] - mu) * rs * gv[nt] + bv[nt]));
  }

  // dh = (...)@N2^T
  f32x4 acc2[8];
  #pragma unroll
  for (int nt = 0; nt < 8; ++nt) acc2[nt] = zf;
  #pragma unroll
  for (int q = 0; q < 4; ++q) {
    short8 af = *(const short8*)&Ahn[w * 16 + lr][q * 32 + lh * 8];
    #pragma unroll
    for (int nt = 0; nt < 8; ++nt) {
      short8 bf = *(const short8*)(N2 + (size_t)(nt * 16 + lr) * HID + q * 32 + lh * 8);
      acc2[nt] = __builtin_amdgcn_mfma_f32_16x16x32_bf16(af, bf, acc2[nt], 0, 0, 0);
    }
  }

  float vb2[8];
  #pragma unroll
  for (int nt = 0; nt < 8; ++nt) vb2[nt] = nb2[nt * 16 + lr];

  // h' = hn + dh + nb2  -> stage bf16 into Ahn (wave-private rows)
  #pragma unroll
  for (int r = 0; r < 4; ++r) {
    int row = n0 + w * 16 + lh * 4 + r;
    bool ok = row < n;
    const float* hr = Hn + (size_t)row * HID;
    int lrow = w * 16 + lh * 4 + r;
    #pragma unroll
    for (int nt = 0; nt < 8; ++nt) {
      int col = nt * 16 + lr;
      float base = ok ? hr[col] : 0.f;
      Ahn[lrow][nt * 16 + lr] = f2bf(base + acc2[nt][r] + vb2[nt]);
    }
  }

  // embedding_out GEMM1: silu(h'@Wo1^T + bo1) -> Ahn
  f32x4 acc3[8];
  #pragma unroll
  for (int nt = 0; nt < 8; ++nt) acc3[nt] = zf;
  #pragma unroll
  for (int q = 0; q < 4; ++q) {
    short8 af = *(const short8*)&Ahn[w * 16 + lr][q * 32 + lh * 8];
    #pragma unroll
    for (int nt = 0; nt < 8; ++nt) {
      short8 bf = *(const short8*)(Wo1 + (size_t)(nt * 16 + lr) * HID + q * 32 + lh * 8);
      acc3[nt] = __builtin_amdgcn_mfma_f32_16x16x32_bf16(af, bf, acc3[nt], 0, 0, 0);
    }
  }
  float vb3[8];
  #pragma unroll
  for (int nt = 0; nt < 8; ++nt) vb3[nt] = bo1[nt * 16 + lr];
  #pragma unroll
  for (int r = 0; r < 4; ++r) {
    int lrow = w * 16 + lh * 4 + r;
    #pragma unroll
    for (int nt = 0; nt < 8; ++nt)
      Ahn[lrow][nt * 16 + lr] = f2bf(silu_f(acc3[nt][r] + vb3[nt]));
  }

  // embedding_out GEMM2: @Wo2^T + bo2 -> Out
  f32x4 acc4[8];
  #pragma unroll
  for (int nt = 0; nt < 8; ++nt) acc4[nt] = zf;
  #pragma unroll
  for (int q = 0; q < 4; ++q) {
    short8 af = *(const short8*)&Ahn[w * 16 + lr][q * 32 + lh * 8];
    #pragma unroll
    for (int nt = 0; nt < 8; ++nt) {
      short8 bf = *(const short8*)(Wo2 + (size_t)(nt * 16 + lr) * HID + q * 32 + lh * 8);
      acc4[nt] = __builtin_amdgcn_mfma_f32_16x16x32_bf16(af, bf, acc4[nt], 0, 0, 0);
    }
  }
  float vb4[8];
  #pragma unroll
  for (int nt = 0; nt < 8; ++nt) vb4[nt] = bo2[nt * 16 + lr];
  #pragma unroll
  for (int r = 0; r < 4; ++r) {
    int row = n0 + w * 16 + lh * 4 + r;
    if (row < n) {
      float* cr = Out + (size_t)row * HID;
      #pragma unroll
      for (int nt = 0; nt < 8; ++nt)
        cr[nt * 16 + lr] = acc4[nt][r] + vb4[nt];
    }
  }
}

extern "C" void kernel_launch(void* const* d_in, const int* in_sizes, int n_in,
                              void* d_out, int out_size, void* d_ws, size_t ws_size,
                              hipStream_t stream)
{
  const float* in_h  = (const float*)d_in[0];
  const int*   edges = (const int*)d_in[1];
  const float* ea    = (const float*)d_in[2];
  const float* ei_w1 = (const float*)d_in[3];
  const float* ei_b1 = (const float*)d_in[4];
  const float* ei_w2 = (const float*)d_in[5];
  const float* ei_b2 = (const float*)d_in[6];
  const float* ng    = (const float*)d_in[7];
  const float* nbp   = (const float*)d_in[8];
  const float* ew1   = (const float*)d_in[9];
  const float* eb1   = (const float*)d_in[10];
  const float* elg   = (const float*)d_in[11];
  const float* elb   = (const float*)d_in[12];
  const float* ew2   = (const float*)d_in[13];
  const float* eb2   = (const float*)d_in[14];
  const float* nw1   = (const float*)d_in[15];
  const float* nb1   = (const float*)d_in[16];
  const float* nlg   = (const float*)d_in[17];
  const float* nlb   = (const float*)d_in[18];
  const float* nw2   = (const float*)d_in[19];
  const float* nb2   = (const float*)d_in[20];
  const float* eo_w1 = (const float*)d_in[21];
  const float* eo_b1 = (const float*)d_in[22];
  const float* eo_w2 = (const float*)d_in[23];
  const float* eo_b2 = (const float*)d_in[24];

  float* wf    = (float*)d_ws;
  float* B_hn  = wf + NNH;
  float* B_S   = wf + 2 * NNH;
  float* B_tmp = wf + 3 * NNH;
  float* B_pb  = wf + 4 * NNH;
  ushort* Sh   = (ushort*)B_S;
  ushort* Pah  = (ushort*)B_tmp;
  ushort* Pbh  = (ushort*)B_pb;

  const size_t WOFF = 5 * NNH;
  ushort* wu = (ushort*)(wf + WOFF);
  // ei1@0, ei2@16384, eo1@32768, eo2@49152; per-layer base 65536 + l*104448:
  //   Wab@0 [256][128] | W2N(f16)@32768 | N1a@49152 | N2@81920
  const size_t SOFF = WOFF + 262144;
  int* dst_s = (int*)(wf + SOFF);
  int* cnt   = dst_s + NE;       // = deg
  int* cur   = cnt + NPAD;
  int* base  = cur + NPAD;
  ushort* ea_s = (ushort*)(base + NPAD);
  float* nvb = (float*)(ea_s + (size_t)NE * 16);   // 4*128 fp32

  const int NB  = (NN + 63) / 64;
  const int NBE = (NN + 3) / 4;
  const int NEB = (NE + 255) / 256;

  const int* erow = edges;
  const int* ecol = edges + NE;

  // ---- counting sort by src (once; ea permute+cvt fused into placement) ----
  zero_i<<<(2 * NPAD + 255) / 256, 256, 0, stream>>>(cnt, 2 * NPAD);
  count_src<<<NEB, 256, 0, stream>>>(erow, cnt);
  scan_excl<<<1, 1024, 0, stream>>>(cnt, base, NN);
  place_edges<<<NEB, 256, 0, stream>>>(erow, ecol, (const float4*)ea, base, cur, dst_s, ea_s);

  // ---- weight conversion / folding ----
  cvt4<<<256, 256, 0, stream>>>(ei_w1, ei_w2, eo_w1, eo_w2, wu);
  cvt_wab<<<512, 256, 0, stream>>>(ew1, wu + 65536);
  cvt_std<<<(4 * 16384 + 255) / 256, 256, 0, stream>>>(nw2, wu + 65536 + 81920, 128, 128, 16384);
  fold_w<<<512, 128, 0, stream>>>(nw1, ew2, eb2, wu + 65536, nvb);

  // ---- embedding_in fused with layer-0 pab_ln ----
  emb2<1><<<NB, 256, 0, stream>>>(in_h, wu, ei_b1, wu + 16384, ei_b2,
      ng, nbp, wu + 65536, eb1, B_hn, Pah, Pbh, nullptr, NN);

  for (int lyr = 0; lyr < 4; ++lyr) {
    ushort* lb = wu + 65536 + lyr * 104448;
    node_edge<<<NBE, 256, 0, stream>>>(Pah, Pbh, ea_s, dst_s, base, cnt,
        ew1 + 34816 * lyr, elg + 128 * lyr, elb + 128 * lyr, Sh, NN);
    if (lyr < 3) {
      ushort* lb2 = lb + 104448;
      node_mlp_pab<<<NB, 256, 0, stream>>>(B_hn, Sh, lb + 49152, lb + 32768, lb + 81920,
          nb1 + 128 * lyr, nvb + 128 * lyr, cnt,
          nlg + 128 * lyr, nlb + 128 * lyr, nb2 + 128 * lyr,
          ng + 128 * (lyr + 1), nbp + 128 * (lyr + 1), lb2, eb1 + 128 * (lyr + 1),
          B_hn, Pah, Pbh, NN);
    } else {
      node_mlp_out<<<NB, 256, 0, stream>>>(B_hn, Sh, lb + 49152, lb + 32768, lb + 81920,
          nb1 + 128 * lyr, nvb + 128 * lyr, cnt,
          nlg + 128 * lyr, nlb + 128 * lyr, nb2 + 128 * lyr,
          wu + 32768, eo_b1, wu + 49152, eo_b2,
          (float*)d_out, NN);
    }
  }
}